// Round 5
// baseline (603.787 us; speedup 1.0000x reference)
//
#include <hip/hip_runtime.h>
#include <cstdint>
#include <cstddef>

// Problem constants
#define N_TOK 4096
#define E_DIM 2048
#define NH    16
#define DH    128
#define KEXP  4
#define CAPN  1280
#define NTILE 20                 // CAPN/64
#define QKV_STRIDE 6144          // fused QKV output row stride
#define SCALE_QK 0.08838834764831845f
#define LOG2E    1.4426950408889634f
#define NEG_BIG -1e30f

typedef __attribute__((ext_vector_type(4))) float f32x4;
typedef __attribute__((ext_vector_type(8))) short s16x8;

__device__ __forceinline__ float bf2f(unsigned short u){
  union{unsigned int i; float fl;} c; c.i = ((unsigned int)u)<<16; return c.fl;
}
__device__ __forceinline__ unsigned short f2bf(float x){
  union{float fl; unsigned int i;} c; c.fl=x;
  return (unsigned short)((c.i + 0x7FFFu + ((c.i>>16)&1u))>>16);
}
__device__ __forceinline__ f32x4 mfma_bf16(s16x8 a, s16x8 b, f32x4 c){
  asm("v_mfma_f32_16x16x32_bf16 %0, %1, %2, %0" : "+v"(c) : "v"(a), "v"(b));
  return c;
}
// async global->LDS 16B: LDS dest must be lane-linear (base + lane*16)
__device__ __forceinline__ void gl_lds16(const unsigned short* g, unsigned short* l){
  __builtin_amdgcn_global_load_lds(
      (const __attribute__((address_space(1))) unsigned int*)g,
      (__attribute__((address_space(3))) unsigned int*)l, 16, 0, 0);
}

// ---------------- conversions ----------------
__global__ __launch_bounds__(256) void conv_x_kernel(const float* __restrict__ x,
    unsigned short* __restrict__ hi, unsigned short* __restrict__ lo, int n4){
  int idx = blockIdx.x*256 + threadIdx.x;
  if (idx >= n4) return;
  float4 v = ((const float4*)x)[idx];
  float ar[4] = {v.x, v.y, v.z, v.w};
  union{ unsigned short u[4]; uint2 q; } H, L;
  #pragma unroll
  for(int i=0;i<4;i++){
    unsigned short h = f2bf(ar[i]);
    H.u[i] = h;
    L.u[i] = f2bf(ar[i] - bf2f(h));
  }
  ((uint2*)hi)[idx] = H.q;
  ((uint2*)lo)[idx] = L.q;
}

// transpose + f32->bf16 (optionally also lo residual). W[R][C] -> T[C][R]
__global__ __launch_bounds__(256) void tconv_kernel(const float* __restrict__ W,
    unsigned short* __restrict__ Thi, unsigned short* __restrict__ Tlo, int R, int C){
  __shared__ float t[32][33];
  int tx = threadIdx.x, ty = threadIdx.y;   // (32,8)
  int c0 = blockIdx.x*32, r0 = blockIdx.y*32;
  #pragma unroll
  for(int i=0;i<4;i++){
    int r = r0 + ty + i*8;
    t[ty+i*8][tx] = W[(size_t)r*C + c0 + tx];
  }
  __syncthreads();
  #pragma unroll
  for(int i=0;i<4;i++){
    int c = c0 + ty + i*8;
    float v = t[tx][ty+i*8];
    size_t o = (size_t)c*R + r0 + tx;
    unsigned short h = f2bf(v);
    Thi[o] = h;
    if (Tlo) Tlo[o] = f2bf(v - bf2f(h));
  }
}

// ============ 128x256 BK=64 phase-pipelined GEMM (T2+T3+T4+T5) ============
// C[M][N] = A[M][K] * Bt[N][K]^T. 512 thr = 8 waves 2Mx4N, wave tile 64x64.
// LDS 96KB: A k-slabs [2buf][2ks][128x32], B [2][2][256x32].
// Phases per K-tile: (ks0,collo)(ks0,colhi)(ks1,collo)(ks1,colhi), 8 MFMA each.
// Stage stream (1 unit/phase): ph0:A1(t+1) ph1:B1(t+1) ph2:A0(t+2) ph3:B0(t+2).
// vmcnt(3) at ph1/ph3 -> 3 loads stay in flight, never drains (T4).
// Chunk swizzle c ^ ((row&3)^((row>>2)&3)) baked into global source (T2).
template<int OUTBF>
__global__ __launch_bounds__(512, 2) void gemm_mn_kernel(
    const unsigned short* __restrict__ A, const unsigned short* __restrict__ Bt,
    void* __restrict__ Cp, int N, int Kd, int NBx){
  __shared__ __align__(16) unsigned short Asl[2][2][128*32];
  __shared__ __align__(16) unsigned short Bsl[2][2][256*32];
  const int tid = threadIdx.x;
  const int w = tid>>6, lane = tid&63, g = lane>>4, r16 = lane&15;
  const int wm = w>>2, wn = w&3;
  const int nblk = gridDim.x;
  const int lin = (blockIdx.x & 7)*(nblk>>3) + (blockIdx.x>>3);  // XCD-chunked
  const int mb = lin / NBx, nb = lin % NBx;
  const unsigned short* Ab = A  + (size_t)mb*128*Kd;
  const unsigned short* Bb = Bt + (size_t)nb*256*Kd;
  const int NT = Kd >> 6;

  f32x4 acc[4][4];
  #pragma unroll
  for(int i=0;i<4;i++)
    #pragma unroll
    for(int j=0;j<4;j++) acc[i][j]=f32x4{0.f,0.f,0.f,0.f};

  const int arow = tid>>2, ac = tid&3;
  const int asrc = ac ^ ((arow&3) ^ ((arow>>2)&3));
  auto stageA = [&](int buf, int ks, int t){
    gl_lds16(Ab + (size_t)arow*Kd + t*64 + ks*32 + asrc*8, &Asl[buf][ks][tid*8]);
  };
  auto stageB = [&](int buf, int ks, int t){
    #pragma unroll
    for(int i=0;i<2;i++){
      int n = i*512 + tid;
      int row = n>>2, c = n&3;
      int sc = c ^ ((row&3) ^ ((row>>2)&3));
      gl_lds16(Bb + (size_t)row*Kd + t*64 + ks*32 + sc*8, &Bsl[buf][ks][n*8]);
    }
  };
  const int fxr = (r16&3) ^ ((r16>>2)&3);
  const int xoff = (g ^ fxr) << 3;

  // prologue: tile0 full -> buf0, tile1 {A0,B0} -> buf1; keep 3 loads in flight
  stageA(0,0,0); stageB(0,0,0); stageA(0,1,0); stageB(0,1,0);
  stageA(1,0,1); stageB(1,0,1);
  asm volatile("s_waitcnt vmcnt(3)" ::: "memory");
  __builtin_amdgcn_s_barrier();

  int cur = 0;
  for(int t=0; t<NT; ++t){
    const int nxt = cur^1;
    s16x8 aA[4], bB[2];
    // ---- phase 0: ks0, col-frags 0,1 ----
    if (t+1 < NT) stageA(nxt, 1, t+1);
    #pragma unroll
    for(int f=0; f<4; f++)
      aA[f] = *(const s16x8*)&Asl[cur][0][(wm*64+f*16+r16)*32 + xoff];
    #pragma unroll
    for(int c=0; c<2; c++)
      bB[c] = *(const s16x8*)&Bsl[cur][0][(wn*64+c*16+r16)*32 + xoff];
    __builtin_amdgcn_s_barrier();
    __builtin_amdgcn_s_setprio(1);
    #pragma unroll
    for(int f=0; f<4; f++)
      #pragma unroll
      for(int c=0; c<2; c++)
        acc[f][c] = mfma_bf16(aA[f], bB[c], acc[f][c]);
    __builtin_amdgcn_s_setprio(0);
    __builtin_amdgcn_s_barrier();
    // ---- phase 1: ks0, col-frags 2,3 ----
    if (t+1 < NT) stageB(nxt, 1, t+1);
    #pragma unroll
    for(int c=0; c<2; c++)
      bB[c] = *(const s16x8*)&Bsl[cur][0][(wn*64+(2+c)*16+r16)*32 + xoff];
    if (t+1 < NT) asm volatile("s_waitcnt vmcnt(3)" ::: "memory");
    else          asm volatile("s_waitcnt vmcnt(0)" ::: "memory");
    __builtin_amdgcn_s_barrier();
    __builtin_amdgcn_s_setprio(1);
    #pragma unroll
    for(int f=0; f<4; f++)
      #pragma unroll
      for(int c=0; c<2; c++)
        acc[f][2+c] = mfma_bf16(aA[f], bB[c], acc[f][2+c]);
    __builtin_amdgcn_s_setprio(0);
    __builtin_amdgcn_s_barrier();
    // ---- phase 2: ks1, col-frags 0,1 ----
    if (t+2 < NT) stageA(cur, 0, t+2);
    #pragma unroll
    for(int f=0; f<4; f++)
      aA[f] = *(const s16x8*)&Asl[cur][1][(wm*64+f*16+r16)*32 + xoff];
    #pragma unroll
    for(int c=0; c<2; c++)
      bB[c] = *(const s16x8*)&Bsl[cur][1][(wn*64+c*16+r16)*32 + xoff];
    __builtin_amdgcn_s_barrier();
    __builtin_amdgcn_s_setprio(1);
    #pragma unroll
    for(int f=0; f<4; f++)
      #pragma unroll
      for(int c=0; c<2; c++)
        acc[f][c] = mfma_bf16(aA[f], bB[c], acc[f][c]);
    __builtin_amdgcn_s_setprio(0);
    __builtin_amdgcn_s_barrier();
    // ---- phase 3: ks1, col-frags 2,3 ----
    if (t+2 < NT) stageB(cur, 0, t+2);
    #pragma unroll
    for(int c=0; c<2; c++)
      bB[c] = *(const s16x8*)&Bsl[cur][1][(wn*64+(2+c)*16+r16)*32 + xoff];
    if (t+2 < NT) asm volatile("s_waitcnt vmcnt(3)" ::: "memory");
    else          asm volatile("s_waitcnt vmcnt(0)" ::: "memory");
    __builtin_amdgcn_s_barrier();
    __builtin_amdgcn_s_setprio(1);
    #pragma unroll
    for(int f=0; f<4; f++)
      #pragma unroll
      for(int c=0; c<2; c++)
        acc[f][2+c] = mfma_bf16(aA[f], bB[c], acc[f][2+c]);
    __builtin_amdgcn_s_setprio(0);
    __builtin_amdgcn_s_barrier();
    cur ^= 1;
  }

  const int rowb = mb*128 + wm*64, colb = nb*256 + wn*64;
  #pragma unroll
  for(int f=0; f<4; f++)
    #pragma unroll
    for(int c=0; c<4; c++)
      #pragma unroll
      for(int r=0; r<4; r++){
        int rr = rowb + f*16 + 4*g + r;
        int cc = colb + c*16 + r16;
        size_t o = (size_t)rr*N + cc;
        if (OUTBF) ((unsigned short*)Cp)[o] = f2bf(acc[f][c][r]);
        else       ((float*)Cp)[o] = acc[f][c][r];
      }
}

// ---------------- fused router GEMM: H = gelu(x@Wr1 + br1) via hi/lo split ----------------
__global__ __launch_bounds__(256) void gemm_router_kernel(
    const unsigned short* __restrict__ Ahi, const unsigned short* __restrict__ Alo,
    const unsigned short* __restrict__ Bhi, const unsigned short* __restrict__ Blo,
    const float* __restrict__ br1, float* __restrict__ H){
  __shared__ __align__(16) unsigned short AsH[128*32];
  __shared__ __align__(16) unsigned short AsL[128*32];
  __shared__ __align__(16) unsigned short BsH[128*32];
  __shared__ __align__(16) unsigned short BsL[128*32];
  const int mb = blockIdx.y, nb = blockIdx.x;
  const int tid = threadIdx.x;
  const int lane = tid & 63, w = tid >> 6;
  const int g = lane >> 4, r16 = lane & 15;
  const int wm = w >> 1, wn = w & 1;
  f32x4 acc[4][4];
  #pragma unroll
  for(int i=0;i<4;i++)
    #pragma unroll
    for(int j=0;j<4;j++) acc[i][j] = f32x4{0.f,0.f,0.f,0.f};
  const unsigned short* AbH = Ahi + (size_t)mb*128*E_DIM;
  const unsigned short* AbL = Alo + (size_t)mb*128*E_DIM;
  const unsigned short* BbH = Bhi + (size_t)nb*128*E_DIM;
  const unsigned short* BbL = Blo + (size_t)nb*128*E_DIM;
  const int xr2 = (r16>>1)&3;
  for(int k0=0;k0<E_DIM;k0+=32){
    __syncthreads();
    #pragma unroll
    for(int i=0;i<2;i++){
      int c = i*256 + tid;
      int row = c>>2;
      int sc = ((c&3) ^ ((row>>1)&3))*8;   // pre-swizzled source
      size_t go = (size_t)row*E_DIM + k0 + sc;
      gl_lds16(AbH + go, &AsH[c*8]);
      gl_lds16(AbL + go, &AsL[c*8]);
      gl_lds16(BbH + go, &BsH[c*8]);
      gl_lds16(BbL + go, &BsL[c*8]);
    }
    __syncthreads();
    s16x8 ah[4], al[4], bh[4], bl[4];
    #pragma unroll
    for(int f2=0;f2<4;f2++){
      int ra = (wm*64 + f2*16 + r16)*32 + 8*(g ^ xr2);
      int rb = (wn*64 + f2*16 + r16)*32 + 8*(g ^ xr2);
      ah[f2] = *(const s16x8*)&AsH[ra];
      al[f2] = *(const s16x8*)&AsL[ra];
      bh[f2] = *(const s16x8*)&BsH[rb];
      bl[f2] = *(const s16x8*)&BsL[rb];
    }
    #pragma unroll
    for(int fm=0;fm<4;fm++)
      #pragma unroll
      for(int fn=0;fn<4;fn++){
        acc[fm][fn] = mfma_bf16(ah[fm], bh[fn], acc[fm][fn]);
        acc[fm][fn] = mfma_bf16(ah[fm], bl[fn], acc[fm][fn]);
        acc[fm][fn] = mfma_bf16(al[fm], bh[fn], acc[fm][fn]);
      }
  }
  const int rowb = mb*128 + wm*64, colb = nb*128 + wn*64;
  #pragma unroll
  for(int fm=0;fm<4;fm++)
    #pragma unroll
    for(int fn=0;fn<4;fn++)
      #pragma unroll
      for(int r=0;r<4;r++){
        int rr = rowb + fm*16 + 4*g + r;
        int cc = colb + fn*16 + r16;
        float v = acc[fm][fn][r] + br1[cc];
        H[(size_t)rr*1024 + cc] = 0.5f*v*(1.0f + erff(v*0.70710678118654752f));
      }
}

// ---------------- router scores ----------------
__global__ __launch_bounds__(256) void scores_kernel(const float* __restrict__ h,
    const float* __restrict__ Wr2, const float* __restrict__ br2,
    float* __restrict__ scores, float* __restrict__ tokmax){
  int tid = threadIdx.x;
  int n = blockIdx.x*4 + (tid>>6);
  int lane = tid & 63;
  const float* hr = h + (size_t)n*1024;
  float s0=0,s1=0,s2=0,s3=0;
  #pragma unroll
  for(int i=0;i<16;i++){
    int j = lane + i*64;
    float hv = hr[j];
    float4 wv = *(const float4*)(Wr2 + (size_t)j*4);
    s0 += hv*wv.x; s1 += hv*wv.y; s2 += hv*wv.z; s3 += hv*wv.w;
  }
  #pragma unroll
  for(int m=32;m>=1;m>>=1){
    s0 += __shfl_xor(s0,m); s1 += __shfl_xor(s1,m);
    s2 += __shfl_xor(s2,m); s3 += __shfl_xor(s3,m);
  }
  if (lane==0){
    s0+=br2[0]; s1+=br2[1]; s2+=br2[2]; s3+=br2[3];
    scores[n*4+0]=s0; scores[n*4+1]=s1; scores[n*4+2]=s2; scores[n*4+3]=s3;
    tokmax[n]=fmaxf(fmaxf(s0,s1),fmaxf(s2,s3));
  }
}

__global__ __launch_bounds__(1024) void aux_kernel(const float* __restrict__ tokmax, float* __restrict__ out_aux){
  __shared__ float red[1024];
  int t = threadIdx.x;
  red[t] = tokmax[t] + tokmax[t+1024] + tokmax[t+2048] + tokmax[t+3072];
  __syncthreads();
  for(int k=512;k>=1;k>>=1){ if(t<k) red[t]+=red[t+k]; __syncthreads(); }
  if (t==0) out_aux[0] = -red[0]/4096.0f;
}

// ---------------- exact top-k (bitonic sort of 4096 per expert) ----------------
__global__ __launch_bounds__(1024) void topk_kernel(const float* __restrict__ scores,
    int* __restrict__ topk_idx, float* __restrict__ sel_w, int* __restrict__ rank_of){
  __shared__ float sv[4096];
  __shared__ int   si[4096];
  __shared__ float red[1024];
  int e = blockIdx.x, t = threadIdx.x;
  for(int i=t;i<4096;i+=1024){ sv[i]=scores[i*4+e]; si[i]=i; }
  __syncthreads();
  for(int k=2;k<=4096;k<<=1){
    for(int j=k>>1;j>0;j>>=1){
      for(int i=t;i<4096;i+=1024){
        int ixj = i^j;
        if (ixj>i){
          float vi=sv[i], vj=sv[ixj];
          int ii=si[i], ij=si[ixj];
          bool jGreater = (vj>vi) || (vj==vi && ij<ii);
          bool asc = (i&k)==0;
          if (asc ? jGreater : !jGreater){
            sv[i]=vj; sv[ixj]=vi; si[i]=ij; si[ixj]=ii;
          }
        }
      }
      __syncthreads();
    }
  }
  for(int i=t;i<4096;i+=1024) rank_of[e*4096+i] = -1;
  __syncthreads();
  for(int r=t;r<CAPN;r+=1024){
    int tok = si[r];
    topk_idx[e*CAPN+r] = tok;
    rank_of[e*4096+tok] = r;
  }
  float mx = sv[0];
  float part = 0.f;
  for(int r=t;r<CAPN;r+=1024) part += expf(sv[r]-mx);
  red[t]=part; __syncthreads();
  for(int k=512;k>=1;k>>=1){ if(t<k) red[t]+=red[t+k]; __syncthreads(); }
  float denom = red[0];
  for(int r=t;r<CAPN;r+=1024) sel_w[e*CAPN+r] = expf(sv[r]-mx)/denom;
}

// ---------------- RoPE tables [CAPN][64] ----------------
__global__ __launch_bounds__(256) void rope_kernel(float* __restrict__ cosT, float* __restrict__ sinT){
  int idx = blockIdx.x*256 + threadIdx.x;
  int p = idx>>6, dm = idx&63;
  float inv = powf(10000.0f, -(float)dm/64.0f);
  float ang = (float)p*inv;
  cosT[idx]=cosf(ang);
  sinT[idx]=sinf(ang);
}

// ---------------- pre-gather + pre-rope K into swizzled tiles ----------------
__global__ __launch_bounds__(256) void prerope_k_kernel(const unsigned short* __restrict__ kb,
    const int* __restrict__ topk_idx, const float* __restrict__ cosT, const float* __restrict__ sinT,
    unsigned short* __restrict__ Kg){
  int idx = blockIdx.x*256 + threadIdx.x;   // exact 4*16*1280*16
  int ch = idx & 15;
  int rest = idx >> 4;
  int rank = rest % CAPN;
  int he = rest / CAPN;           // e*16+h
  int e = he >> 4, h = he & 15;
  int tok = topk_idx[e*CAPN + rank];
  int d0 = ch*8;
  const unsigned short* krow = kb + (size_t)tok*QKV_STRIDE + h*DH;
  unsigned short held[8], part[8];
  *(uint4*)held = *(const uint4*)(krow + d0);
  *(uint4*)part = *(const uint4*)(krow + (d0^64));
  const float* cr = cosT + rank*64;
  const float* sr = sinT + rank*64;
  float sgn = (d0<64) ? -1.f : 1.f;
  unsigned short outv[8];
  #pragma unroll
  for(int jj=0;jj<8;jj++){
    int dm = (d0+jj)&63;
    outv[jj] = f2bf(bf2f(held[jj])*cr[dm] + sgn*bf2f(part[jj])*sr[dm]);
  }
  int t = rank >> 6, row = rank & 63;
  size_t tbase = ((size_t)(he)*NTILE + t) * 8192;
  *(uint4*)(Kg + tbase + row*128 + ((ch ^ (row&7))<<3)) = *(uint4*)outv;
}

// ---------------- pre-gather + transpose V into swizzled tiles ----------------
__global__ __launch_bounds__(256) void prev_kernel(const unsigned short* __restrict__ vb,
    const int* __restrict__ topk_idx, unsigned short* __restrict__ Vg){
  __shared__ __align__(16) unsigned short T2[128][72];
  int bid = blockIdx.x;           // e*320 + h*20 + t
  int t = bid % NTILE, h = (bid/NTILE) & 15, e = bid/(NTILE*NH);
  int tid = threadIdx.x, lane = tid & 63, dchb = tid >> 6;
  int tok = topk_idx[e*CAPN + t*64 + lane];
  const unsigned short* vrow = vb + (size_t)tok*QKV_STRIDE + h*DH;
  #pragma unroll
  for(int i=0;i<4;i++){
    int d0 = (dchb + i*4)*8;
    unsigned short vv[8];
    *(uint4*)vv = *(const uint4*)(vrow + d0);
    #pragma unroll
    for(int j=0;j<8;j++) T2[d0+j][lane] = vv[j];   // lane-consecutive: conflict-free
  }
  __syncthreads();
  unsigned short* out = Vg + ((size_t)(e*NH+h)*NTILE + t)*8192;
  #pragma unroll
  for(int i=0;i<4;i++){
    int c = i*256 + tid;
    int d = c>>3, ch = c&7;
    *(uint4*)(out + d*64 + ((ch ^ (d&7))<<3)) = *(const uint4*)&T2[d][ch*8];
  }
}

// ---------------- gathered causal flash attention ----------------
__global__ __launch_bounds__(256) void attn_kernel(
    const unsigned short* __restrict__ qb,
    const unsigned short* __restrict__ Kg, const unsigned short* __restrict__ Vg,
    const int* __restrict__ topk_idx, const float* __restrict__ sel_w,
    const float* __restrict__ cosT, const float* __restrict__ sinT,
    unsigned short* __restrict__ oexp){
  __shared__ __align__(16) unsigned short KsA[2][8192];
  __shared__ __align__(16) unsigned short Vs[8192];
  __shared__ __align__(16) unsigned short Ps[4][16][72];
  const int id = blockIdx.x;
  const int xcd = id & 7, s_ = id >> 3;
  const int qt = NTILE - 1 - (s_ % NTILE);          // longest first
  const int grp = (s_ / NTILE)*8 + xcd;             // 0..63
  const int e = grp >> 4, hh = grp & 15;
  const int tid = threadIdx.x, w = tid>>6, lane = tid&63, g = lane>>4, r16 = lane&15;
  const int* idxE = topk_idx + e*CAPN;
  const unsigned short* Kgb = Kg + (size_t)(e*NH+hh)*CAPN*DH;
  const unsigned short* Vgb = Vg + (size_t)(e*NH+hh)*CAPN*DH;

  s16x8 aq[4];
  {
    int qr = qt*64 + w*16 + r16;
    int tok = idxE[qr];
    const unsigned short* qrow = qb + (size_t)tok*QKV_STRIDE + hh*DH;
    const float* cr = cosT + qr*64;
    const float* sr = sinT + qr*64;
    #pragma unroll
    for(int s=0;s<4;s++){
      int d0 = s*32 + 8*g;
      unsigned short held[8], part[8];
      *(uint4*)held = *(const uint4*)(qrow + d0);
      *(uint4*)part = *(const uint4*)(qrow + (d0^64));
      float sgn = (d0<64) ? -1.f : 1.f;
      union{ s16x8 v; unsigned short u[8]; } fr;
      #pragma unroll
      for(int jj=0;jj<8;jj++){
        int dm = (d0+jj)&63;
        float val = bf2f(held[jj])*cr[dm] + sgn*bf2f(part[jj])*sr[dm];
        fr.u[jj] = f2bf(val * (SCALE_QK*LOG2E));
      }
      aq[s] = fr.v;
    }
  }
  float m_r[4], l_r[4];
  f32x4 o[8];
  #pragma unroll
  for(int r=0;r<4;r++){ m_r[r]=-INFINITY; l_r[r]=0.f; }
  #pragma unroll
  for(int f2=0;f2<8;f2++) o[f2]=f32x4{0.f,0.f,0.f,0.f};

  #pragma unroll
  for(int i=0;i<4;i++){ int c=i*256+tid; gl_lds16(Kgb + c*8, &KsA[0][c*8]); }
  #pragma unroll
  for(int i=0;i<4;i++){ int c=i*256+tid; gl_lds16(Vgb + c*8, &Vs[c*8]); }
  __syncthreads();

  for(int kt=0; kt<=qt; kt++){
    const int cur = kt & 1;
    if (kt < qt){
      const unsigned short* Ksrc = Kgb + (size_t)(kt+1)*8192;
      #pragma unroll
      for(int i=0;i<4;i++){ int c=i*256+tid; gl_lds16(Ksrc + c*8, &KsA[cur^1][c*8]); }
    }
    f32x4 sfr[4];
    #pragma unroll
    for(int fc=0;fc<4;fc++){
      f32x4 a4 = f32x4{0.f,0.f,0.f,0.f};
      const int row = fc*16 + r16;
      #pragma unroll
      for(int s=0;s<4;s++){
        s16x8 bk = *(const s16x8*)&KsA[cur][row*128 + (((s*4+g) ^ (r16&7))<<3)];
        a4 = mfma_bf16(aq[s], bk, a4);
      }
      sfr[fc] = a4;
    }
    if (kt==qt){
      #pragma unroll
      for(int fc=0;fc<4;fc++)
        #pragma unroll
        for(int r=0;r<4;r++){
          int qrank  = qt*64 + w*16 + 4*g + r;
          int kvrank = kt*64 + fc*16 + r16;
          if (kvrank > qrank) sfr[fc][r] = NEG_BIG;
        }
    }
    float corr[4];
    bool need = false;
    #pragma unroll
    for(int r=0;r<4;r++){
      float mx = fmaxf(fmaxf(sfr[0][r],sfr[1][r]), fmaxf(sfr[2][r],sfr[3][r]));
      #pragma unroll
      for(int mk=1;mk<16;mk<<=1) mx = fmaxf(mx, __shfl_xor(mx,mk));
      float nm = fmaxf(m_r[r], mx);
      need = need || (nm > m_r[r]);
      corr[r] = exp2f(m_r[r]-nm);
      m_r[r] = nm;
    }
    if (__any(need)){
      #pragma unroll
      for(int f2=0;f2<8;f2++)
        #pragma unroll
        for(int r=0;r<4;r++) o[f2][r] *= corr[r];
      #pragma unroll
      for(int r=0;r<4;r++) l_r[r] *= corr[r];
    }
    float rs[4] = {0.f,0.f,0.f,0.f};
    #pragma unroll
    for(int fc=0;fc<4;fc++)
      #pragma unroll
      for(int r=0;r<4;r++){
        float p = exp2f(sfr[fc][r] - m_r[r]);
        rs[r] += p;
        Ps[w][4*g+r][fc*16+r16] = f2bf(p);
      }
    #pragma unroll
    for(int r=0;r<4;r++){
      float ts = rs[r];
      #pragma unroll
      for(int mk=1;mk<16;mk<<=1) ts += __shfl_xor(ts,mk);
      l_r[r] += ts;
    }
    __syncthreads();
    #pragma unroll
    for(int ks=0;ks<2;ks++){
      s16x8 pa = *(const s16x8*)&Ps[w][r16][ks*32 + 8*g];
      #pragma unroll
      for(int fd=0;fd<8;fd++){
        const int row = fd*16 + r16;
        s16x8 vf = *(const s16x8*)&Vs[row*64 + (((ks*4+g) ^ (r16&7))<<3)];
        o[fd] = mfma_bf16(pa, vf, o[fd]);
      }
    }
    __syncthreads();
    if (kt < qt){
      const unsigned short* Vsrc = Vgb + (size_t)(kt+1)*8192;
      #pragma unroll
      for(int i=0;i<4;i++){ int c=i*256+tid; gl_lds16(Vsrc + c*8, &Vs[c*8]); }
    }
  }
  #pragma unroll
  for(int r=0;r<4;r++){
    int qrank = qt*64 + w*16 + 4*g + r;
    float fac = sel_w[e*CAPN + qrank] / l_r[r];
    #pragma unroll
    for(int fd=0;fd<8;fd++){
      oexp[((size_t)(e*CAPN + qrank))*E_DIM + hh*DH + fd*16 + r16] = f2bf(o[fd][r]*fac);
    }
  }
}

// ---------------- scatter-accumulate over experts ----------------
__global__ __launch_bounds__(256) void acc_kernel(const unsigned short* __restrict__ oexp,
    const int* __restrict__ rank_of, unsigned short* __restrict__ accb){
  int n = blockIdx.x, t = threadIdx.x;
  int base = t*8;
  float s[8] = {0,0,0,0,0,0,0,0};
  #pragma unroll
  for(int e=0;e<4;e++){
    int r = rank_of[e*4096+n];
    if (r>=0){
      union{uint4 q; unsigned short u[8];} ld;
      ld.q = *(const uint4*)(oexp + ((size_t)(e*CAPN+r))*E_DIM + base);
      #pragma unroll
      for(int j2=0;j2<8;j2++) s[j2] += bf2f(ld.u[j2]);
    }
  }
  union{uint4 q; unsigned short u[8];} st;
  #pragma unroll
  for(int j2=0;j2<8;j2++) st.u[j2] = f2bf(s[j2]);
  *(uint4*)(accb + (size_t)n*E_DIM + base) = st.q;
}

// ---------------- launch ----------------
extern "C" void kernel_launch(void* const* d_in, const int* in_sizes, int n_in,
                              void* d_out, int out_size, void* d_ws, size_t ws_size,
                              hipStream_t stream) {
  const float* x   = (const float*)d_in[0];
  const float* Wq  = (const float*)d_in[1];
  const float* Wk  = (const float*)d_in[2];
  const float* Wv  = (const float*)d_in[3];
  const float* Wo  = (const float*)d_in[4];
  const float* Wr1 = (const float*)d_in[5];
  const float* br1 = (const float*)d_in[6];
  const float* Wr2 = (const float*)d_in[7];
  const float* br2 = (const float*)d_in[8];

  char* ws = (char*)d_ws;
  size_t off = 0;
  auto alloc = [&](size_t bytes)->void*{
    void* p = ws + off;
    off += (bytes + 255) & ~(size_t)255;
    return p;
  };
  unsigned short* xhi   = (unsigned short*)alloc((size_t)N_TOK*E_DIM*2);
  unsigned short* xlo   = (unsigned short*)alloc((size_t)N_TOK*E_DIM*2);
  unsigned short* wr1hi = (unsigned short*)alloc((size_t)E_DIM*1024*2);   // transposed [1024][2048]
  unsigned short* wr1lo = (unsigned short*)alloc((size_t)E_DIM*1024*2);
  unsigned short* wqkvT = (unsigned short*)alloc((size_t)3*E_DIM*E_DIM*2); // [6144][2048]
  unsigned short* woT   = (unsigned short*)alloc((size_t)E_DIM*E_DIM*2);
  void* hv = alloc((size_t)KEXP*NH*CAPN*DH*2);   // max(hbuf 16.8MB, Vg 21MB)
  float* hbuf = (float*)hv;                      // dead after scores_kernel
  unsigned short* Vg = (unsigned short*)hv;      // written by prev_kernel later
  float* scores = (float*)alloc((size_t)N_TOK*4*4);
  float* tokmax = (float*)alloc((size_t)N_TOK*4);
  int*   topkI  = (int*)alloc((size_t)KEXP*CAPN*4);
  float* selw   = (float*)alloc((size_t)KEXP*CAPN*4);
  int*   rankof = (int*)alloc((size_t)KEXP*N_TOK*4);
  float* cosT   = (float*)alloc((size_t)CAPN*64*4);
  float* sinT   = (float*)alloc((size_t)CAPN*64*4);
  unsigned short* qkvbuf = (unsigned short*)alloc((size_t)N_TOK*QKV_STRIDE*2);
  unsigned short* oexp = (unsigned short*)alloc((size_t)KEXP*CAPN*E_DIM*2);
  unsigned short* accb = (unsigned short*)alloc((size_t)N_TOK*E_DIM*2);
  if (off > ws_size) return;   // fail loudly (output stays poisoned)

  // Kg (21MB, swizzled) aliases xlo+wr1hi+wr1lo (25.2MB), dead after router GEMM
  unsigned short* Kg = xlo;

  // conversions
  conv_x_kernel<<<(N_TOK*E_DIM/4+255)/256, 256, 0, stream>>>(x, xhi, xlo, N_TOK*E_DIM/4);
  tconv_kernel<<<dim3(1024/32, E_DIM/32), dim3(32,8), 0, stream>>>(Wr1, wr1hi, wr1lo, E_DIM, 1024);
  tconv_kernel<<<dim3(E_DIM/32, E_DIM/32), dim3(32,8), 0, stream>>>(Wq, wqkvT,                nullptr, E_DIM, E_DIM);
  tconv_kernel<<<dim3(E_DIM/32, E_DIM/32), dim3(32,8), 0, stream>>>(Wk, wqkvT +   (size_t)E_DIM*E_DIM, nullptr, E_DIM, E_DIM);
  tconv_kernel<<<dim3(E_DIM/32, E_DIM/32), dim3(32,8), 0, stream>>>(Wv, wqkvT + (size_t)2*E_DIM*E_DIM, nullptr, E_DIM, E_DIM);
  tconv_kernel<<<dim3(E_DIM/32, E_DIM/32), dim3(32,8), 0, stream>>>(Wo, woT, nullptr, E_DIM, E_DIM);

  // fused router: H = gelu(x@Wr1 + br1) (hi/lo split, one pass)
  gemm_router_kernel<<<dim3(8, 32), 256, 0, stream>>>(xhi, xlo, wr1hi, wr1lo, br1, hbuf);
  scores_kernel<<<N_TOK/4, 256, 0, stream>>>(hbuf, Wr2, br2, scores, tokmax);
  aux_kernel<<<1, 1024, 0, stream>>>(tokmax, ((float*)d_out) + (size_t)N_TOK*E_DIM);
  topk_kernel<<<KEXP, 1024, 0, stream>>>(scores, topkI, selw, rankof);
  rope_kernel<<<CAPN*64/256, 256, 0, stream>>>(cosT, sinT);

  // fused QKV projection (bf16): [4096][6144] via 128x256 pipelined GEMM (3.0 full rounds)
  gemm_mn_kernel<1><<<(N_TOK/128)*(QKV_STRIDE/256), 512, 0, stream>>>(xhi, wqkvT, qkvbuf, QKV_STRIDE, E_DIM, QKV_STRIDE/256);

  // pre-gather/rope/transpose K,V into dense swizzled tiles
  prerope_k_kernel<<<KEXP*NH*CAPN*16/256, 256, 0, stream>>>(qkvbuf + E_DIM, topkI, cosT, sinT, Kg);
  prev_kernel<<<KEXP*NH*NTILE, 256, 0, stream>>>(qkvbuf + 2*E_DIM, topkI, Vg);

  // gathered causal attention
  attn_kernel<<<KEXP*NH*NTILE, 256, 0, stream>>>(qkvbuf, Kg, Vg, topkI, selw, cosT, sinT, oexp);

  // scatter-accumulate experts -> token rows
  acc_kernel<<<N_TOK, 256, 0, stream>>>(oexp, rankof, accb);

  // final projection -> d_out (128x256 tiles: 256 blocks = 1.0 full round)
  gemm_mn_kernel<0><<<(N_TOK/128)*(E_DIM/256), 512, 0, stream>>>(accb, woT, (float*)d_out, E_DIM, E_DIM, E_DIM/256);
}

// Round 6
// 504.980 us; speedup vs baseline: 1.1957x; 1.1957x over previous
//
#include <hip/hip_runtime.h>
#include <cstdint>
#include <cstddef>

// Problem constants
#define N_TOK 4096
#define E_DIM 2048
#define NH    16
#define DH    128
#define KEXP  4
#define CAPN  1280
#define NTILE 20                 // CAPN/64
#define QKV_STRIDE 6144          // fused QKV output row stride
#define SCALE_QK 0.08838834764831845f
#define LOG2E    1.4426950408889634f
#define NEG_BIG -1e30f

typedef __attribute__((ext_vector_type(4))) float f32x4;
typedef __attribute__((ext_vector_type(8))) short s16x8;

__device__ __forceinline__ float bf2f(unsigned short u){
  union{unsigned int i; float fl;} c; c.i = ((unsigned int)u)<<16; return c.fl;
}
__device__ __forceinline__ unsigned short f2bf(float x){
  union{float fl; unsigned int i;} c; c.fl=x;
  return (unsigned short)((c.i + 0x7FFFu + ((c.i>>16)&1u))>>16);
}
__device__ __forceinline__ f32x4 mfma_bf16(s16x8 a, s16x8 b, f32x4 c){
  asm("v_mfma_f32_16x16x32_bf16 %0, %1, %2, %0" : "+v"(c) : "v"(a), "v"(b));
  return c;
}
// async global->LDS 16B: LDS dest must be lane-linear (base + lane*16)
__device__ __forceinline__ void gl_lds16(const unsigned short* g, unsigned short* l){
  __builtin_amdgcn_global_load_lds(
      (const __attribute__((address_space(1))) unsigned int*)g,
      (__attribute__((address_space(3))) unsigned int*)l, 16, 0, 0);
}
// raw barrier: no vmcnt/lgkmcnt drain; memory clobber stops LDS-op reordering across it
#define BARRIER() asm volatile("s_barrier" ::: "memory")

// ---------------- conversions ----------------
__global__ __launch_bounds__(256) void conv_x_kernel(const float* __restrict__ x,
    unsigned short* __restrict__ hi, unsigned short* __restrict__ lo, int n4){
  int idx = blockIdx.x*256 + threadIdx.x;
  if (idx >= n4) return;
  float4 v = ((const float4*)x)[idx];
  float ar[4] = {v.x, v.y, v.z, v.w};
  union{ unsigned short u[4]; uint2 q; } H, L;
  #pragma unroll
  for(int i=0;i<4;i++){
    unsigned short h = f2bf(ar[i]);
    H.u[i] = h;
    L.u[i] = f2bf(ar[i] - bf2f(h));
  }
  ((uint2*)hi)[idx] = H.q;
  ((uint2*)lo)[idx] = L.q;
}

// transpose + f32->bf16 (optionally also lo residual). W[R][C] -> T[C][R]
__global__ __launch_bounds__(256) void tconv_kernel(const float* __restrict__ W,
    unsigned short* __restrict__ Thi, unsigned short* __restrict__ Tlo, int R, int C){
  __shared__ float t[32][33];
  int tx = threadIdx.x, ty = threadIdx.y;   // (32,8)
  int c0 = blockIdx.x*32, r0 = blockIdx.y*32;
  #pragma unroll
  for(int i=0;i<4;i++){
    int r = r0 + ty + i*8;
    t[ty+i*8][tx] = W[(size_t)r*C + c0 + tx];
  }
  __syncthreads();
  #pragma unroll
  for(int i=0;i<4;i++){
    int c = c0 + ty + i*8;
    float v = t[tx][ty+i*8];
    size_t o = (size_t)c*R + r0 + tx;
    unsigned short h = f2bf(v);
    Thi[o] = h;
    if (Tlo) Tlo[o] = f2bf(v - bf2f(h));
  }
}

// fused transpose of 4 ExE weights (Wq,Wk,Wv,Wo) -> contiguous [4][E][E] bf16
__global__ __launch_bounds__(256) void tconv4_kernel(const float* __restrict__ W0,
    const float* __restrict__ W1, const float* __restrict__ W2, const float* __restrict__ W3,
    unsigned short* __restrict__ out){
  __shared__ float t[32][33];
  int z = blockIdx.z;
  const float* W = (z==0)?W0 : (z==1)?W1 : (z==2)?W2 : W3;
  unsigned short* T = out + (size_t)z*E_DIM*E_DIM;
  int tx = threadIdx.x, ty = threadIdx.y;   // (32,8)
  int c0 = blockIdx.x*32, r0 = blockIdx.y*32;
  #pragma unroll
  for(int i=0;i<4;i++){
    int r = r0 + ty + i*8;
    t[ty+i*8][tx] = W[(size_t)r*E_DIM + c0 + tx];
  }
  __syncthreads();
  #pragma unroll
  for(int i=0;i<4;i++){
    int c = c0 + ty + i*8;
    T[(size_t)c*E_DIM + r0 + tx] = f2bf(t[tx][ty+i*8]);
  }
}

// ---------------- bf16 MFMA GEMM (m97 structure): C[M][N] = A[M][K] * Bt[N][K]^T
template<int ACCUM, int OUTBF>
__global__ __launch_bounds__(256) void gemm_kernel(const unsigned short* __restrict__ A,
    const unsigned short* __restrict__ Bt, void* __restrict__ Cp, int N, int Kd){
  __shared__ __align__(16) unsigned short As[128][64];
  __shared__ __align__(16) unsigned short Bs[128][64];
  const int mb = blockIdx.y, nb = blockIdx.x;
  const int tid = threadIdx.x;
  const int lane = tid & 63, w = tid >> 6;
  const int g = lane >> 4, r16 = lane & 15;
  const int wm = w >> 1, wn = w & 1;
  f32x4 acc[4][4];
  #pragma unroll
  for(int i=0;i<4;i++)
    #pragma unroll
    for(int j=0;j<4;j++) acc[i][j] = f32x4{0.f,0.f,0.f,0.f};
  const unsigned short* Ab = A  + (size_t)mb*128*Kd;
  const unsigned short* Bb = Bt + (size_t)nb*128*Kd;
  const int srow = tid >> 3, sc8 = (tid & 7) * 8;   // linear LDS: byte off = tid*16
  for(int k0=0;k0<Kd;k0+=64){
    __syncthreads();
    #pragma unroll
    for(int i=0;i<4;i++)
      gl_lds16(Ab + (size_t)(srow + i*32)*Kd + k0 + sc8, &As[srow + i*32][sc8]);
    #pragma unroll
    for(int i=0;i<4;i++)
      gl_lds16(Bb + (size_t)(srow + i*32)*Kd + k0 + sc8, &Bs[srow + i*32][sc8]);
    __syncthreads();
    #pragma unroll
    for(int ks=0;ks<2;ks++){
      s16x8 af[4], bfr[4];
      #pragma unroll
      for(int f2=0;f2<4;f2++){
        af[f2]  = *(const s16x8*)&As[wm*64 + f2*16 + r16][ks*32 + 8*g];
        bfr[f2] = *(const s16x8*)&Bs[wn*64 + f2*16 + r16][ks*32 + 8*g];
      }
      #pragma unroll
      for(int fm=0;fm<4;fm++)
        #pragma unroll
        for(int fn=0;fn<4;fn++)
          acc[fm][fn] = mfma_bf16(af[fm], bfr[fn], acc[fm][fn]);
    }
  }
  const int rowb = mb*128 + wm*64, colb = nb*128 + wn*64;
  #pragma unroll
  for(int fm=0;fm<4;fm++)
    #pragma unroll
    for(int fn=0;fn<4;fn++)
      #pragma unroll
      for(int r=0;r<4;r++){
        int rr = rowb + fm*16 + 4*g + r;
        int cc = colb + fn*16 + r16;
        size_t o = (size_t)rr*N + cc;
        float v = acc[fm][fn][r];
        if (OUTBF)        ((unsigned short*)Cp)[o] = f2bf(v);
        else if (ACCUM)   ((float*)Cp)[o] += v;
        else              ((float*)Cp)[o] = v;
      }
}

// ============ 256x256 BK=64 8-wave 4-phase pipelined GEMM (m201-style) ============
// 8 waves 2Mx4N, wave tile 128x64. LDS 128KB: [buf][unit][8192] shorts,
// units: 0=A-ks0 [256][32], 1=A-ks1, 2=B-ks0, 3=B-ks1 (16KB each, 2 loads/thread).
// Phases per K-tile: p1(ks0,col-lo) p2(ks0,col-hi) p3(ks1,col-lo) p4(ks1,col-hi).
// Stage stream: p1: A-ks1(t+1)->nxt, p2: B-ks1(t+1)->nxt, p3: A-ks0(t+2)->cur
// (A-ks0 dead after p1), p4: B-ks0(t+2)->cur (dead after p2). vmcnt(8) at p2/p4:
// completes exactly the 2 units needed 2 phases later; queue never drains.
// Swizzle: LDS(row,ch) = G(row, ch ^ ((row>>1)&3)); read chunk g^((r16>>1)&3)
// -> 8 words/bank exactly (balanced, no excess conflicts).
template<int OUTBF>
__global__ __launch_bounds__(512, 2) void gemm256_8p(
    const unsigned short* __restrict__ A, const unsigned short* __restrict__ Bt,
    void* __restrict__ Cp, int N, int Kd){
  __shared__ __align__(16) unsigned short lds[2][4][8192];
  const int tid = threadIdx.x;
  const int w = tid>>6, lane = tid&63, g = lane>>4, r16 = lane&15;
  const int wm = w>>2, wn = w&3;                      // 2 x 4 waves
  const int mb = blockIdx.y, nb = blockIdx.x;
  const unsigned short* Ab = A  + (size_t)mb*256*Kd;
  const unsigned short* Bb = Bt + (size_t)nb*256*Kd;
  const int NT = Kd >> 6;

  f32x4 acc[8][4];
  #pragma unroll
  for(int i=0;i<8;i++)
    #pragma unroll
    for(int j=0;j<4;j++) acc[i][j] = f32x4{0.f,0.f,0.f,0.f};

  auto stage = [&](int buf, int unit, int t){
    const unsigned short* base = (unit < 2) ? Ab : Bb;
    const int ks = unit & 1;
    #pragma unroll
    for(int i=0;i<2;i++){
      int n = i*512 + tid;                 // 1024 chunks of 16B
      int row = n>>2, ch = n&3;
      int sc = ch ^ ((row>>1)&3);
      gl_lds16(base + (size_t)row*Kd + t*64 + ks*32 + sc*8, &lds[buf][unit][n*8]);
    }
  };
  const int xr = (r16>>1)&3;
  const int aoff = (g ^ xr) << 3;          // element offset of swizzled chunk

  // prologue: tile0 all 4 units -> buf0; tile1 ks0 units -> buf1; keep 8 in flight
  stage(0,0,0); stage(0,2,0); stage(0,1,0); stage(0,3,0);
  stage(1,0,1); stage(1,2,1);
  asm volatile("s_waitcnt vmcnt(8)" ::: "memory");
  BARRIER();

  int cur = 0;
  for(int t=0; t<NT; ++t){
    const int nxt = cur^1;
    s16x8 afr[8], bfr[2];
    // ---- p1: ks0 x col-lo ----
    #pragma unroll
    for(int mf=0;mf<8;mf++)
      afr[mf] = *(const s16x8*)&lds[cur][0][(wm*128 + mf*16 + r16)*32 + aoff];
    #pragma unroll
    for(int c=0;c<2;c++)
      bfr[c] = *(const s16x8*)&lds[cur][2][(wn*64 + c*16 + r16)*32 + aoff];
    if (t+1 < NT) stage(nxt, 1, t+1);
    BARRIER();
    __builtin_amdgcn_s_setprio(1);
    #pragma unroll
    for(int mf=0;mf<8;mf++){
      acc[mf][0] = mfma_bf16(afr[mf], bfr[0], acc[mf][0]);
      acc[mf][1] = mfma_bf16(afr[mf], bfr[1], acc[mf][1]);
    }
    __builtin_amdgcn_s_setprio(0);
    BARRIER();
    // ---- p2: ks0 x col-hi ----
    #pragma unroll
    for(int c=0;c<2;c++)
      bfr[c] = *(const s16x8*)&lds[cur][2][(wn*64 + 32 + c*16 + r16)*32 + aoff];
    if (t+1 < NT){ stage(nxt, 3, t+1); asm volatile("s_waitcnt vmcnt(8)" ::: "memory"); }
    else         {                     asm volatile("s_waitcnt vmcnt(0)" ::: "memory"); }
    BARRIER();
    __builtin_amdgcn_s_setprio(1);
    #pragma unroll
    for(int mf=0;mf<8;mf++){
      acc[mf][2] = mfma_bf16(afr[mf], bfr[0], acc[mf][2]);
      acc[mf][3] = mfma_bf16(afr[mf], bfr[1], acc[mf][3]);
    }
    __builtin_amdgcn_s_setprio(0);
    BARRIER();
    // ---- p3: ks1 x col-lo ----
    #pragma unroll
    for(int mf=0;mf<8;mf++)
      afr[mf] = *(const s16x8*)&lds[cur][1][(wm*128 + mf*16 + r16)*32 + aoff];
    #pragma unroll
    for(int c=0;c<2;c++)
      bfr[c] = *(const s16x8*)&lds[cur][3][(wn*64 + c*16 + r16)*32 + aoff];
    if (t+2 < NT) stage(cur, 0, t+2);
    BARRIER();
    __builtin_amdgcn_s_setprio(1);
    #pragma unroll
    for(int mf=0;mf<8;mf++){
      acc[mf][0] = mfma_bf16(afr[mf], bfr[0], acc[mf][0]);
      acc[mf][1] = mfma_bf16(afr[mf], bfr[1], acc[mf][1]);
    }
    __builtin_amdgcn_s_setprio(0);
    BARRIER();
    // ---- p4: ks1 x col-hi ----
    #pragma unroll
    for(int c=0;c<2;c++)
      bfr[c] = *(const s16x8*)&lds[cur][3][(wn*64 + 32 + c*16 + r16)*32 + aoff];
    if (t+2 < NT){ stage(cur, 2, t+2); asm volatile("s_waitcnt vmcnt(8)" ::: "memory"); }
    else if (t+1 < NT){               asm volatile("s_waitcnt vmcnt(4)" ::: "memory"); }
    else              {               asm volatile("s_waitcnt vmcnt(0)" ::: "memory"); }
    BARRIER();
    __builtin_amdgcn_s_setprio(1);
    #pragma unroll
    for(int mf=0;mf<8;mf++){
      acc[mf][2] = mfma_bf16(afr[mf], bfr[0], acc[mf][2]);
      acc[mf][3] = mfma_bf16(afr[mf], bfr[1], acc[mf][3]);
    }
    __builtin_amdgcn_s_setprio(0);
    BARRIER();
    cur ^= 1;
  }

  const int rowb = mb*256 + wm*128, colb = nb*256 + wn*64;
  #pragma unroll
  for(int mf=0;mf<8;mf++)
    #pragma unroll
    for(int c=0;c<4;c++)
      #pragma unroll
      for(int r=0;r<4;r++){
        int rr = rowb + mf*16 + 4*g + r;
        int cc = colb + (c>>1)*32 + (c&1)*16 + r16;
        size_t o = (size_t)rr*N + cc;
        if (OUTBF) ((unsigned short*)Cp)[o] = f2bf(acc[mf][c][r]);
        else       ((float*)Cp)[o] = acc[mf][c][r];
      }
}

// ---------------- fused router GEMM: H = gelu(x@Wr1 + br1) via hi/lo split ----------------
__global__ __launch_bounds__(256) void gemm_router_kernel(
    const unsigned short* __restrict__ Ahi, const unsigned short* __restrict__ Alo,
    const unsigned short* __restrict__ Bhi, const unsigned short* __restrict__ Blo,
    const float* __restrict__ br1, float* __restrict__ H){
  __shared__ __align__(16) unsigned short AsH[128*32];
  __shared__ __align__(16) unsigned short AsL[128*32];
  __shared__ __align__(16) unsigned short BsH[128*32];
  __shared__ __align__(16) unsigned short BsL[128*32];
  const int mb = blockIdx.y, nb = blockIdx.x;
  const int tid = threadIdx.x;
  const int lane = tid & 63, w = tid >> 6;
  const int g = lane >> 4, r16 = lane & 15;
  const int wm = w >> 1, wn = w & 1;
  f32x4 acc[4][4];
  #pragma unroll
  for(int i=0;i<4;i++)
    #pragma unroll
    for(int j=0;j<4;j++) acc[i][j] = f32x4{0.f,0.f,0.f,0.f};
  const unsigned short* AbH = Ahi + (size_t)mb*128*E_DIM;
  const unsigned short* AbL = Alo + (size_t)mb*128*E_DIM;
  const unsigned short* BbH = Bhi + (size_t)nb*128*E_DIM;
  const unsigned short* BbL = Blo + (size_t)nb*128*E_DIM;
  const int xr2 = (r16>>1)&3;
  for(int k0=0;k0<E_DIM;k0+=32){
    __syncthreads();
    #pragma unroll
    for(int i=0;i<2;i++){
      int c = i*256 + tid;
      int row = c>>2;
      int sc = ((c&3) ^ ((row>>1)&3))*8;   // pre-swizzled source
      size_t go = (size_t)row*E_DIM + k0 + sc;
      gl_lds16(AbH + go, &AsH[c*8]);
      gl_lds16(AbL + go, &AsL[c*8]);
      gl_lds16(BbH + go, &BsH[c*8]);
      gl_lds16(BbL + go, &BsL[c*8]);
    }
    __syncthreads();
    s16x8 ah[4], al[4], bh[4], bl[4];
    #pragma unroll
    for(int f2=0;f2<4;f2++){
      int ra = (wm*64 + f2*16 + r16)*32 + 8*(g ^ xr2);
      int rb = (wn*64 + f2*16 + r16)*32 + 8*(g ^ xr2);
      ah[f2] = *(const s16x8*)&AsH[ra];
      al[f2] = *(const s16x8*)&AsL[ra];
      bh[f2] = *(const s16x8*)&BsH[rb];
      bl[f2] = *(const s16x8*)&BsL[rb];
    }
    #pragma unroll
    for(int fm=0;fm<4;fm++)
      #pragma unroll
      for(int fn=0;fn<4;fn++){
        acc[fm][fn] = mfma_bf16(ah[fm], bh[fn], acc[fm][fn]);
        acc[fm][fn] = mfma_bf16(ah[fm], bl[fn], acc[fm][fn]);
        acc[fm][fn] = mfma_bf16(al[fm], bh[fn], acc[fm][fn]);
      }
  }
  const int rowb = mb*128 + wm*64, colb = nb*128 + wn*64;
  #pragma unroll
  for(int fm=0;fm<4;fm++)
    #pragma unroll
    for(int fn=0;fn<4;fn++)
      #pragma unroll
      for(int r=0;r<4;r++){
        int rr = rowb + fm*16 + 4*g + r;
        int cc = colb + fn*16 + r16;
        float v = acc[fm][fn][r] + br1[cc];
        H[(size_t)rr*1024 + cc] = 0.5f*v*(1.0f + erff(v*0.70710678118654752f));
      }
}

// ---------------- router scores ----------------
__global__ __launch_bounds__(256) void scores_kernel(const float* __restrict__ h,
    const float* __restrict__ Wr2, const float* __restrict__ br2,
    float* __restrict__ scores, float* __restrict__ tokmax){
  int tid = threadIdx.x;
  int n = blockIdx.x*4 + (tid>>6);
  int lane = tid & 63;
  const float* hr = h + (size_t)n*1024;
  float s0=0,s1=0,s2=0,s3=0;
  #pragma unroll
  for(int i=0;i<16;i++){
    int j = lane + i*64;
    float hv = hr[j];
    float4 wv = *(const float4*)(Wr2 + (size_t)j*4);
    s0 += hv*wv.x; s1 += hv*wv.y; s2 += hv*wv.z; s3 += hv*wv.w;
  }
  #pragma unroll
  for(int m=32;m>=1;m>>=1){
    s0 += __shfl_xor(s0,m); s1 += __shfl_xor(s1,m);
    s2 += __shfl_xor(s2,m); s3 += __shfl_xor(s3,m);
  }
  if (lane==0){
    s0+=br2[0]; s1+=br2[1]; s2+=br2[2]; s3+=br2[3];
    scores[n*4+0]=s0; scores[n*4+1]=s1; scores[n*4+2]=s2; scores[n*4+3]=s3;
    tokmax[n]=fmaxf(fmaxf(s0,s1),fmaxf(s2,s3));
  }
}

__global__ __launch_bounds__(1024) void aux_kernel(const float* __restrict__ tokmax, float* __restrict__ out_aux){
  __shared__ float red[1024];
  int t = threadIdx.x;
  red[t] = tokmax[t] + tokmax[t+1024] + tokmax[t+2048] + tokmax[t+3072];
  __syncthreads();
  for(int k=512;k>=1;k>>=1){ if(t<k) red[t]+=red[t+k]; __syncthreads(); }
  if (t==0) out_aux[0] = -red[0]/4096.0f;
}

// ---------------- exact top-k (bitonic sort of 4096 per expert) ----------------
__global__ __launch_bounds__(1024) void topk_kernel(const float* __restrict__ scores,
    int* __restrict__ topk_idx, float* __restrict__ sel_w, int* __restrict__ rank_of){
  __shared__ float sv[4096];
  __shared__ int   si[4096];
  __shared__ float red[1024];
  int e = blockIdx.x, t = threadIdx.x;
  for(int i=t;i<4096;i+=1024){ sv[i]=scores[i*4+e]; si[i]=i; }
  __syncthreads();
  for(int k=2;k<=4096;k<<=1){
    for(int j=k>>1;j>0;j>>=1){
      for(int i=t;i<4096;i+=1024){
        int ixj = i^j;
        if (ixj>i){
          float vi=sv[i], vj=sv[ixj];
          int ii=si[i], ij=si[ixj];
          bool jGreater = (vj>vi) || (vj==vi && ij<ii);
          bool asc = (i&k)==0;
          if (asc ? jGreater : !jGreater){
            sv[i]=vj; sv[ixj]=vi; si[i]=ij; si[ixj]=ii;
          }
        }
      }
      __syncthreads();
    }
  }
  for(int i=t;i<4096;i+=1024) rank_of[e*4096+i] = -1;
  __syncthreads();
  for(int r=t;r<CAPN;r+=1024){
    int tok = si[r];
    topk_idx[e*CAPN+r] = tok;
    rank_of[e*4096+tok] = r;
  }
  float mx = sv[0];
  float part = 0.f;
  for(int r=t;r<CAPN;r+=1024) part += expf(sv[r]-mx);
  red[t]=part; __syncthreads();
  for(int k=512;k>=1;k>>=1){ if(t<k) red[t]+=red[t+k]; __syncthreads(); }
  float denom = red[0];
  for(int r=t;r<CAPN;r+=1024) sel_w[e*CAPN+r] = expf(sv[r]-mx)/denom;
}

// ---------------- RoPE tables [CAPN][64] ----------------
__global__ __launch_bounds__(256) void rope_kernel(float* __restrict__ cosT, float* __restrict__ sinT){
  int idx = blockIdx.x*256 + threadIdx.x;
  int p = idx>>6, dm = idx&63;
  float inv = powf(10000.0f, -(float)dm/64.0f);
  float ang = (float)p*inv;
  cosT[idx]=cosf(ang);
  sinT[idx]=sinf(ang);
}

// ---------------- pre-gather + pre-rope K into swizzled tiles ----------------
__global__ __launch_bounds__(256) void prerope_k_kernel(const unsigned short* __restrict__ kb,
    const int* __restrict__ topk_idx, const float* __restrict__ cosT, const float* __restrict__ sinT,
    unsigned short* __restrict__ Kg){
  int idx = blockIdx.x*256 + threadIdx.x;   // exact 4*16*1280*16
  int ch = idx & 15;
  int rest = idx >> 4;
  int rank = rest % CAPN;
  int he = rest / CAPN;           // e*16+h
  int e = he >> 4, h = he & 15;
  int tok = topk_idx[e*CAPN + rank];
  int d0 = ch*8;
  const unsigned short* krow = kb + (size_t)tok*QKV_STRIDE + h*DH;
  unsigned short held[8], part[8];
  *(uint4*)held = *(const uint4*)(krow + d0);
  *(uint4*)part = *(const uint4*)(krow + (d0^64));
  const float* cr = cosT + rank*64;
  const float* sr = sinT + rank*64;
  float sgn = (d0<64) ? -1.f : 1.f;
  unsigned short outv[8];
  #pragma unroll
  for(int jj=0;jj<8;jj++){
    int dm = (d0+jj)&63;
    outv[jj] = f2bf(bf2f(held[jj])*cr[dm] + sgn*bf2f(part[jj])*sr[dm]);
  }
  int t = rank >> 6, row = rank & 63;
  size_t tbase = ((size_t)(he)*NTILE + t) * 8192;
  *(uint4*)(Kg + tbase + row*128 + ((ch ^ (row&7))<<3)) = *(uint4*)outv;
}

// ---------------- pre-gather + transpose V into swizzled tiles ----------------
__global__ __launch_bounds__(256) void prev_kernel(const unsigned short* __restrict__ vb,
    const int* __restrict__ topk_idx, unsigned short* __restrict__ Vg){
  __shared__ __align__(16) unsigned short T2[128][72];
  int bid = blockIdx.x;           // e*320 + h*20 + t
  int t = bid % NTILE, h = (bid/NTILE) & 15, e = bid/(NTILE*NH);
  int tid = threadIdx.x, lane = tid & 63, dchb = tid >> 6;
  int tok = topk_idx[e*CAPN + t*64 + lane];
  const unsigned short* vrow = vb + (size_t)tok*QKV_STRIDE + h*DH;
  #pragma unroll
  for(int i=0;i<4;i++){
    int d0 = (dchb + i*4)*8;
    unsigned short vv[8];
    *(uint4*)vv = *(const uint4*)(vrow + d0);
    #pragma unroll
    for(int j=0;j<8;j++) T2[d0+j][lane] = vv[j];   // lane-consecutive: conflict-free
  }
  __syncthreads();
  unsigned short* out = Vg + ((size_t)(e*NH+h)*NTILE + t)*8192;
  #pragma unroll
  for(int i=0;i<4;i++){
    int c = i*256 + tid;
    int d = c>>3, ch = c&7;
    *(uint4*)(out + d*64 + ((ch ^ (d&7))<<3)) = *(const uint4*)&T2[d][ch*8];
  }
}

// ---------------- gathered causal flash attention ----------------
__global__ __launch_bounds__(256) void attn_kernel(
    const unsigned short* __restrict__ qb,
    const unsigned short* __restrict__ Kg, const unsigned short* __restrict__ Vg,
    const int* __restrict__ topk_idx, const float* __restrict__ sel_w,
    const float* __restrict__ cosT, const float* __restrict__ sinT,
    unsigned short* __restrict__ oexp){
  __shared__ __align__(16) unsigned short KsA[2][8192];
  __shared__ __align__(16) unsigned short Vs[8192];
  __shared__ __align__(16) unsigned short Ps[4][16][72];
  const int id = blockIdx.x;
  const int xcd = id & 7, s_ = id >> 3;
  const int qt = NTILE - 1 - (s_ % NTILE);          // longest first
  const int grp = (s_ / NTILE)*8 + xcd;             // 0..63
  const int e = grp >> 4, hh = grp & 15;
  const int tid = threadIdx.x, w = tid>>6, lane = tid&63, g = lane>>4, r16 = lane&15;
  const int* idxE = topk_idx + e*CAPN;
  const unsigned short* Kgb = Kg + (size_t)(e*NH+hh)*CAPN*DH;
  const unsigned short* Vgb = Vg + (size_t)(e*NH+hh)*CAPN*DH;

  s16x8 aq[4];
  {
    int qr = qt*64 + w*16 + r16;
    int tok = idxE[qr];
    const unsigned short* qrow = qb + (size_t)tok*QKV_STRIDE + hh*DH;
    const float* cr = cosT + qr*64;
    const float* sr = sinT + qr*64;
    #pragma unroll
    for(int s=0;s<4;s++){
      int d0 = s*32 + 8*g;
      unsigned short held[8], part[8];
      *(uint4*)held = *(const uint4*)(qrow + d0);
      *(uint4*)part = *(const uint4*)(qrow + (d0^64));
      float sgn = (d0<64) ? -1.f : 1.f;
      union{ s16x8 v; unsigned short u[8]; } fr;
      #pragma unroll
      for(int jj=0;jj<8;jj++){
        int dm = (d0+jj)&63;
        float val = bf2f(held[jj])*cr[dm] + sgn*bf2f(part[jj])*sr[dm];
        fr.u[jj] = f2bf(val * (SCALE_QK*LOG2E));
      }
      aq[s] = fr.v;
    }
  }
  float m_r[4], l_r[4];
  f32x4 o[8];
  #pragma unroll
  for(int r=0;r<4;r++){ m_r[r]=-INFINITY; l_r[r]=0.f; }
  #pragma unroll
  for(int f2=0;f2<8;f2++) o[f2]=f32x4{0.f,0.f,0.f,0.f};

  #pragma unroll
  for(int i=0;i<4;i++){ int c=i*256+tid; gl_lds16(Kgb + c*8, &KsA[0][c*8]); }
  #pragma unroll
  for(int i=0;i<4;i++){ int c=i*256+tid; gl_lds16(Vgb + c*8, &Vs[c*8]); }
  __syncthreads();

  for(int kt=0; kt<=qt; kt++){
    const int cur = kt & 1;
    if (kt < qt){
      const unsigned short* Ksrc = Kgb + (size_t)(kt+1)*8192;
      #pragma unroll
      for(int i=0;i<4;i++){ int c=i*256+tid; gl_lds16(Ksrc + c*8, &KsA[cur^1][c*8]); }
    }
    f32x4 sfr[4];
    #pragma unroll
    for(int fc=0;fc<4;fc++){
      f32x4 a4 = f32x4{0.f,0.f,0.f,0.f};
      const int row = fc*16 + r16;
      #pragma unroll
      for(int s=0;s<4;s++){
        s16x8 bk = *(const s16x8*)&KsA[cur][row*128 + (((s*4+g) ^ (r16&7))<<3)];
        a4 = mfma_bf16(aq[s], bk, a4);
      }
      sfr[fc] = a4;
    }
    if (kt==qt){
      #pragma unroll
      for(int fc=0;fc<4;fc++)
        #pragma unroll
        for(int r=0;r<4;r++){
          int qrank  = qt*64 + w*16 + 4*g + r;
          int kvrank = kt*64 + fc*16 + r16;
          if (kvrank > qrank) sfr[fc][r] = NEG_BIG;
        }
    }
    float corr[4];
    bool need = false;
    #pragma unroll
    for(int r=0;r<4;r++){
      float mx = fmaxf(fmaxf(sfr[0][r],sfr[1][r]), fmaxf(sfr[2][r],sfr[3][r]));
      #pragma unroll
      for(int mk=1;mk<16;mk<<=1) mx = fmaxf(mx, __shfl_xor(mx,mk));
      float nm = fmaxf(m_r[r], mx);
      need = need || (nm > m_r[r]);
      corr[r] = exp2f(m_r[r]-nm);
      m_r[r] = nm;
    }
    if (__any(need)){
      #pragma unroll
      for(int f2=0;f2<8;f2++)
        #pragma unroll
        for(int r=0;r<4;r++) o[f2][r] *= corr[r];
      #pragma unroll
      for(int r=0;r<4;r++) l_r[r] *= corr[r];
    }
    float rs[4] = {0.f,0.f,0.f,0.f};
    #pragma unroll
    for(int fc=0;fc<4;fc++)
      #pragma unroll
      for(int r=0;r<4;r++){
        float p = exp2f(sfr[fc][r] - m_r[r]);
        rs[r] += p;
        Ps[w][4*g+r][fc*16+r16] = f2bf(p);
      }
    #pragma unroll
    for(int r=0;r<4;r++){
      float ts = rs[r];
      #pragma unroll
      for(int mk=1;mk<16;mk<<=1) ts += __shfl_xor(ts,mk);
      l_r[r] += ts;
    }
    __syncthreads();
    #pragma unroll
    for(int ks=0;ks<2;ks++){
      s16x8 pa = *(const s16x8*)&Ps[w][r16][ks*32 + 8*g];
      #pragma unroll
      for(int fd=0;fd<8;fd++){
        const int row = fd*16 + r16;
        s16x8 vf = *(const s16x8*)&Vs[row*64 + (((ks*4+g) ^ (r16&7))<<3)];
        o[fd] = mfma_bf16(pa, vf, o[fd]);
      }
    }
    __syncthreads();
    if (kt < qt){
      const unsigned short* Vsrc = Vgb + (size_t)(kt+1)*8192;
      #pragma unroll
      for(int i=0;i<4;i++){ int c=i*256+tid; gl_lds16(Vsrc + c*8, &Vs[c*8]); }
    }
  }
  #pragma unroll
  for(int r=0;r<4;r++){
    int qrank = qt*64 + w*16 + 4*g + r;
    float fac = sel_w[e*CAPN + qrank] / l_r[r];
    #pragma unroll
    for(int fd=0;fd<8;fd++){
      oexp[((size_t)(e*CAPN + qrank))*E_DIM + hh*DH + fd*16 + r16] = f2bf(o[fd][r]*fac);
    }
  }
}

// ---------------- scatter-accumulate over experts ----------------
__global__ __launch_bounds__(256) void acc_kernel(const unsigned short* __restrict__ oexp,
    const int* __restrict__ rank_of, unsigned short* __restrict__ accb){
  int n = blockIdx.x, t = threadIdx.x;
  int base = t*8;
  float s[8] = {0,0,0,0,0,0,0,0};
  #pragma unroll
  for(int e=0;e<4;e++){
    int r = rank_of[e*4096+n];
    if (r>=0){
      union{uint4 q; unsigned short u[8];} ld;
      ld.q = *(const uint4*)(oexp + ((size_t)(e*CAPN+r))*E_DIM + base);
      #pragma unroll
      for(int j2=0;j2<8;j2++) s[j2] += bf2f(ld.u[j2]);
    }
  }
  union{uint4 q; unsigned short u[8];} st;
  #pragma unroll
  for(int j2=0;j2<8;j2++) st.u[j2] = f2bf(s[j2]);
  *(uint4*)(accb + (size_t)n*E_DIM + base) = st.q;
}

// ---------------- launch ----------------
extern "C" void kernel_launch(void* const* d_in, const int* in_sizes, int n_in,
                              void* d_out, int out_size, void* d_ws, size_t ws_size,
                              hipStream_t stream) {
  const float* x   = (const float*)d_in[0];
  const float* Wq  = (const float*)d_in[1];
  const float* Wk  = (const float*)d_in[2];
  const float* Wv  = (const float*)d_in[3];
  const float* Wo  = (const float*)d_in[4];
  const float* Wr1 = (const float*)d_in[5];
  const float* br1 = (const float*)d_in[6];
  const float* Wr2 = (const float*)d_in[7];
  const float* br2 = (const float*)d_in[8];

  char* ws = (char*)d_ws;
  size_t off = 0;
  auto alloc = [&](size_t bytes)->void*{
    void* p = ws + off;
    off += (bytes + 255) & ~(size_t)255;
    return p;
  };
  unsigned short* xhi   = (unsigned short*)alloc((size_t)N_TOK*E_DIM*2);
  unsigned short* xlo   = (unsigned short*)alloc((size_t)N_TOK*E_DIM*2);
  unsigned short* wr1hi = (unsigned short*)alloc((size_t)E_DIM*1024*2);   // transposed [1024][2048]
  unsigned short* wr1lo = (unsigned short*)alloc((size_t)E_DIM*1024*2);
  unsigned short* wqkvT = (unsigned short*)alloc((size_t)3*E_DIM*E_DIM*2); // [6144][2048]
  unsigned short* woT   = (unsigned short*)alloc((size_t)E_DIM*E_DIM*2);   // contiguous after wqkvT
  void* hv = alloc((size_t)KEXP*NH*CAPN*DH*2);   // max(hbuf 16.8MB, Vg 21MB)
  float* hbuf = (float*)hv;                      // dead after scores_kernel
  unsigned short* Vg = (unsigned short*)hv;      // written by prev_kernel later
  float* scores = (float*)alloc((size_t)N_TOK*4*4);
  float* tokmax = (float*)alloc((size_t)N_TOK*4);
  int*   topkI  = (int*)alloc((size_t)KEXP*CAPN*4);
  float* selw   = (float*)alloc((size_t)KEXP*CAPN*4);
  int*   rankof = (int*)alloc((size_t)KEXP*N_TOK*4);
  float* cosT   = (float*)alloc((size_t)CAPN*64*4);
  float* sinT   = (float*)alloc((size_t)CAPN*64*4);
  unsigned short* qkvbuf = (unsigned short*)alloc((size_t)N_TOK*QKV_STRIDE*2);
  unsigned short* oexp = (unsigned short*)alloc((size_t)KEXP*CAPN*E_DIM*2);
  unsigned short* accb = (unsigned short*)alloc((size_t)N_TOK*E_DIM*2);
  if (off > ws_size) return;   // fail loudly (output stays poisoned)

  // Kg (21MB, swizzled) aliases xlo+wr1hi+wr1lo (25.2MB), dead after router GEMM
  unsigned short* Kg = xlo;

  // conversions
  conv_x_kernel<<<(N_TOK*E_DIM/4+255)/256, 256, 0, stream>>>(x, xhi, xlo, N_TOK*E_DIM/4);
  tconv_kernel<<<dim3(1024/32, E_DIM/32), dim3(32,8), 0, stream>>>(Wr1, wr1hi, wr1lo, E_DIM, 1024);
  // fused transpose Wq,Wk,Wv,Wo -> wqkvT(+woT, contiguous)
  tconv4_kernel<<<dim3(E_DIM/32, E_DIM/32, 4), dim3(32,8), 0, stream>>>(Wq, Wk, Wv, Wo, wqkvT);

  // fused router: H = gelu(x@Wr1 + br1) (hi/lo split, one pass)
  gemm_router_kernel<<<dim3(8, 32), 256, 0, stream>>>(xhi, xlo, wr1hi, wr1lo, br1, hbuf);
  scores_kernel<<<N_TOK/4, 256, 0, stream>>>(hbuf, Wr2, br2, scores, tokmax);
  aux_kernel<<<1, 1024, 0, stream>>>(tokmax, ((float*)d_out) + (size_t)N_TOK*E_DIM);
  topk_kernel<<<KEXP, 1024, 0, stream>>>(scores, topkI, selw, rankof);
  rope_kernel<<<CAPN*64/256, 256, 0, stream>>>(cosT, sinT);

  // fused QKV projection (bf16): [4096][6144] via 256x256 8-phase pipelined GEMM
  gemm256_8p<1><<<dim3(QKV_STRIDE/256, N_TOK/256), 512, 0, stream>>>(xhi, wqkvT, qkvbuf, QKV_STRIDE, E_DIM);

  // pre-gather/rope/transpose K,V into dense swizzled tiles
  prerope_k_kernel<<<KEXP*NH*CAPN*16/256, 256, 0, stream>>>(qkvbuf + E_DIM, topkI, cosT, sinT, Kg);
  prev_kernel<<<KEXP*NH*NTILE, 256, 0, stream>>>(qkvbuf + 2*E_DIM, topkI, Vg);

  // gathered causal attention
  attn_kernel<<<KEXP*NH*NTILE, 256, 0, stream>>>(qkvbuf, Kg, Vg, topkI, selw, cosT, sinT, oexp);

  // scatter-accumulate experts -> token rows
  acc_kernel<<<N_TOK, 256, 0, stream>>>(oexp, rankof, accb);

  // final projection -> d_out (proven m97 128^2 structure, 512 blocks)
  gemm_kernel<0,0><<<dim3(E_DIM/128, N_TOK/128), 256, 0, stream>>>(accb, woT, (float*)d_out, E_DIM, E_DIM);
}

// Round 7
// 478.537 us; speedup vs baseline: 1.2617x; 1.0553x over previous
//
#include <hip/hip_runtime.h>
#include <cstdint>
#include <cstddef>

// Problem constants
#define N_TOK 4096
#define E_DIM 2048
#define NH    16
#define DH    128
#define KEXP  4
#define CAPN  1280
#define NTILE 20                 // CAPN/64
#define QKV_STRIDE 6144          // fused QKV output row stride
#define SCALE_QK 0.08838834764831845f
#define LOG2E    1.4426950408889634f
#define NEG_BIG -1e30f

typedef __attribute__((ext_vector_type(4))) float f32x4;
typedef __attribute__((ext_vector_type(8))) short s16x8;

__device__ __forceinline__ float bf2f(unsigned short u){
  union{unsigned int i; float fl;} c; c.i = ((unsigned int)u)<<16; return c.fl;
}
__device__ __forceinline__ unsigned short f2bf(float x){
  union{float fl; unsigned int i;} c; c.fl=x;
  return (unsigned short)((c.i + 0x7FFFu + ((c.i>>16)&1u))>>16);
}
__device__ __forceinline__ f32x4 mfma_bf16(s16x8 a, s16x8 b, f32x4 c){
  asm("v_mfma_f32_16x16x32_bf16 %0, %1, %2, %0" : "+v"(c) : "v"(a), "v"(b));
  return c;
}
// async global->LDS 16B: LDS dest must be lane-linear (base + lane*16)
__device__ __forceinline__ void gl_lds16(const unsigned short* g, unsigned short* l){
  __builtin_amdgcn_global_load_lds(
      (const __attribute__((address_space(1))) unsigned int*)g,
      (__attribute__((address_space(3))) unsigned int*)l, 16, 0, 0);
}

// ---------------- conversions ----------------
__global__ __launch_bounds__(256) void conv_x_kernel(const float* __restrict__ x,
    unsigned short* __restrict__ hi, unsigned short* __restrict__ lo, int n4){
  int idx = blockIdx.x*256 + threadIdx.x;
  if (idx >= n4) return;
  float4 v = ((const float4*)x)[idx];
  float ar[4] = {v.x, v.y, v.z, v.w};
  union{ unsigned short u[4]; uint2 q; } H, L;
  #pragma unroll
  for(int i=0;i<4;i++){
    unsigned short h = f2bf(ar[i]);
    H.u[i] = h;
    L.u[i] = f2bf(ar[i] - bf2f(h));
  }
  ((uint2*)hi)[idx] = H.q;
  ((uint2*)lo)[idx] = L.q;
}

// transpose + f32->bf16 (optionally also lo residual). W[R][C] -> T[C][R]
__global__ __launch_bounds__(256) void tconv_kernel(const float* __restrict__ W,
    unsigned short* __restrict__ Thi, unsigned short* __restrict__ Tlo, int R, int C){
  __shared__ float t[32][33];
  int tx = threadIdx.x, ty = threadIdx.y;   // (32,8)
  int c0 = blockIdx.x*32, r0 = blockIdx.y*32;
  #pragma unroll
  for(int i=0;i<4;i++){
    int r = r0 + ty + i*8;
    t[ty+i*8][tx] = W[(size_t)r*C + c0 + tx];
  }
  __syncthreads();
  #pragma unroll
  for(int i=0;i<4;i++){
    int c = c0 + ty + i*8;
    float v = t[tx][ty+i*8];
    size_t o = (size_t)c*R + r0 + tx;
    unsigned short h = f2bf(v);
    Thi[o] = h;
    if (Tlo) Tlo[o] = f2bf(v - bf2f(h));
  }
}

// fused transpose of 4 ExE weights (Wq,Wk,Wv,Wo) -> contiguous [4][E][E] bf16
__global__ __launch_bounds__(256) void tconv4_kernel(const float* __restrict__ W0,
    const float* __restrict__ W1, const float* __restrict__ W2, const float* __restrict__ W3,
    unsigned short* __restrict__ out){
  __shared__ float t[32][33];
  int z = blockIdx.z;
  const float* W = (z==0)?W0 : (z==1)?W1 : (z==2)?W2 : W3;
  unsigned short* T = out + (size_t)z*E_DIM*E_DIM;
  int tx = threadIdx.x, ty = threadIdx.y;   // (32,8)
  int c0 = blockIdx.x*32, r0 = blockIdx.y*32;
  #pragma unroll
  for(int i=0;i<4;i++){
    int r = r0 + ty + i*8;
    t[ty+i*8][tx] = W[(size_t)r*E_DIM + c0 + tx];
  }
  __syncthreads();
  #pragma unroll
  for(int i=0;i<4;i++){
    int c = c0 + ty + i*8;
    T[(size_t)c*E_DIM + r0 + tx] = f2bf(t[tx][ty+i*8]);
  }
}

// ============ 128x256 BK=64 8-wave 2-phase pipelined GEMM (T2+T3+T4+T5) ============
// C[M][N] = A[M][K] * Bt[N][K]^T. 512 thr = 8 waves 2Mx4N, wave tile 64x64.
// LDS 96KB: [2 buf][ A0 4096 | A1 4096 | B0 8192 | B1 8192 ] shorts (ks slabs of K=32).
// Stage units: A = 1 load/thread, B = 2 -> 3 loads per (A,B) pair.
// Phase p1(ks0): reads A0,B0(t); stages A1,B1(t+1)->nxt; vmcnt(6) [guards p2 reads].
// Phase p2(ks1): reads A1,B1(t); stages A0,B0(t+2)->cur; vmcnt(6) [guards next p1 reads].
// Queue never drains mid-loop (T4). Builtin s_barrier (no clobber) lets the compiler
// pipeline next-phase ds_reads under MFMA clusters; vmcnt asm keeps the memory fence.
// Swizzle: LDS(row,ch)=G(row, ch^((row>>1)&3)); read chunk g^((r16>>1)&3) (T2).
template<int OUTBF>
__global__ __launch_bounds__(512, 1) void gemm_p(
    const unsigned short* __restrict__ A, const unsigned short* __restrict__ Bt,
    void* __restrict__ Cp, int N, int Kd){
  __shared__ __align__(16) unsigned short lds[2][24576];
  const int tid = threadIdx.x;
  const int w = tid>>6, lane = tid&63, g = lane>>4, r16 = lane&15;
  const int wm = w>>2, wn = w&3;                   // 2M x 4N waves
  const int mb = blockIdx.y, nb = blockIdx.x;
  const unsigned short* Ab = A  + (size_t)mb*128*Kd;
  const unsigned short* Bb = Bt + (size_t)nb*256*Kd;
  const int NT = Kd >> 6;

  f32x4 acc[4][4];
  #pragma unroll
  for(int i=0;i<4;i++)
    #pragma unroll
    for(int j=0;j<4;j++) acc[i][j] = f32x4{0.f,0.f,0.f,0.f};

  auto stageA = [&](int buf, int ks, int t){      // 128x32: 512 chunks, 1/thread
    int row = tid>>2, ch = tid&3;
    int sc = ch ^ ((row>>1)&3);
    gl_lds16(Ab + (size_t)row*Kd + t*64 + ks*32 + sc*8, &lds[buf][ks*4096 + tid*8]);
  };
  auto stageB = [&](int buf, int ks, int t){      // 256x32: 1024 chunks, 2/thread
    #pragma unroll
    for(int i=0;i<2;i++){
      int n = i*512 + tid;
      int row = n>>2, ch = n&3;
      int sc = ch ^ ((row>>1)&3);
      gl_lds16(Bb + (size_t)row*Kd + t*64 + ks*32 + sc*8, &lds[buf][8192 + ks*8192 + n*8]);
    }
  };
  const int xoff = (g ^ ((r16>>1)&3)) << 3;

  // prologue: tile0 both slabs -> buf0; tile1 ks0 slabs -> buf1 (stay in flight)
  stageA(0,0,0); stageB(0,0,0);
  stageA(0,1,0); stageB(0,1,0);
  stageA(1,0,1); stageB(1,0,1);
  asm volatile("s_waitcnt vmcnt(6)" ::: "memory");
  __builtin_amdgcn_s_barrier();

  int cur = 0;
  for(int t=0; t<NT; ++t){
    const int nxt = cur^1;
    s16x8 af[4], bfv[4];
    // ---- p1: ks0 ----
    #pragma unroll
    for(int mf=0;mf<4;mf++)
      af[mf] = *(const s16x8*)&lds[cur][(wm*64 + mf*16 + r16)*32 + xoff];
    #pragma unroll
    for(int nf=0;nf<4;nf++)
      bfv[nf] = *(const s16x8*)&lds[cur][8192 + (wn*64 + nf*16 + r16)*32 + xoff];
    if (t+1 < NT){
      stageA(nxt,1,t+1); stageB(nxt,1,t+1);
      asm volatile("s_waitcnt vmcnt(6)" ::: "memory");
    } else {
      asm volatile("s_waitcnt vmcnt(0)" ::: "memory");
    }
    __builtin_amdgcn_s_barrier();
    __builtin_amdgcn_s_setprio(1);
    #pragma unroll
    for(int mf=0;mf<4;mf++)
      #pragma unroll
      for(int nf=0;nf<4;nf++)
        acc[mf][nf] = mfma_bf16(af[mf], bfv[nf], acc[mf][nf]);
    __builtin_amdgcn_s_setprio(0);
    __builtin_amdgcn_s_barrier();
    // ---- p2: ks1 ----
    #pragma unroll
    for(int mf=0;mf<4;mf++)
      af[mf] = *(const s16x8*)&lds[cur][4096 + (wm*64 + mf*16 + r16)*32 + xoff];
    #pragma unroll
    for(int nf=0;nf<4;nf++)
      bfv[nf] = *(const s16x8*)&lds[cur][16384 + (wn*64 + nf*16 + r16)*32 + xoff];
    if (t+2 < NT){
      stageA(cur,0,t+2); stageB(cur,0,t+2);
      asm volatile("s_waitcnt vmcnt(6)" ::: "memory");
    } else if (t+1 < NT){
      asm volatile("s_waitcnt vmcnt(3)" ::: "memory");
    } else {
      asm volatile("s_waitcnt vmcnt(0)" ::: "memory");
    }
    __builtin_amdgcn_s_barrier();
    __builtin_amdgcn_s_setprio(1);
    #pragma unroll
    for(int mf=0;mf<4;mf++)
      #pragma unroll
      for(int nf=0;nf<4;nf++)
        acc[mf][nf] = mfma_bf16(af[mf], bfv[nf], acc[mf][nf]);
    __builtin_amdgcn_s_setprio(0);
    __builtin_amdgcn_s_barrier();
    cur ^= 1;
  }

  const int rowb = mb*128 + wm*64, colb = nb*256 + wn*64;
  #pragma unroll
  for(int mf=0;mf<4;mf++)
    #pragma unroll
    for(int nf=0;nf<4;nf++)
      #pragma unroll
      for(int r=0;r<4;r++){
        int rr = rowb + mf*16 + 4*g + r;
        int cc = colb + nf*16 + r16;
        size_t o = (size_t)rr*N + cc;
        if (OUTBF) ((unsigned short*)Cp)[o] = f2bf(acc[mf][nf][r]);
        else       ((float*)Cp)[o] = acc[mf][nf][r];
      }
}

// ---------------- fused router GEMM: H = gelu(x@Wr1 + br1) via hi/lo split ----------------
__global__ __launch_bounds__(256) void gemm_router_kernel(
    const unsigned short* __restrict__ Ahi, const unsigned short* __restrict__ Alo,
    const unsigned short* __restrict__ Bhi, const unsigned short* __restrict__ Blo,
    const float* __restrict__ br1, float* __restrict__ H){
  __shared__ __align__(16) unsigned short AsH[128*32];
  __shared__ __align__(16) unsigned short AsL[128*32];
  __shared__ __align__(16) unsigned short BsH[128*32];
  __shared__ __align__(16) unsigned short BsL[128*32];
  const int mb = blockIdx.y, nb = blockIdx.x;
  const int tid = threadIdx.x;
  const int lane = tid & 63, w = tid >> 6;
  const int g = lane >> 4, r16 = lane & 15;
  const int wm = w >> 1, wn = w & 1;
  f32x4 acc[4][4];
  #pragma unroll
  for(int i=0;i<4;i++)
    #pragma unroll
    for(int j=0;j<4;j++) acc[i][j] = f32x4{0.f,0.f,0.f,0.f};
  const unsigned short* AbH = Ahi + (size_t)mb*128*E_DIM;
  const unsigned short* AbL = Alo + (size_t)mb*128*E_DIM;
  const unsigned short* BbH = Bhi + (size_t)nb*128*E_DIM;
  const unsigned short* BbL = Blo + (size_t)nb*128*E_DIM;
  const int xr2 = (r16>>1)&3;
  for(int k0=0;k0<E_DIM;k0+=32){
    __syncthreads();
    #pragma unroll
    for(int i=0;i<2;i++){
      int c = i*256 + tid;
      int row = c>>2;
      int sc = ((c&3) ^ ((row>>1)&3))*8;   // pre-swizzled source
      size_t go = (size_t)row*E_DIM + k0 + sc;
      gl_lds16(AbH + go, &AsH[c*8]);
      gl_lds16(AbL + go, &AsL[c*8]);
      gl_lds16(BbH + go, &BsH[c*8]);
      gl_lds16(BbL + go, &BsL[c*8]);
    }
    __syncthreads();
    s16x8 ah[4], al[4], bh[4], bl[4];
    #pragma unroll
    for(int f2=0;f2<4;f2++){
      int ra = (wm*64 + f2*16 + r16)*32 + 8*(g ^ xr2);
      int rb = (wn*64 + f2*16 + r16)*32 + 8*(g ^ xr2);
      ah[f2] = *(const s16x8*)&AsH[ra];
      al[f2] = *(const s16x8*)&AsL[ra];
      bh[f2] = *(const s16x8*)&BsH[rb];
      bl[f2] = *(const s16x8*)&BsL[rb];
    }
    #pragma unroll
    for(int fm=0;fm<4;fm++)
      #pragma unroll
      for(int fn=0;fn<4;fn++){
        acc[fm][fn] = mfma_bf16(ah[fm], bh[fn], acc[fm][fn]);
        acc[fm][fn] = mfma_bf16(ah[fm], bl[fn], acc[fm][fn]);
        acc[fm][fn] = mfma_bf16(al[fm], bh[fn], acc[fm][fn]);
      }
  }
  const int rowb = mb*128 + wm*64, colb = nb*128 + wn*64;
  #pragma unroll
  for(int fm=0;fm<4;fm++)
    #pragma unroll
    for(int fn=0;fn<4;fn++)
      #pragma unroll
      for(int r=0;r<4;r++){
        int rr = rowb + fm*16 + 4*g + r;
        int cc = colb + fn*16 + r16;
        float v = acc[fm][fn][r] + br1[cc];
        H[(size_t)rr*1024 + cc] = 0.5f*v*(1.0f + erff(v*0.70710678118654752f));
      }
}

// ---------------- router scores ----------------
__global__ __launch_bounds__(256) void scores_kernel(const float* __restrict__ h,
    const float* __restrict__ Wr2, const float* __restrict__ br2,
    float* __restrict__ scores, float* __restrict__ tokmax){
  int tid = threadIdx.x;
  int n = blockIdx.x*4 + (tid>>6);
  int lane = tid & 63;
  const float* hr = h + (size_t)n*1024;
  float s0=0,s1=0,s2=0,s3=0;
  #pragma unroll
  for(int i=0;i<16;i++){
    int j = lane + i*64;
    float hv = hr[j];
    float4 wv = *(const float4*)(Wr2 + (size_t)j*4);
    s0 += hv*wv.x; s1 += hv*wv.y; s2 += hv*wv.z; s3 += hv*wv.w;
  }
  #pragma unroll
  for(int m=32;m>=1;m>>=1){
    s0 += __shfl_xor(s0,m); s1 += __shfl_xor(s1,m);
    s2 += __shfl_xor(s2,m); s3 += __shfl_xor(s3,m);
  }
  if (lane==0){
    s0+=br2[0]; s1+=br2[1]; s2+=br2[2]; s3+=br2[3];
    scores[n*4+0]=s0; scores[n*4+1]=s1; scores[n*4+2]=s2; scores[n*4+3]=s3;
    tokmax[n]=fmaxf(fmaxf(s0,s1),fmaxf(s2,s3));
  }
}

__global__ __launch_bounds__(1024) void aux_kernel(const float* __restrict__ tokmax, float* __restrict__ out_aux){
  __shared__ float red[1024];
  int t = threadIdx.x;
  red[t] = tokmax[t] + tokmax[t+1024] + tokmax[t+2048] + tokmax[t+3072];
  __syncthreads();
  for(int k=512;k>=1;k>>=1){ if(t<k) red[t]+=red[t+k]; __syncthreads(); }
  if (t==0) out_aux[0] = -red[0]/4096.0f;
}

// ---------------- exact top-k (bitonic sort of 4096 per expert) ----------------
__global__ __launch_bounds__(1024) void topk_kernel(const float* __restrict__ scores,
    int* __restrict__ topk_idx, float* __restrict__ sel_w, int* __restrict__ rank_of){
  __shared__ float sv[4096];
  __shared__ int   si[4096];
  __shared__ float red[1024];
  int e = blockIdx.x, t = threadIdx.x;
  for(int i=t;i<4096;i+=1024){ sv[i]=scores[i*4+e]; si[i]=i; }
  __syncthreads();
  for(int k=2;k<=4096;k<<=1){
    for(int j=k>>1;j>0;j>>=1){
      for(int i=t;i<4096;i+=1024){
        int ixj = i^j;
        if (ixj>i){
          float vi=sv[i], vj=sv[ixj];
          int ii=si[i], ij=si[ixj];
          bool jGreater = (vj>vi) || (vj==vi && ij<ii);
          bool asc = (i&k)==0;
          if (asc ? jGreater : !jGreater){
            sv[i]=vj; sv[ixj]=vi; si[i]=ij; si[ixj]=ii;
          }
        }
      }
      __syncthreads();
    }
  }
  for(int i=t;i<4096;i+=1024) rank_of[e*4096+i] = -1;
  __syncthreads();
  for(int r=t;r<CAPN;r+=1024){
    int tok = si[r];
    topk_idx[e*CAPN+r] = tok;
    rank_of[e*4096+tok] = r;
  }
  float mx = sv[0];
  float part = 0.f;
  for(int r=t;r<CAPN;r+=1024) part += expf(sv[r]-mx);
  red[t]=part; __syncthreads();
  for(int k=512;k>=1;k>>=1){ if(t<k) red[t]+=red[t+k]; __syncthreads(); }
  float denom = red[0];
  for(int r=t;r<CAPN;r+=1024) sel_w[e*CAPN+r] = expf(sv[r]-mx)/denom;
}

// ---------------- RoPE tables [CAPN][64] ----------------
__global__ __launch_bounds__(256) void rope_kernel(float* __restrict__ cosT, float* __restrict__ sinT){
  int idx = blockIdx.x*256 + threadIdx.x;
  int p = idx>>6, dm = idx&63;
  float inv = powf(10000.0f, -(float)dm/64.0f);
  float ang = (float)p*inv;
  cosT[idx]=cosf(ang);
  sinT[idx]=sinf(ang);
}

// ---------------- pre-gather + pre-rope K into swizzled tiles ----------------
__global__ __launch_bounds__(256) void prerope_k_kernel(const unsigned short* __restrict__ kb,
    const int* __restrict__ topk_idx, const float* __restrict__ cosT, const float* __restrict__ sinT,
    unsigned short* __restrict__ Kg){
  int idx = blockIdx.x*256 + threadIdx.x;   // exact 4*16*1280*16
  int ch = idx & 15;
  int rest = idx >> 4;
  int rank = rest % CAPN;
  int he = rest / CAPN;           // e*16+h
  int e = he >> 4, h = he & 15;
  int tok = topk_idx[e*CAPN + rank];
  int d0 = ch*8;
  const unsigned short* krow = kb + (size_t)tok*QKV_STRIDE + h*DH;
  unsigned short held[8], part[8];
  *(uint4*)held = *(const uint4*)(krow + d0);
  *(uint4*)part = *(const uint4*)(krow + (d0^64));
  const float* cr = cosT + rank*64;
  const float* sr = sinT + rank*64;
  float sgn = (d0<64) ? -1.f : 1.f;
  unsigned short outv[8];
  #pragma unroll
  for(int jj=0;jj<8;jj++){
    int dm = (d0+jj)&63;
    outv[jj] = f2bf(bf2f(held[jj])*cr[dm] + sgn*bf2f(part[jj])*sr[dm]);
  }
  int t = rank >> 6, row = rank & 63;
  size_t tbase = ((size_t)(he)*NTILE + t) * 8192;
  *(uint4*)(Kg + tbase + row*128 + ((ch ^ (row&7))<<3)) = *(uint4*)outv;
}

// ---------------- pre-gather + transpose V into swizzled tiles ----------------
__global__ __launch_bounds__(256) void prev_kernel(const unsigned short* __restrict__ vb,
    const int* __restrict__ topk_idx, unsigned short* __restrict__ Vg){
  __shared__ __align__(16) unsigned short T2[128][72];
  int bid = blockIdx.x;           // e*320 + h*20 + t
  int t = bid % NTILE, h = (bid/NTILE) & 15, e = bid/(NTILE*NH);
  int tid = threadIdx.x, lane = tid & 63, dchb = tid >> 6;
  int tok = topk_idx[e*CAPN + t*64 + lane];
  const unsigned short* vrow = vb + (size_t)tok*QKV_STRIDE + h*DH;
  #pragma unroll
  for(int i=0;i<4;i++){
    int d0 = (dchb + i*4)*8;
    unsigned short vv[8];
    *(uint4*)vv = *(const uint4*)(vrow + d0);
    #pragma unroll
    for(int j=0;j<8;j++) T2[d0+j][lane] = vv[j];   // lane-consecutive: conflict-free
  }
  __syncthreads();
  unsigned short* out = Vg + ((size_t)(e*NH+h)*NTILE + t)*8192;
  #pragma unroll
  for(int i=0;i<4;i++){
    int c = i*256 + tid;
    int d = c>>3, ch = c&7;
    *(uint4*)(out + d*64 + ((ch ^ (d&7))<<3)) = *(const uint4*)&T2[d][ch*8];
  }
}

// ---------------- gathered causal flash attention ----------------
// counted-vmcnt pipeline: K(t+1) staged at iter top, V(t+1) at iter end; each
// rendezvous is (per-wave vmcnt(4); s_barrier) so prefetches ride across phases.
__global__ __launch_bounds__(256) void attn_kernel(
    const unsigned short* __restrict__ qb,
    const unsigned short* __restrict__ Kg, const unsigned short* __restrict__ Vg,
    const int* __restrict__ topk_idx, const float* __restrict__ sel_w,
    const float* __restrict__ cosT, const float* __restrict__ sinT,
    unsigned short* __restrict__ oexp){
  __shared__ __align__(16) unsigned short KsA[2][8192];
  __shared__ __align__(16) unsigned short Vs[8192];
  __shared__ __align__(16) unsigned short Ps[4][16][72];
  const int id = blockIdx.x;
  const int xcd = id & 7, s_ = id >> 3;
  const int qt = NTILE - 1 - (s_ % NTILE);          // longest first
  const int grp = (s_ / NTILE)*8 + xcd;             // 0..63
  const int e = grp >> 4, hh = grp & 15;
  const int tid = threadIdx.x, w = tid>>6, lane = tid&63, g = lane>>4, r16 = lane&15;
  const int* idxE = topk_idx + e*CAPN;
  const unsigned short* Kgb = Kg + (size_t)(e*NH+hh)*CAPN*DH;
  const unsigned short* Vgb = Vg + (size_t)(e*NH+hh)*CAPN*DH;

  s16x8 aq[4];
  {
    int qr = qt*64 + w*16 + r16;
    int tok = idxE[qr];
    const unsigned short* qrow = qb + (size_t)tok*QKV_STRIDE + hh*DH;
    const float* cr = cosT + qr*64;
    const float* sr = sinT + qr*64;
    #pragma unroll
    for(int s=0;s<4;s++){
      int d0 = s*32 + 8*g;
      unsigned short held[8], part[8];
      *(uint4*)held = *(const uint4*)(qrow + d0);
      *(uint4*)part = *(const uint4*)(qrow + (d0^64));
      float sgn = (d0<64) ? -1.f : 1.f;
      union{ s16x8 v; unsigned short u[8]; } fr;
      #pragma unroll
      for(int jj=0;jj<8;jj++){
        int dm = (d0+jj)&63;
        float val = bf2f(held[jj])*cr[dm] + sgn*bf2f(part[jj])*sr[dm];
        fr.u[jj] = f2bf(val * (SCALE_QK*LOG2E));
      }
      aq[s] = fr.v;
    }
  }
  float m_r[4], l_r[4];
  f32x4 o[8];
  #pragma unroll
  for(int r=0;r<4;r++){ m_r[r]=-INFINITY; l_r[r]=0.f; }
  #pragma unroll
  for(int f2=0;f2<8;f2++) o[f2]=f32x4{0.f,0.f,0.f,0.f};

  // prologue: K(0), V(0); wait K(0) only (V(0) rides to the mid barrier)
  #pragma unroll
  for(int i=0;i<4;i++){ int c=i*256+tid; gl_lds16(Kgb + c*8, &KsA[0][c*8]); }
  #pragma unroll
  for(int i=0;i<4;i++){ int c=i*256+tid; gl_lds16(Vgb + c*8, &Vs[c*8]); }
  asm volatile("s_waitcnt vmcnt(4)" ::: "memory");
  __builtin_amdgcn_s_barrier();

  for(int kt=0; kt<=qt; kt++){
    const int cur = kt & 1;
    if (kt < qt){
      const unsigned short* Ksrc = Kgb + (size_t)(kt+1)*8192;
      #pragma unroll
      for(int i=0;i<4;i++){ int c=i*256+tid; gl_lds16(Ksrc + c*8, &KsA[cur^1][c*8]); }
    }
    f32x4 sfr[4];
    #pragma unroll
    for(int fc=0;fc<4;fc++){
      f32x4 a4 = f32x4{0.f,0.f,0.f,0.f};
      const int row = fc*16 + r16;
      #pragma unroll
      for(int s=0;s<4;s++){
        s16x8 bk = *(const s16x8*)&KsA[cur][row*128 + (((s*4+g) ^ (r16&7))<<3)];
        a4 = mfma_bf16(aq[s], bk, a4);
      }
      sfr[fc] = a4;
    }
    if (kt==qt){
      #pragma unroll
      for(int fc=0;fc<4;fc++)
        #pragma unroll
        for(int r=0;r<4;r++){
          int qrank  = qt*64 + w*16 + 4*g + r;
          int kvrank = kt*64 + fc*16 + r16;
          if (kvrank > qrank) sfr[fc][r] = NEG_BIG;
        }
    }
    float corr[4];
    bool need = false;
    #pragma unroll
    for(int r=0;r<4;r++){
      float mx = fmaxf(fmaxf(sfr[0][r],sfr[1][r]), fmaxf(sfr[2][r],sfr[3][r]));
      #pragma unroll
      for(int mk=1;mk<16;mk<<=1) mx = fmaxf(mx, __shfl_xor(mx,mk));
      float nm = fmaxf(m_r[r], mx);
      need = need || (nm > m_r[r]);
      corr[r] = exp2f(m_r[r]-nm);
      m_r[r] = nm;
    }
    if (__any(need)){
      #pragma unroll
      for(int f2=0;f2<8;f2++)
        #pragma unroll
        for(int r=0;r<4;r++) o[f2][r] *= corr[r];
      #pragma unroll
      for(int r=0;r<4;r++) l_r[r] *= corr[r];
    }
    float rs[4] = {0.f,0.f,0.f,0.f};
    #pragma unroll
    for(int fc=0;fc<4;fc++)
      #pragma unroll
      for(int r=0;r<4;r++){
        float p = exp2f(sfr[fc][r] - m_r[r]);
        rs[r] += p;
        Ps[w][4*g+r][fc*16+r16] = f2bf(p);
      }
    #pragma unroll
    for(int r=0;r<4;r++){
      float ts = rs[r];
      #pragma unroll
      for(int mk=1;mk<16;mk<<=1) ts += __shfl_xor(ts,mk);
      l_r[r] += ts;
    }
    // mid rendezvous: V(kt) landed (K(kt+1) may stay in flight)
    if (kt < qt) asm volatile("s_waitcnt vmcnt(4)" ::: "memory");
    else         asm volatile("s_waitcnt vmcnt(0)" ::: "memory");
    __builtin_amdgcn_s_barrier();
    #pragma unroll
    for(int ks=0;ks<2;ks++){
      s16x8 pa = *(const s16x8*)&Ps[w][r16][ks*32 + 8*g];
      #pragma unroll
      for(int fd=0;fd<8;fd++){
        const int row = fd*16 + r16;
        s16x8 vf = *(const s16x8*)&Vs[row*64 + (((ks*4+g) ^ (r16&7))<<3)];
        o[fd] = mfma_bf16(pa, vf, o[fd]);
      }
    }
    __builtin_amdgcn_s_barrier();   // PV reads done; Vs safe to overwrite
    if (kt < qt){
      const unsigned short* Vsrc = Vgb + (size_t)(kt+1)*8192;
      #pragma unroll
      for(int i=0;i<4;i++){ int c=i*256+tid; gl_lds16(Vsrc + c*8, &Vs[c*8]); }
      // K(kt+1) landed (V(kt+1) rides to next mid barrier)
      asm volatile("s_waitcnt vmcnt(4)" ::: "memory");
      __builtin_amdgcn_s_barrier();
    }
  }
  #pragma unroll
  for(int r=0;r<4;r++){
    int qrank = qt*64 + w*16 + 4*g + r;
    float fac = sel_w[e*CAPN + qrank] / l_r[r];
    #pragma unroll
    for(int fd=0;fd<8;fd++){
      oexp[((size_t)(e*CAPN + qrank))*E_DIM + hh*DH + fd*16 + r16] = f2bf(o[fd][r]*fac);
    }
  }
}

// ---------------- scatter-accumulate over experts ----------------
__global__ __launch_bounds__(256) void acc_kernel(const unsigned short* __restrict__ oexp,
    const int* __restrict__ rank_of, unsigned short* __restrict__ accb){
  int n = blockIdx.x, t = threadIdx.x;
  int base = t*8;
  float s[8] = {0,0,0,0,0,0,0,0};
  #pragma unroll
  for(int e=0;e<4;e++){
    int r = rank_of[e*4096+n];
    if (r>=0){
      union{uint4 q; unsigned short u[8];} ld;
      ld.q = *(const uint4*)(oexp + ((size_t)(e*CAPN+r))*E_DIM + base);
      #pragma unroll
      for(int j2=0;j2<8;j2++) s[j2] += bf2f(ld.u[j2]);
    }
  }
  union{uint4 q; unsigned short u[8];} st;
  #pragma unroll
  for(int j2=0;j2<8;j2++) st.u[j2] = f2bf(s[j2]);
  *(uint4*)(accb + (size_t)n*E_DIM + base) = st.q;
}

// ---------------- launch ----------------
extern "C" void kernel_launch(void* const* d_in, const int* in_sizes, int n_in,
                              void* d_out, int out_size, void* d_ws, size_t ws_size,
                              hipStream_t stream) {
  const float* x   = (const float*)d_in[0];
  const float* Wq  = (const float*)d_in[1];
  const float* Wk  = (const float*)d_in[2];
  const float* Wv  = (const float*)d_in[3];
  const float* Wo  = (const float*)d_in[4];
  const float* Wr1 = (const float*)d_in[5];
  const float* br1 = (const float*)d_in[6];
  const float* Wr2 = (const float*)d_in[7];
  const float* br2 = (const float*)d_in[8];

  char* ws = (char*)d_ws;
  size_t off = 0;
  auto alloc = [&](size_t bytes)->void*{
    void* p = ws + off;
    off += (bytes + 255) & ~(size_t)255;
    return p;
  };
  unsigned short* xhi   = (unsigned short*)alloc((size_t)N_TOK*E_DIM*2);
  unsigned short* xlo   = (unsigned short*)alloc((size_t)N_TOK*E_DIM*2);
  unsigned short* wr1hi = (unsigned short*)alloc((size_t)E_DIM*1024*2);   // transposed [1024][2048]
  unsigned short* wr1lo = (unsigned short*)alloc((size_t)E_DIM*1024*2);
  unsigned short* wqkvT = (unsigned short*)alloc((size_t)3*E_DIM*E_DIM*2); // [6144][2048]
  unsigned short* woT   = (unsigned short*)alloc((size_t)E_DIM*E_DIM*2);   // contiguous after wqkvT
  void* hv = alloc((size_t)KEXP*NH*CAPN*DH*2);   // max(hbuf 16.8MB, Vg 21MB)
  float* hbuf = (float*)hv;                      // dead after scores_kernel
  unsigned short* Vg = (unsigned short*)hv;      // written by prev_kernel later
  float* scores = (float*)alloc((size_t)N_TOK*4*4);
  float* tokmax = (float*)alloc((size_t)N_TOK*4);
  int*   topkI  = (int*)alloc((size_t)KEXP*CAPN*4);
  float* selw   = (float*)alloc((size_t)KEXP*CAPN*4);
  int*   rankof = (int*)alloc((size_t)KEXP*N_TOK*4);
  float* cosT   = (float*)alloc((size_t)CAPN*64*4);
  float* sinT   = (float*)alloc((size_t)CAPN*64*4);
  unsigned short* qkvbuf = (unsigned short*)alloc((size_t)N_TOK*QKV_STRIDE*2);
  unsigned short* oexp = (unsigned short*)alloc((size_t)KEXP*CAPN*E_DIM*2);
  unsigned short* accb = (unsigned short*)alloc((size_t)N_TOK*E_DIM*2);
  if (off > ws_size) return;   // fail loudly (output stays poisoned)

  // Kg (21MB, swizzled) aliases xlo+wr1hi+wr1lo (25.2MB), dead after router GEMM
  unsigned short* Kg = xlo;

  // conversions
  conv_x_kernel<<<(N_TOK*E_DIM/4+255)/256, 256, 0, stream>>>(x, xhi, xlo, N_TOK*E_DIM/4);
  tconv_kernel<<<dim3(1024/32, E_DIM/32), dim3(32,8), 0, stream>>>(Wr1, wr1hi, wr1lo, E_DIM, 1024);
  // fused transpose Wq,Wk,Wv,Wo -> wqkvT(+woT, contiguous)
  tconv4_kernel<<<dim3(E_DIM/32, E_DIM/32, 4), dim3(32,8), 0, stream>>>(Wq, Wk, Wv, Wo, wqkvT);

  // fused router: H = gelu(x@Wr1 + br1) (hi/lo split, one pass)
  gemm_router_kernel<<<dim3(8, 32), 256, 0, stream>>>(xhi, xlo, wr1hi, wr1lo, br1, hbuf);
  scores_kernel<<<N_TOK/4, 256, 0, stream>>>(hbuf, Wr2, br2, scores, tokmax);
  aux_kernel<<<1, 1024, 0, stream>>>(tokmax, ((float*)d_out) + (size_t)N_TOK*E_DIM);
  topk_kernel<<<KEXP, 1024, 0, stream>>>(scores, topkI, selw, rankof);
  rope_kernel<<<CAPN*64/256, 256, 0, stream>>>(cosT, sinT);

  // fused QKV projection: [4096][6144] via 128x256 2-phase pipelined GEMM (3.0 exact rounds)
  gemm_p<1><<<dim3(QKV_STRIDE/256, N_TOK/128), 512, 0, stream>>>(xhi, wqkvT, qkvbuf, QKV_STRIDE, E_DIM);

  // pre-gather/rope/transpose K,V into dense swizzled tiles
  prerope_k_kernel<<<KEXP*NH*CAPN*16/256, 256, 0, stream>>>(qkvbuf + E_DIM, topkI, cosT, sinT, Kg);
  prev_kernel<<<KEXP*NH*NTILE, 256, 0, stream>>>(qkvbuf + 2*E_DIM, topkI, Vg);

  // gathered causal attention
  attn_kernel<<<KEXP*NH*NTILE, 256, 0, stream>>>(qkvbuf, Kg, Vg, topkI, selw, cosT, sinT, oexp);

  // scatter-accumulate experts -> token rows
  acc_kernel<<<N_TOK, 256, 0, stream>>>(oexp, rankof, accb);

  // final projection -> d_out (128x256 pipelined, 256 blocks = 1.0 exact round)
  gemm_p<0><<<dim3(E_DIM/256, N_TOK/128), 512, 0, stream>>>(accb, woT, (float*)d_out, E_DIM, E_DIM);
}

// Round 8
// 448.251 us; speedup vs baseline: 1.3470x; 1.0676x over previous
//
#include <hip/hip_runtime.h>
#include <cstdint>
#include <cstddef>

// Problem constants
#define N_TOK 4096
#define E_DIM 2048
#define NH    16
#define DH    128
#define KEXP  4
#define CAPN  1280
#define NTILE 20                 // CAPN/64
#define QKV_STRIDE 6144          // fused QKV output row stride
#define SCALE_QK 0.08838834764831845f
#define LOG2E    1.4426950408889634f
#define NEG_BIG -1e30f

typedef __attribute__((ext_vector_type(4))) float f32x4;
typedef __attribute__((ext_vector_type(8))) short s16x8;

__device__ __forceinline__ float bf2f(unsigned short u){
  union{unsigned int i; float fl;} c; c.i = ((unsigned int)u)<<16; return c.fl;
}
__device__ __forceinline__ unsigned short f2bf(float x){
  union{float fl; unsigned int i;} c; c.fl=x;
  return (unsigned short)((c.i + 0x7FFFu + ((c.i>>16)&1u))>>16);
}
__device__ __forceinline__ f32x4 mfma_bf16(s16x8 a, s16x8 b, f32x4 c){
  asm("v_mfma_f32_16x16x32_bf16 %0, %1, %2, %0" : "+v"(c) : "v"(a), "v"(b));
  return c;
}
// async global->LDS 16B: LDS dest must be lane-linear (base + lane*16)
__device__ __forceinline__ void gl_lds16(const unsigned short* g, unsigned short* l){
  __builtin_amdgcn_global_load_lds(
      (const __attribute__((address_space(1))) unsigned int*)g,
      (__attribute__((address_space(3))) unsigned int*)l, 16, 0, 0);
}

// ---------------- conversions ----------------
__global__ __launch_bounds__(256) void conv_x_kernel(const float* __restrict__ x,
    unsigned short* __restrict__ hi, unsigned short* __restrict__ lo, int n4){
  int idx = blockIdx.x*256 + threadIdx.x;
  if (idx >= n4) return;
  float4 v = ((const float4*)x)[idx];
  float ar[4] = {v.x, v.y, v.z, v.w};
  union{ unsigned short u[4]; uint2 q; } H, L;
  #pragma unroll
  for(int i=0;i<4;i++){
    unsigned short h = f2bf(ar[i]);
    H.u[i] = h;
    L.u[i] = f2bf(ar[i] - bf2f(h));
  }
  ((uint2*)hi)[idx] = H.q;
  ((uint2*)lo)[idx] = L.q;
}

// transpose + f32->bf16 (optionally also lo residual). W[R][C] -> T[C][R]
__global__ __launch_bounds__(256) void tconv_kernel(const float* __restrict__ W,
    unsigned short* __restrict__ Thi, unsigned short* __restrict__ Tlo, int R, int C){
  __shared__ float t[32][33];
  int tx = threadIdx.x, ty = threadIdx.y;   // (32,8)
  int c0 = blockIdx.x*32, r0 = blockIdx.y*32;
  #pragma unroll
  for(int i=0;i<4;i++){
    int r = r0 + ty + i*8;
    t[ty+i*8][tx] = W[(size_t)r*C + c0 + tx];
  }
  __syncthreads();
  #pragma unroll
  for(int i=0;i<4;i++){
    int c = c0 + ty + i*8;
    float v = t[tx][ty+i*8];
    size_t o = (size_t)c*R + r0 + tx;
    unsigned short h = f2bf(v);
    Thi[o] = h;
    if (Tlo) Tlo[o] = f2bf(v - bf2f(h));
  }
}

// fused transpose of 4 ExE weights (Wq,Wk,Wv,Wo) -> contiguous [4][E][E] bf16
__global__ __launch_bounds__(256) void tconv4_kernel(const float* __restrict__ W0,
    const float* __restrict__ W1, const float* __restrict__ W2, const float* __restrict__ W3,
    unsigned short* __restrict__ out){
  __shared__ float t[32][33];
  int z = blockIdx.z;
  const float* W = (z==0)?W0 : (z==1)?W1 : (z==2)?W2 : W3;
  unsigned short* T = out + (size_t)z*E_DIM*E_DIM;
  int tx = threadIdx.x, ty = threadIdx.y;   // (32,8)
  int c0 = blockIdx.x*32, r0 = blockIdx.y*32;
  #pragma unroll
  for(int i=0;i<4;i++){
    int r = r0 + ty + i*8;
    t[ty+i*8][tx] = W[(size_t)r*E_DIM + c0 + tx];
  }
  __syncthreads();
  #pragma unroll
  for(int i=0;i<4;i++){
    int c = c0 + ty + i*8;
    T[(size_t)c*E_DIM + r0 + tx] = f2bf(t[tx][ty+i*8]);
  }
}

// ============ 128x256 BK=64 8-wave 2-phase pipelined GEMM (T2+T3+T4+T5) ============
template<int OUTBF>
__global__ __launch_bounds__(512, 1) void gemm_p(
    const unsigned short* __restrict__ A, const unsigned short* __restrict__ Bt,
    void* __restrict__ Cp, int N, int Kd){
  __shared__ __align__(16) unsigned short lds[2][24576];
  const int tid = threadIdx.x;
  const int w = tid>>6, lane = tid&63, g = lane>>4, r16 = lane&15;
  const int wm = w>>2, wn = w&3;                   // 2M x 4N waves
  const int mb = blockIdx.y, nb = blockIdx.x;
  const unsigned short* Ab = A  + (size_t)mb*128*Kd;
  const unsigned short* Bb = Bt + (size_t)nb*256*Kd;
  const int NT = Kd >> 6;

  f32x4 acc[4][4];
  #pragma unroll
  for(int i=0;i<4;i++)
    #pragma unroll
    for(int j=0;j<4;j++) acc[i][j] = f32x4{0.f,0.f,0.f,0.f};

  auto stageA = [&](int buf, int ks, int t){      // 128x32: 512 chunks, 1/thread
    int row = tid>>2, ch = tid&3;
    int sc = ch ^ ((row>>1)&3);
    gl_lds16(Ab + (size_t)row*Kd + t*64 + ks*32 + sc*8, &lds[buf][ks*4096 + tid*8]);
  };
  auto stageB = [&](int buf, int ks, int t){      // 256x32: 1024 chunks, 2/thread
    #pragma unroll
    for(int i=0;i<2;i++){
      int n = i*512 + tid;
      int row = n>>2, ch = n&3;
      int sc = ch ^ ((row>>1)&3);
      gl_lds16(Bb + (size_t)row*Kd + t*64 + ks*32 + sc*8, &lds[buf][8192 + ks*8192 + n*8]);
    }
  };
  const int xoff = (g ^ ((r16>>1)&3)) << 3;

  stageA(0,0,0); stageB(0,0,0);
  stageA(0,1,0); stageB(0,1,0);
  stageA(1,0,1); stageB(1,0,1);
  asm volatile("s_waitcnt vmcnt(6)" ::: "memory");
  __builtin_amdgcn_s_barrier();

  int cur = 0;
  for(int t=0; t<NT; ++t){
    const int nxt = cur^1;
    s16x8 af[4], bfv[4];
    // ---- p1: ks0 ----
    #pragma unroll
    for(int mf=0;mf<4;mf++)
      af[mf] = *(const s16x8*)&lds[cur][(wm*64 + mf*16 + r16)*32 + xoff];
    #pragma unroll
    for(int nf=0;nf<4;nf++)
      bfv[nf] = *(const s16x8*)&lds[cur][8192 + (wn*64 + nf*16 + r16)*32 + xoff];
    if (t+1 < NT){
      stageA(nxt,1,t+1); stageB(nxt,1,t+1);
      asm volatile("s_waitcnt vmcnt(6)" ::: "memory");
    } else {
      asm volatile("s_waitcnt vmcnt(0)" ::: "memory");
    }
    __builtin_amdgcn_s_barrier();
    __builtin_amdgcn_s_setprio(1);
    #pragma unroll
    for(int mf=0;mf<4;mf++)
      #pragma unroll
      for(int nf=0;nf<4;nf++)
        acc[mf][nf] = mfma_bf16(af[mf], bfv[nf], acc[mf][nf]);
    __builtin_amdgcn_s_setprio(0);
    __builtin_amdgcn_s_barrier();
    // ---- p2: ks1 ----
    #pragma unroll
    for(int mf=0;mf<4;mf++)
      af[mf] = *(const s16x8*)&lds[cur][4096 + (wm*64 + mf*16 + r16)*32 + xoff];
    #pragma unroll
    for(int nf=0;nf<4;nf++)
      bfv[nf] = *(const s16x8*)&lds[cur][16384 + (wn*64 + nf*16 + r16)*32 + xoff];
    if (t+2 < NT){
      stageA(cur,0,t+2); stageB(cur,0,t+2);
      asm volatile("s_waitcnt vmcnt(6)" ::: "memory");
    } else if (t+1 < NT){
      asm volatile("s_waitcnt vmcnt(3)" ::: "memory");
    } else {
      asm volatile("s_waitcnt vmcnt(0)" ::: "memory");
    }
    __builtin_amdgcn_s_barrier();
    __builtin_amdgcn_s_setprio(1);
    #pragma unroll
    for(int mf=0;mf<4;mf++)
      #pragma unroll
      for(int nf=0;nf<4;nf++)
        acc[mf][nf] = mfma_bf16(af[mf], bfv[nf], acc[mf][nf]);
    __builtin_amdgcn_s_setprio(0);
    __builtin_amdgcn_s_barrier();
    cur ^= 1;
  }

  const int rowb = mb*128 + wm*64, colb = nb*256 + wn*64;
  #pragma unroll
  for(int mf=0;mf<4;mf++)
    #pragma unroll
    for(int nf=0;nf<4;nf++)
      #pragma unroll
      for(int r=0;r<4;r++){
        int rr = rowb + mf*16 + 4*g + r;
        int cc = colb + nf*16 + r16;
        size_t o = (size_t)rr*N + cc;
        if (OUTBF) ((unsigned short*)Cp)[o] = f2bf(acc[mf][nf][r]);
        else       ((float*)Cp)[o] = acc[mf][nf][r];
      }
}

// ============ pipelined router GEMM: H = gelu(x@Wr1 + br1), hi/lo split ============
// Same skeleton as gemm_p: BM=128, BN=128, BK=64 (2 ks phases), 8 waves 2Mx4N
// (wave tile 64x32). LDS 128KB: [2 buf][2 ks][Ah|Al|Bh|Bl 4096 shorts each].
// Stage unit = one ks group (4 slabs, 1 load/thread each = 4 loads). vmcnt(8)
// counted waits (2 units in flight), never drains mid-loop. 24 MFMA/phase.
__global__ __launch_bounds__(512, 1) void gemm_router_p(
    const unsigned short* __restrict__ Ahi, const unsigned short* __restrict__ Alo,
    const unsigned short* __restrict__ Bhi, const unsigned short* __restrict__ Blo,
    const float* __restrict__ br1, float* __restrict__ H){
  __shared__ __align__(16) unsigned short lds[2][32768];
  const int tid = threadIdx.x;
  const int w = tid>>6, lane = tid&63, g = lane>>4, r16 = lane&15;
  const int wm = w>>2, wn = w&3;                   // 2M x 4N waves, tile 64x32
  const int mb = blockIdx.y, nb = blockIdx.x;
  const unsigned short* AbH = Ahi + (size_t)mb*128*E_DIM;
  const unsigned short* AbL = Alo + (size_t)mb*128*E_DIM;
  const unsigned short* BbH = Bhi + (size_t)nb*128*E_DIM;
  const unsigned short* BbL = Blo + (size_t)nb*128*E_DIM;
  const int NT = E_DIM >> 6;   // 32

  f32x4 acc[4][2];
  #pragma unroll
  for(int i=0;i<4;i++){ acc[i][0]=f32x4{0.f,0.f,0.f,0.f}; acc[i][1]=f32x4{0.f,0.f,0.f,0.f}; }

  auto stage = [&](int buf, int ks, int t){   // 4 slabs x (128x32), 1 load/thread each
    int row = tid>>2, ch = tid&3;
    int sc = ch ^ ((row>>1)&3);
    size_t go = (size_t)row*E_DIM + t*64 + ks*32 + sc*8;
    unsigned short* base = &lds[buf][ks*16384];
    gl_lds16(AbH + go, base +         tid*8);
    gl_lds16(AbL + go, base +  4096 + tid*8);
    gl_lds16(BbH + go, base +  8192 + tid*8);
    gl_lds16(BbL + go, base + 12288 + tid*8);
  };
  const int xoff = (g ^ ((r16>>1)&3)) << 3;

  stage(0,0,0); stage(0,1,0); stage(1,0,1);
  asm volatile("s_waitcnt vmcnt(8)" ::: "memory");
  __builtin_amdgcn_s_barrier();

  int cur = 0;
  for(int t=0; t<NT; ++t){
    const int nxt = cur^1;
    #pragma unroll
    for(int ph=0; ph<2; ph++){
      const unsigned short* base = &lds[cur][ph*16384];
      s16x8 ah[4], al[4], bh[2], bl[2];
      #pragma unroll
      for(int mf=0;mf<4;mf++){
        int ro = (wm*64 + mf*16 + r16)*32 + xoff;
        ah[mf] = *(const s16x8*)&base[ro];
        al[mf] = *(const s16x8*)&base[4096 + ro];
      }
      #pragma unroll
      for(int nf=0;nf<2;nf++){
        int ro = (wn*32 + nf*16 + r16)*32 + xoff;
        bh[nf] = *(const s16x8*)&base[8192 + ro];
        bl[nf] = *(const s16x8*)&base[12288 + ro];
      }
      if (ph==0){
        if (t+1 < NT){ stage(nxt,1,t+1); asm volatile("s_waitcnt vmcnt(8)" ::: "memory"); }
        else         {                   asm volatile("s_waitcnt vmcnt(0)" ::: "memory"); }
      } else {
        if (t+2 < NT){ stage(cur,0,t+2); asm volatile("s_waitcnt vmcnt(8)" ::: "memory"); }
        else if (t+1 < NT){              asm volatile("s_waitcnt vmcnt(4)" ::: "memory"); }
        else              {              asm volatile("s_waitcnt vmcnt(0)" ::: "memory"); }
      }
      __builtin_amdgcn_s_barrier();
      __builtin_amdgcn_s_setprio(1);
      #pragma unroll
      for(int mf=0;mf<4;mf++)
        #pragma unroll
        for(int nf=0;nf<2;nf++){
          acc[mf][nf] = mfma_bf16(ah[mf], bh[nf], acc[mf][nf]);
          acc[mf][nf] = mfma_bf16(ah[mf], bl[nf], acc[mf][nf]);
          acc[mf][nf] = mfma_bf16(al[mf], bh[nf], acc[mf][nf]);
        }
      __builtin_amdgcn_s_setprio(0);
      __builtin_amdgcn_s_barrier();
    }
    cur ^= 1;
  }

  const int rowb = mb*128 + wm*64, colb = nb*128 + wn*32;
  #pragma unroll
  for(int mf=0;mf<4;mf++)
    #pragma unroll
    for(int nf=0;nf<2;nf++)
      #pragma unroll
      for(int r=0;r<4;r++){
        int rr = rowb + mf*16 + 4*g + r;
        int cc = colb + nf*16 + r16;
        float v = acc[mf][nf][r] + br1[cc];
        H[(size_t)rr*1024 + cc] = 0.5f*v*(1.0f + erff(v*0.70710678118654752f));
      }
}

// ---------------- router scores ----------------
__global__ __launch_bounds__(256) void scores_kernel(const float* __restrict__ h,
    const float* __restrict__ Wr2, const float* __restrict__ br2,
    float* __restrict__ scores, float* __restrict__ tokmax){
  int tid = threadIdx.x;
  int n = blockIdx.x*4 + (tid>>6);
  int lane = tid & 63;
  const float* hr = h + (size_t)n*1024;
  float s0=0,s1=0,s2=0,s3=0;
  #pragma unroll
  for(int i=0;i<16;i++){
    int j = lane + i*64;
    float hv = hr[j];
    float4 wv = *(const float4*)(Wr2 + (size_t)j*4);
    s0 += hv*wv.x; s1 += hv*wv.y; s2 += hv*wv.z; s3 += hv*wv.w;
  }
  #pragma unroll
  for(int m=32;m>=1;m>>=1){
    s0 += __shfl_xor(s0,m); s1 += __shfl_xor(s1,m);
    s2 += __shfl_xor(s2,m); s3 += __shfl_xor(s3,m);
  }
  if (lane==0){
    s0+=br2[0]; s1+=br2[1]; s2+=br2[2]; s3+=br2[3];
    scores[n*4+0]=s0; scores[n*4+1]=s1; scores[n*4+2]=s2; scores[n*4+3]=s3;
    tokmax[n]=fmaxf(fmaxf(s0,s1),fmaxf(s2,s3));
  }
}

__global__ __launch_bounds__(1024) void aux_kernel(const float* __restrict__ tokmax, float* __restrict__ out_aux){
  __shared__ float red[1024];
  int t = threadIdx.x;
  red[t] = tokmax[t] + tokmax[t+1024] + tokmax[t+2048] + tokmax[t+3072];
  __syncthreads();
  for(int k=512;k>=1;k>>=1){ if(t<k) red[t]+=red[t+k]; __syncthreads(); }
  if (t==0) out_aux[0] = -red[0]/4096.0f;
}

// ---------------- exact top-k via parallel rank (replaces 4-block bitonic) ----------------
// key = (monotonic-flipped fp32)<<32 | (4095-idx): descending score, ties -> lower idx
// (== jax.lax.top_k order). Keys are distinct, so rank = #{j: key_j > key_i} is exact.
__global__ __launch_bounds__(256) void rank_kernel(const float* __restrict__ scores,
    int* __restrict__ topk_idx, float* __restrict__ topv, int* __restrict__ rank_of){
  __shared__ unsigned long long keys[4096];   // 32KB
  const int e = blockIdx.y, blk = blockIdx.x, tid = threadIdx.x;
  for(int i=tid;i<4096;i+=256){
    unsigned u = __float_as_uint(scores[i*4+e]);
    unsigned m = (u & 0x80000000u) ? ~u : (u | 0x80000000u);
    keys[i] = (((unsigned long long)m)<<32) | (unsigned)(4095-i);
  }
  __syncthreads();
  const int i = blk*256 + tid;
  const unsigned long long mykey = keys[i];
  int cnt = 0;
  #pragma unroll 8
  for(int j=0;j<4096;j++) cnt += (keys[j] > mykey) ? 1 : 0;
  if (cnt < CAPN){
    topk_idx[e*CAPN + cnt] = i;
    topv[e*CAPN + cnt]     = scores[i*4+e];
    rank_of[e*4096 + i]    = cnt;
  } else {
    rank_of[e*4096 + i]    = -1;
  }
}

// per-expert softmax over the CAPN sorted top values -> sel_w
__global__ __launch_bounds__(1024) void selw_kernel(const float* __restrict__ topv,
    float* __restrict__ sel_w){
  __shared__ float red[1024];
  const int e = blockIdx.x, t = threadIdx.x;
  const float mx = topv[e*CAPN];        // rank 0 == max
  float p0 = expf(topv[e*CAPN + t] - mx);                              // t < 1280 always
  float p1 = (t + 1024 < CAPN) ? expf(topv[e*CAPN + t + 1024] - mx) : 0.f;
  red[t] = p0 + p1;
  __syncthreads();
  for(int k=512;k>=1;k>>=1){ if(t<k) red[t]+=red[t+k]; __syncthreads(); }
  const float denom = red[0];
  sel_w[e*CAPN + t] = p0/denom;
  if (t + 1024 < CAPN) sel_w[e*CAPN + t + 1024] = p1/denom;
}

// ---------------- RoPE tables [CAPN][64] ----------------
__global__ __launch_bounds__(256) void rope_kernel(float* __restrict__ cosT, float* __restrict__ sinT){
  int idx = blockIdx.x*256 + threadIdx.x;
  int p = idx>>6, dm = idx&63;
  float inv = powf(10000.0f, -(float)dm/64.0f);
  float ang = (float)p*inv;
  cosT[idx]=cosf(ang);
  sinT[idx]=sinf(ang);
}

// ---------------- pre-gather + pre-rope K into swizzled tiles ----------------
__global__ __launch_bounds__(256) void prerope_k_kernel(const unsigned short* __restrict__ kb,
    const int* __restrict__ topk_idx, const float* __restrict__ cosT, const float* __restrict__ sinT,
    unsigned short* __restrict__ Kg){
  int idx = blockIdx.x*256 + threadIdx.x;   // exact 4*16*1280*16
  int ch = idx & 15;
  int rest = idx >> 4;
  int rank = rest % CAPN;
  int he = rest / CAPN;           // e*16+h
  int e = he >> 4, h = he & 15;
  int tok = topk_idx[e*CAPN + rank];
  int d0 = ch*8;
  const unsigned short* krow = kb + (size_t)tok*QKV_STRIDE + h*DH;
  unsigned short held[8], part[8];
  *(uint4*)held = *(const uint4*)(krow + d0);
  *(uint4*)part = *(const uint4*)(krow + (d0^64));
  const float* cr = cosT + rank*64;
  const float* sr = sinT + rank*64;
  float sgn = (d0<64) ? -1.f : 1.f;
  unsigned short outv[8];
  #pragma unroll
  for(int jj=0;jj<8;jj++){
    int dm = (d0+jj)&63;
    outv[jj] = f2bf(bf2f(held[jj])*cr[dm] + sgn*bf2f(part[jj])*sr[dm]);
  }
  int t = rank >> 6, row = rank & 63;
  size_t tbase = ((size_t)(he)*NTILE + t) * 8192;
  *(uint4*)(Kg + tbase + row*128 + ((ch ^ (row&7))<<3)) = *(uint4*)outv;
}

// ---------------- pre-gather + transpose V into swizzled tiles ----------------
__global__ __launch_bounds__(256) void prev_kernel(const unsigned short* __restrict__ vb,
    const int* __restrict__ topk_idx, unsigned short* __restrict__ Vg){
  __shared__ __align__(16) unsigned short T2[128][72];
  int bid = blockIdx.x;           // e*320 + h*20 + t
  int t = bid % NTILE, h = (bid/NTILE) & 15, e = bid/(NTILE*NH);
  int tid = threadIdx.x, lane = tid & 63, dchb = tid >> 6;
  int tok = topk_idx[e*CAPN + t*64 + lane];
  const unsigned short* vrow = vb + (size_t)tok*QKV_STRIDE + h*DH;
  #pragma unroll
  for(int i=0;i<4;i++){
    int d0 = (dchb + i*4)*8;
    unsigned short vv[8];
    *(uint4*)vv = *(const uint4*)(vrow + d0);
    #pragma unroll
    for(int j=0;j<8;j++) T2[d0+j][lane] = vv[j];   // lane-consecutive: conflict-free
  }
  __syncthreads();
  unsigned short* out = Vg + ((size_t)(e*NH+h)*NTILE + t)*8192;
  #pragma unroll
  for(int i=0;i<4;i++){
    int c = i*256 + tid;
    int d = c>>3, ch = c&7;
    *(uint4*)(out + d*64 + ((ch ^ (d&7))<<3)) = *(const uint4*)&T2[d][ch*8];
  }
}

// ---------------- gathered causal flash attention ----------------
__global__ __launch_bounds__(256) void attn_kernel(
    const unsigned short* __restrict__ qb,
    const unsigned short* __restrict__ Kg, const unsigned short* __restrict__ Vg,
    const int* __restrict__ topk_idx, const float* __restrict__ sel_w,
    const float* __restrict__ cosT, const float* __restrict__ sinT,
    unsigned short* __restrict__ oexp){
  __shared__ __align__(16) unsigned short KsA[2][8192];
  __shared__ __align__(16) unsigned short Vs[8192];
  __shared__ __align__(16) unsigned short Ps[4][16][72];
  const int id = blockIdx.x;
  const int xcd = id & 7, s_ = id >> 3;
  const int qt = NTILE - 1 - (s_ % NTILE);          // longest first
  const int grp = (s_ / NTILE)*8 + xcd;             // 0..63
  const int e = grp >> 4, hh = grp & 15;
  const int tid = threadIdx.x, w = tid>>6, lane = tid&63, g = lane>>4, r16 = lane&15;
  const int* idxE = topk_idx + e*CAPN;
  const unsigned short* Kgb = Kg + (size_t)(e*NH+hh)*CAPN*DH;
  const unsigned short* Vgb = Vg + (size_t)(e*NH+hh)*CAPN*DH;

  s16x8 aq[4];
  {
    int qr = qt*64 + w*16 + r16;
    int tok = idxE[qr];
    const unsigned short* qrow = qb + (size_t)tok*QKV_STRIDE + hh*DH;
    const float* cr = cosT + qr*64;
    const float* sr = sinT + qr*64;
    #pragma unroll
    for(int s=0;s<4;s++){
      int d0 = s*32 + 8*g;
      unsigned short held[8], part[8];
      *(uint4*)held = *(const uint4*)(qrow + d0);
      *(uint4*)part = *(const uint4*)(qrow + (d0^64));
      float sgn = (d0<64) ? -1.f : 1.f;
      union{ s16x8 v; unsigned short u[8]; } fr;
      #pragma unroll
      for(int jj=0;jj<8;jj++){
        int dm = (d0+jj)&63;
        float val = bf2f(held[jj])*cr[dm] + sgn*bf2f(part[jj])*sr[dm];
        fr.u[jj] = f2bf(val * (SCALE_QK*LOG2E));
      }
      aq[s] = fr.v;
    }
  }
  float m_r[4], l_r[4];
  f32x4 o[8];
  #pragma unroll
  for(int r=0;r<4;r++){ m_r[r]=-INFINITY; l_r[r]=0.f; }
  #pragma unroll
  for(int f2=0;f2<8;f2++) o[f2]=f32x4{0.f,0.f,0.f,0.f};

  // prologue: K(0), V(0); wait K(0) only (V(0) rides to the mid barrier)
  #pragma unroll
  for(int i=0;i<4;i++){ int c=i*256+tid; gl_lds16(Kgb + c*8, &KsA[0][c*8]); }
  #pragma unroll
  for(int i=0;i<4;i++){ int c=i*256+tid; gl_lds16(Vgb + c*8, &Vs[c*8]); }
  asm volatile("s_waitcnt vmcnt(4)" ::: "memory");
  __builtin_amdgcn_s_barrier();

  for(int kt=0; kt<=qt; kt++){
    const int cur = kt & 1;
    if (kt < qt){
      const unsigned short* Ksrc = Kgb + (size_t)(kt+1)*8192;
      #pragma unroll
      for(int i=0;i<4;i++){ int c=i*256+tid; gl_lds16(Ksrc + c*8, &KsA[cur^1][c*8]); }
    }
    f32x4 sfr[4];
    #pragma unroll
    for(int fc=0;fc<4;fc++){
      f32x4 a4 = f32x4{0.f,0.f,0.f,0.f};
      const int row = fc*16 + r16;
      #pragma unroll
      for(int s=0;s<4;s++){
        s16x8 bk = *(const s16x8*)&KsA[cur][row*128 + (((s*4+g) ^ (r16&7))<<3)];
        a4 = mfma_bf16(aq[s], bk, a4);
      }
      sfr[fc] = a4;
    }
    if (kt==qt){
      #pragma unroll
      for(int fc=0;fc<4;fc++)
        #pragma unroll
        for(int r=0;r<4;r++){
          int qrank  = qt*64 + w*16 + 4*g + r;
          int kvrank = kt*64 + fc*16 + r16;
          if (kvrank > qrank) sfr[fc][r] = NEG_BIG;
        }
    }
    float corr[4];
    bool need = false;
    #pragma unroll
    for(int r=0;r<4;r++){
      float mx = fmaxf(fmaxf(sfr[0][r],sfr[1][r]), fmaxf(sfr[2][r],sfr[3][r]));
      #pragma unroll
      for(int mk=1;mk<16;mk<<=1) mx = fmaxf(mx, __shfl_xor(mx,mk));
      float nm = fmaxf(m_r[r], mx);
      need = need || (nm > m_r[r]);
      corr[r] = exp2f(m_r[r]-nm);
      m_r[r] = nm;
    }
    if (__any(need)){
      #pragma unroll
      for(int f2=0;f2<8;f2++)
        #pragma unroll
        for(int r=0;r<4;r++) o[f2][r] *= corr[r];
      #pragma unroll
      for(int r=0;r<4;r++) l_r[r] *= corr[r];
    }
    float rs[4] = {0.f,0.f,0.f,0.f};
    #pragma unroll
    for(int fc=0;fc<4;fc++)
      #pragma unroll
      for(int r=0;r<4;r++){
        float p = exp2f(sfr[fc][r] - m_r[r]);
        rs[r] += p;
        Ps[w][4*g+r][fc*16+r16] = f2bf(p);
      }
    #pragma unroll
    for(int r=0;r<4;r++){
      float ts = rs[r];
      #pragma unroll
      for(int mk=1;mk<16;mk<<=1) ts += __shfl_xor(ts,mk);
      l_r[r] += ts;
    }
    // mid rendezvous: V(kt) landed (K(kt+1) may stay in flight)
    if (kt < qt) asm volatile("s_waitcnt vmcnt(4)" ::: "memory");
    else         asm volatile("s_waitcnt vmcnt(0)" ::: "memory");
    __builtin_amdgcn_s_barrier();
    #pragma unroll
    for(int ks=0;ks<2;ks++){
      s16x8 pa = *(const s16x8*)&Ps[w][r16][ks*32 + 8*g];
      #pragma unroll
      for(int fd=0;fd<8;fd++){
        const int row = fd*16 + r16;
        s16x8 vf = *(const s16x8*)&Vs[row*64 + (((ks*4+g) ^ (r16&7))<<3)];
        o[fd] = mfma_bf16(pa, vf, o[fd]);
      }
    }
    __builtin_amdgcn_s_barrier();   // PV reads done; Vs safe to overwrite
    if (kt < qt){
      const unsigned short* Vsrc = Vgb + (size_t)(kt+1)*8192;
      #pragma unroll
      for(int i=0;i<4;i++){ int c=i*256+tid; gl_lds16(Vsrc + c*8, &Vs[c*8]); }
      asm volatile("s_waitcnt vmcnt(4)" ::: "memory");
      __builtin_amdgcn_s_barrier();
    }
  }
  #pragma unroll
  for(int r=0;r<4;r++){
    int qrank = qt*64 + w*16 + 4*g + r;
    float fac = sel_w[e*CAPN + qrank] / l_r[r];
    #pragma unroll
    for(int fd=0;fd<8;fd++){
      oexp[((size_t)(e*CAPN + qrank))*E_DIM + hh*DH + fd*16 + r16] = f2bf(o[fd][r]*fac);
    }
  }
}

// ---------------- scatter-accumulate over experts ----------------
__global__ __launch_bounds__(256) void acc_kernel(const unsigned short* __restrict__ oexp,
    const int* __restrict__ rank_of, unsigned short* __restrict__ accb){
  int n = blockIdx.x, t = threadIdx.x;
  int base = t*8;
  float s[8] = {0,0,0,0,0,0,0,0};
  #pragma unroll
  for(int e=0;e<4;e++){
    int r = rank_of[e*4096+n];
    if (r>=0){
      union{uint4 q; unsigned short u[8];} ld;
      ld.q = *(const uint4*)(oexp + ((size_t)(e*CAPN+r))*E_DIM + base);
      #pragma unroll
      for(int j2=0;j2<8;j2++) s[j2] += bf2f(ld.u[j2]);
    }
  }
  union{uint4 q; unsigned short u[8];} st;
  #pragma unroll
  for(int j2=0;j2<8;j2++) st.u[j2] = f2bf(s[j2]);
  *(uint4*)(accb + (size_t)n*E_DIM + base) = st.q;
}

// ---------------- launch ----------------
extern "C" void kernel_launch(void* const* d_in, const int* in_sizes, int n_in,
                              void* d_out, int out_size, void* d_ws, size_t ws_size,
                              hipStream_t stream) {
  const float* x   = (const float*)d_in[0];
  const float* Wq  = (const float*)d_in[1];
  const float* Wk  = (const float*)d_in[2];
  const float* Wv  = (const float*)d_in[3];
  const float* Wo  = (const float*)d_in[4];
  const float* Wr1 = (const float*)d_in[5];
  const float* br1 = (const float*)d_in[6];
  const float* Wr2 = (const float*)d_in[7];
  const float* br2 = (const float*)d_in[8];

  char* ws = (char*)d_ws;
  size_t off = 0;
  auto alloc = [&](size_t bytes)->void*{
    void* p = ws + off;
    off += (bytes + 255) & ~(size_t)255;
    return p;
  };
  unsigned short* xhi   = (unsigned short*)alloc((size_t)N_TOK*E_DIM*2);
  unsigned short* xlo   = (unsigned short*)alloc((size_t)N_TOK*E_DIM*2);
  unsigned short* wr1hi = (unsigned short*)alloc((size_t)E_DIM*1024*2);   // transposed [1024][2048]
  unsigned short* wr1lo = (unsigned short*)alloc((size_t)E_DIM*1024*2);
  unsigned short* wqkvT = (unsigned short*)alloc((size_t)3*E_DIM*E_DIM*2); // [6144][2048]
  unsigned short* woT   = (unsigned short*)alloc((size_t)E_DIM*E_DIM*2);   // contiguous after wqkvT
  void* hv = alloc((size_t)KEXP*NH*CAPN*DH*2);   // max(hbuf 16.8MB, Vg 21MB)
  float* hbuf = (float*)hv;                      // dead after scores_kernel
  unsigned short* Vg = (unsigned short*)hv;      // written by prev_kernel later
  float* scores = (float*)alloc((size_t)N_TOK*4*4);
  float* tokmax = (float*)alloc((size_t)N_TOK*4);
  int*   topkI  = (int*)alloc((size_t)KEXP*CAPN*4);
  float* topv   = (float*)alloc((size_t)KEXP*CAPN*4);
  float* selw   = (float*)alloc((size_t)KEXP*CAPN*4);
  int*   rankof = (int*)alloc((size_t)KEXP*N_TOK*4);
  float* cosT   = (float*)alloc((size_t)CAPN*64*4);
  float* sinT   = (float*)alloc((size_t)CAPN*64*4);
  unsigned short* qkvbuf = (unsigned short*)alloc((size_t)N_TOK*QKV_STRIDE*2);
  unsigned short* oexp = (unsigned short*)alloc((size_t)KEXP*CAPN*E_DIM*2);
  unsigned short* accb = (unsigned short*)alloc((size_t)N_TOK*E_DIM*2);
  if (off > ws_size) return;   // fail loudly (output stays poisoned)

  // Kg (21MB, swizzled) aliases xlo+wr1hi+wr1lo (25.2MB), dead after router GEMM
  unsigned short* Kg = xlo;

  // conversions
  conv_x_kernel<<<(N_TOK*E_DIM/4+255)/256, 256, 0, stream>>>(x, xhi, xlo, N_TOK*E_DIM/4);
  tconv_kernel<<<dim3(1024/32, E_DIM/32), dim3(32,8), 0, stream>>>(Wr1, wr1hi, wr1lo, E_DIM, 1024);
  // fused transpose Wq,Wk,Wv,Wo -> wqkvT(+woT, contiguous)
  tconv4_kernel<<<dim3(E_DIM/32, E_DIM/32, 4), dim3(32,8), 0, stream>>>(Wq, Wk, Wv, Wo, wqkvT);

  // pipelined fused router: H = gelu(x@Wr1 + br1) (hi/lo split)
  gemm_router_p<<<dim3(8, 32), 512, 0, stream>>>(xhi, xlo, wr1hi, wr1lo, br1, hbuf);
  scores_kernel<<<N_TOK/4, 256, 0, stream>>>(hbuf, Wr2, br2, scores, tokmax);
  aux_kernel<<<1, 1024, 0, stream>>>(tokmax, ((float*)d_out) + (size_t)N_TOK*E_DIM);
  // exact top-k via parallel rank + per-expert softmax
  rank_kernel<<<dim3(16, KEXP), 256, 0, stream>>>(scores, topkI, topv, rankof);
  selw_kernel<<<KEXP, 1024, 0, stream>>>(topv, selw);
  rope_kernel<<<CAPN*64/256, 256, 0, stream>>>(cosT, sinT);

  // fused QKV projection: [4096][6144] via 128x256 2-phase pipelined GEMM (3.0 exact rounds)
  gemm_p<1><<<dim3(QKV_STRIDE/256, N_TOK/128), 512, 0, stream>>>(xhi, wqkvT, qkvbuf, QKV_STRIDE, E_DIM);

  // pre-gather/rope/transpose K,V into dense swizzled tiles
  prerope_k_kernel<<<KEXP*NH*CAPN*16/256, 256, 0, stream>>>(qkvbuf + E_DIM, topkI, cosT, sinT, Kg);
  prev_kernel<<<KEXP*NH*NTILE, 256, 0, stream>>>(qkvbuf + 2*E_DIM, topkI, Vg);

  // gathered causal attention
  attn_kernel<<<KEXP*NH*NTILE, 256, 0, stream>>>(qkvbuf, Kg, Vg, topkI, selw, cosT, sinT, oexp);

  // scatter-accumulate experts -> token rows
  acc_kernel<<<N_TOK, 256, 0, stream>>>(oexp, rankof, accb);

  // final projection -> d_out (128x256 pipelined, 256 blocks = 1.0 exact round)
  gemm_p<0><<<dim3(E_DIM/256, N_TOK/128), 512, 0, stream>>>(accb, woT, (float*)d_out, E_DIM, E_DIM);
}

// Round 9
// 445.928 us; speedup vs baseline: 1.3540x; 1.0052x over previous
//
#include <hip/hip_runtime.h>
#include <cstdint>
#include <cstddef>

// Problem constants
#define N_TOK 4096
#define E_DIM 2048
#define NH    16
#define DH    128
#define KEXP  4
#define CAPN  1280
#define NTILE 20                 // CAPN/64
#define QKV_STRIDE 6144          // fused QKV output row stride
#define SCALE_QK 0.08838834764831845f
#define LOG2E    1.4426950408889634f
#define NEG_BIG -1e30f

typedef __attribute__((ext_vector_type(4))) float f32x4;
typedef __attribute__((ext_vector_type(8))) short s16x8;

__device__ __forceinline__ float bf2f(unsigned short u){
  union{unsigned int i; float fl;} c; c.i = ((unsigned int)u)<<16; return c.fl;
}
__device__ __forceinline__ unsigned short f2bf(float x){
  union{float fl; unsigned int i;} c; c.fl=x;
  return (unsigned short)((c.i + 0x7FFFu + ((c.i>>16)&1u))>>16);
}
__device__ __forceinline__ f32x4 mfma_bf16(s16x8 a, s16x8 b, f32x4 c){
  asm("v_mfma_f32_16x16x32_bf16 %0, %1, %2, %0" : "+v"(c) : "v"(a), "v"(b));
  return c;
}
// async global->LDS 16B: LDS dest must be lane-linear (base + lane*16)
__device__ __forceinline__ void gl_lds16(const unsigned short* g, unsigned short* l){
  __builtin_amdgcn_global_load_lds(
      (const __attribute__((address_space(1))) unsigned int*)g,
      (__attribute__((address_space(3))) unsigned int*)l, 16, 0, 0);
}

// ---------------- conversions ----------------
__global__ __launch_bounds__(256) void conv_x_kernel(const float* __restrict__ x,
    unsigned short* __restrict__ hi, unsigned short* __restrict__ lo, int n4){
  int idx = blockIdx.x*256 + threadIdx.x;
  if (idx >= n4) return;
  float4 v = ((const float4*)x)[idx];
  float ar[4] = {v.x, v.y, v.z, v.w};
  union{ unsigned short u[4]; uint2 q; } H, L;
  #pragma unroll
  for(int i=0;i<4;i++){
    unsigned short h = f2bf(ar[i]);
    H.u[i] = h;
    L.u[i] = f2bf(ar[i] - bf2f(h));
  }
  ((uint2*)hi)[idx] = H.q;
  ((uint2*)lo)[idx] = L.q;
}

// transpose + f32->bf16 (optionally also lo residual). W[R][C] -> T[C][R]
__global__ __launch_bounds__(256) void tconv_kernel(const float* __restrict__ W,
    unsigned short* __restrict__ Thi, unsigned short* __restrict__ Tlo, int R, int C){
  __shared__ float t[32][33];
  int tx = threadIdx.x, ty = threadIdx.y;   // (32,8)
  int c0 = blockIdx.x*32, r0 = blockIdx.y*32;
  #pragma unroll
  for(int i=0;i<4;i++){
    int r = r0 + ty + i*8;
    t[ty+i*8][tx] = W[(size_t)r*C + c0 + tx];
  }
  __syncthreads();
  #pragma unroll
  for(int i=0;i<4;i++){
    int c = c0 + ty + i*8;
    float v = t[tx][ty+i*8];
    size_t o = (size_t)c*R + r0 + tx;
    unsigned short h = f2bf(v);
    Thi[o] = h;
    if (Tlo) Tlo[o] = f2bf(v - bf2f(h));
  }
}

// fused transpose of 4 ExE weights (Wq,Wk,Wv,Wo) -> contiguous [4][E][E] bf16
__global__ __launch_bounds__(256) void tconv4_kernel(const float* __restrict__ W0,
    const float* __restrict__ W1, const float* __restrict__ W2, const float* __restrict__ W3,
    unsigned short* __restrict__ out){
  __shared__ float t[32][33];
  int z = blockIdx.z;
  const float* W = (z==0)?W0 : (z==1)?W1 : (z==2)?W2 : W3;
  unsigned short* T = out + (size_t)z*E_DIM*E_DIM;
  int tx = threadIdx.x, ty = threadIdx.y;   // (32,8)
  int c0 = blockIdx.x*32, r0 = blockIdx.y*32;
  #pragma unroll
  for(int i=0;i<4;i++){
    int r = r0 + ty + i*8;
    t[ty+i*8][tx] = W[(size_t)r*E_DIM + c0 + tx];
  }
  __syncthreads();
  #pragma unroll
  for(int i=0;i<4;i++){
    int c = c0 + ty + i*8;
    T[(size_t)c*E_DIM + r0 + tx] = f2bf(t[tx][ty+i*8]);
  }
}

// ============ 128x256 BK=32-slab 5-slot-ring pipelined GEMM (T2+T3+T4+T5) ============
// C[M][N] = A[M][K] * Bt[N][K]^T. 512 thr = 8 waves 2Mx4N, wave tile 64x64.
// Phase P = K-column-slab 32*P. LDS ring of 5 slots (A 4096 + B 8192 shorts each,
// 120KB): read slot P%5, stage phase P+4 into slot (P+4)%5 (= (P-1)%5, whose readers
// finished before barrier(P-1)). One barrier/phase; reads/stage/MFMA interleave freely.
// Steady vmcnt(9) = 3 stage-units x 3 loads in flight; issue-to-wait = 3 phases
// (~1900cy >> HBM latency); epilogue degrades 9->6->3->0. Queue never drains mid-loop.
// Swizzle (verified r7): LDS(row,ch)=G(row, ch^((row>>1)&3)); read chunk g^((r16>>1)&3).
template<int OUTBF>
__global__ __launch_bounds__(512, 1) void gemm_p(
    const unsigned short* __restrict__ A, const unsigned short* __restrict__ Bt,
    void* __restrict__ Cp, int N, int Kd){
  __shared__ __align__(16) unsigned short lds[5*12288];   // 120 KB
  const int tid = threadIdx.x;
  const int w = tid>>6, lane = tid&63, g = lane>>4, r16 = lane&15;
  const int wm = w>>2, wn = w&3;                   // 2M x 4N waves
  const int mb = blockIdx.y, nb = blockIdx.x;
  const unsigned short* Ab = A  + (size_t)mb*128*Kd;
  const unsigned short* Bb = Bt + (size_t)nb*256*Kd;
  const int PMAX = Kd >> 5;                        // K/32 phases

  f32x4 acc[4][4];
  #pragma unroll
  for(int i=0;i<4;i++)
    #pragma unroll
    for(int j=0;j<4;j++) acc[i][j] = f32x4{0.f,0.f,0.f,0.f};

  // stage phase Pst (K columns 32*Pst..+32) into slot
  auto stageP = [&](int Pst, int slot){
    unsigned short* base = &lds[slot*12288];
    const int col = Pst*32;
    {
      int row = tid>>2, ch = tid&3;
      int sc = ch ^ ((row>>1)&3);
      gl_lds16(Ab + (size_t)row*Kd + col + sc*8, base + tid*8);
    }
    #pragma unroll
    for(int i=0;i<2;i++){
      int n = i*512 + tid;
      int rw = n>>2, c2 = n&3;
      int s2 = c2 ^ ((rw>>1)&3);
      gl_lds16(Bb + (size_t)rw*Kd + col + s2*8, base + 4096 + n*8);
    }
  };
  const int xoff = (g ^ ((r16>>1)&3)) << 3;

  // prologue: phases 0..3 into slots 0..3 (12 loads); wait phase-0's unit
  stageP(0,0); stageP(1,1); stageP(2,2); stageP(3,3);
  asm volatile("s_waitcnt vmcnt(9)" ::: "memory");
  __builtin_amdgcn_s_barrier();

  int sR = 0, sW = 4;
  for(int P=0; P<PMAX; ++P){
    const unsigned short* base = &lds[sR*12288];
    s16x8 af[4], bfv[4];
    #pragma unroll
    for(int mf=0;mf<4;mf++)
      af[mf] = *(const s16x8*)&base[(wm*64 + mf*16 + r16)*32 + xoff];
    #pragma unroll
    for(int nf=0;nf<4;nf++)
      bfv[nf] = *(const s16x8*)&base[4096 + (wn*64 + nf*16 + r16)*32 + xoff];
    if (P+4 < PMAX) stageP(P+4, sW);
    __builtin_amdgcn_s_setprio(1);
    #pragma unroll
    for(int mf=0;mf<4;mf++)
      #pragma unroll
      for(int nf=0;nf<4;nf++)
        acc[mf][nf] = mfma_bf16(af[mf], bfv[nf], acc[mf][nf]);
    __builtin_amdgcn_s_setprio(0);
    // guard next phase's slot (staged at P-3): allow the 3 newer units in flight
    if      (P+4 < PMAX) asm volatile("s_waitcnt vmcnt(9)" ::: "memory");
    else if (P+3 < PMAX) asm volatile("s_waitcnt vmcnt(6)" ::: "memory");
    else if (P+2 < PMAX) asm volatile("s_waitcnt vmcnt(3)" ::: "memory");
    else                 asm volatile("s_waitcnt vmcnt(0)" ::: "memory");
    __builtin_amdgcn_s_barrier();
    sR = (sR==4) ? 0 : sR+1;
    sW = (sW==4) ? 0 : sW+1;
  }

  const int rowb = mb*128 + wm*64, colb = nb*256 + wn*64;
  #pragma unroll
  for(int mf=0;mf<4;mf++)
    #pragma unroll
    for(int nf=0;nf<4;nf++)
      #pragma unroll
      for(int r=0;r<4;r++){
        int rr = rowb + mf*16 + 4*g + r;
        int cc = colb + nf*16 + r16;
        size_t o = (size_t)rr*N + cc;
        if (OUTBF) ((unsigned short*)Cp)[o] = f2bf(acc[mf][nf][r]);
        else       ((float*)Cp)[o] = acc[mf][nf][r];
      }
}

// ============ pipelined router GEMM: H = gelu(x@Wr1 + br1), hi/lo split ============
__global__ __launch_bounds__(512, 1) void gemm_router_p(
    const unsigned short* __restrict__ Ahi, const unsigned short* __restrict__ Alo,
    const unsigned short* __restrict__ Bhi, const unsigned short* __restrict__ Blo,
    const float* __restrict__ br1, float* __restrict__ H){
  __shared__ __align__(16) unsigned short lds[2][32768];
  const int tid = threadIdx.x;
  const int w = tid>>6, lane = tid&63, g = lane>>4, r16 = lane&15;
  const int wm = w>>2, wn = w&3;                   // 2M x 4N waves, tile 64x32
  const int mb = blockIdx.y, nb = blockIdx.x;
  const unsigned short* AbH = Ahi + (size_t)mb*128*E_DIM;
  const unsigned short* AbL = Alo + (size_t)mb*128*E_DIM;
  const unsigned short* BbH = Bhi + (size_t)nb*128*E_DIM;
  const unsigned short* BbL = Blo + (size_t)nb*128*E_DIM;
  const int NT = E_DIM >> 6;   // 32

  f32x4 acc[4][2];
  #pragma unroll
  for(int i=0;i<4;i++){ acc[i][0]=f32x4{0.f,0.f,0.f,0.f}; acc[i][1]=f32x4{0.f,0.f,0.f,0.f}; }

  auto stage = [&](int buf, int ks, int t){   // 4 slabs x (128x32), 1 load/thread each
    int row = tid>>2, ch = tid&3;
    int sc = ch ^ ((row>>1)&3);
    size_t go = (size_t)row*E_DIM + t*64 + ks*32 + sc*8;
    unsigned short* base = &lds[buf][ks*16384];
    gl_lds16(AbH + go, base +         tid*8);
    gl_lds16(AbL + go, base +  4096 + tid*8);
    gl_lds16(BbH + go, base +  8192 + tid*8);
    gl_lds16(BbL + go, base + 12288 + tid*8);
  };
  const int xoff = (g ^ ((r16>>1)&3)) << 3;

  stage(0,0,0); stage(0,1,0); stage(1,0,1);
  asm volatile("s_waitcnt vmcnt(8)" ::: "memory");
  __builtin_amdgcn_s_barrier();

  int cur = 0;
  for(int t=0; t<NT; ++t){
    const int nxt = cur^1;
    #pragma unroll
    for(int ph=0; ph<2; ph++){
      const unsigned short* base = &lds[cur][ph*16384];
      s16x8 ah[4], al[4], bh[2], bl[2];
      #pragma unroll
      for(int mf=0;mf<4;mf++){
        int ro = (wm*64 + mf*16 + r16)*32 + xoff;
        ah[mf] = *(const s16x8*)&base[ro];
        al[mf] = *(const s16x8*)&base[4096 + ro];
      }
      #pragma unroll
      for(int nf=0;nf<2;nf++){
        int ro = (wn*32 + nf*16 + r16)*32 + xoff;
        bh[nf] = *(const s16x8*)&base[8192 + ro];
        bl[nf] = *(const s16x8*)&base[12288 + ro];
      }
      if (ph==0){
        if (t+1 < NT){ stage(nxt,1,t+1); asm volatile("s_waitcnt vmcnt(8)" ::: "memory"); }
        else         {                   asm volatile("s_waitcnt vmcnt(0)" ::: "memory"); }
      } else {
        if (t+2 < NT){ stage(cur,0,t+2); asm volatile("s_waitcnt vmcnt(8)" ::: "memory"); }
        else if (t+1 < NT){              asm volatile("s_waitcnt vmcnt(4)" ::: "memory"); }
        else              {              asm volatile("s_waitcnt vmcnt(0)" ::: "memory"); }
      }
      __builtin_amdgcn_s_barrier();
      __builtin_amdgcn_s_setprio(1);
      #pragma unroll
      for(int mf=0;mf<4;mf++)
        #pragma unroll
        for(int nf=0;nf<2;nf++){
          acc[mf][nf] = mfma_bf16(ah[mf], bh[nf], acc[mf][nf]);
          acc[mf][nf] = mfma_bf16(ah[mf], bl[nf], acc[mf][nf]);
          acc[mf][nf] = mfma_bf16(al[mf], bh[nf], acc[mf][nf]);
        }
      __builtin_amdgcn_s_setprio(0);
      __builtin_amdgcn_s_barrier();
    }
    cur ^= 1;
  }

  const int rowb = mb*128 + wm*64, colb = nb*128 + wn*32;
  #pragma unroll
  for(int mf=0;mf<4;mf++)
    #pragma unroll
    for(int nf=0;nf<2;nf++)
      #pragma unroll
      for(int r=0;r<4;r++){
        int rr = rowb + mf*16 + 4*g + r;
        int cc = colb + nf*16 + r16;
        float v = acc[mf][nf][r] + br1[cc];
        H[(size_t)rr*1024 + cc] = 0.5f*v*(1.0f + erff(v*0.70710678118654752f));
      }
}

// ---------------- router scores ----------------
__global__ __launch_bounds__(256) void scores_kernel(const float* __restrict__ h,
    const float* __restrict__ Wr2, const float* __restrict__ br2,
    float* __restrict__ scores, float* __restrict__ tokmax){
  int tid = threadIdx.x;
  int n = blockIdx.x*4 + (tid>>6);
  int lane = tid & 63;
  const float* hr = h + (size_t)n*1024;
  float s0=0,s1=0,s2=0,s3=0;
  #pragma unroll
  for(int i=0;i<16;i++){
    int j = lane + i*64;
    float hv = hr[j];
    float4 wv = *(const float4*)(Wr2 + (size_t)j*4);
    s0 += hv*wv.x; s1 += hv*wv.y; s2 += hv*wv.z; s3 += hv*wv.w;
  }
  #pragma unroll
  for(int m=32;m>=1;m>>=1){
    s0 += __shfl_xor(s0,m); s1 += __shfl_xor(s1,m);
    s2 += __shfl_xor(s2,m); s3 += __shfl_xor(s3,m);
  }
  if (lane==0){
    s0+=br2[0]; s1+=br2[1]; s2+=br2[2]; s3+=br2[3];
    scores[n*4+0]=s0; scores[n*4+1]=s1; scores[n*4+2]=s2; scores[n*4+3]=s3;
    tokmax[n]=fmaxf(fmaxf(s0,s1),fmaxf(s2,s3));
  }
}

__global__ __launch_bounds__(1024) void aux_kernel(const float* __restrict__ tokmax, float* __restrict__ out_aux){
  __shared__ float red[1024];
  int t = threadIdx.x;
  red[t] = tokmax[t] + tokmax[t+1024] + tokmax[t+2048] + tokmax[t+3072];
  __syncthreads();
  for(int k=512;k>=1;k>>=1){ if(t<k) red[t]+=red[t+k]; __syncthreads(); }
  if (t==0) out_aux[0] = -red[0]/4096.0f;
}

// ---------------- exact top-k via parallel rank ----------------
__global__ __launch_bounds__(256) void rank_kernel(const float* __restrict__ scores,
    int* __restrict__ topk_idx, float* __restrict__ topv, int* __restrict__ rank_of){
  __shared__ unsigned long long keys[4096];   // 32KB
  const int e = blockIdx.y, blk = blockIdx.x, tid = threadIdx.x;
  for(int i=tid;i<4096;i+=256){
    unsigned u = __float_as_uint(scores[i*4+e]);
    unsigned m = (u & 0x80000000u) ? ~u : (u | 0x80000000u);
    keys[i] = (((unsigned long long)m)<<32) | (unsigned)(4095-i);
  }
  __syncthreads();
  const int i = blk*256 + tid;
  const unsigned long long mykey = keys[i];
  int cnt = 0;
  #pragma unroll 8
  for(int j=0;j<4096;j++) cnt += (keys[j] > mykey) ? 1 : 0;
  if (cnt < CAPN){
    topk_idx[e*CAPN + cnt] = i;
    topv[e*CAPN + cnt]     = scores[i*4+e];
    rank_of[e*4096 + i]    = cnt;
  } else {
    rank_of[e*4096 + i]    = -1;
  }
}

// per-expert softmax over the CAPN sorted top values -> sel_w
__global__ __launch_bounds__(1024) void selw_kernel(const float* __restrict__ topv,
    float* __restrict__ sel_w){
  __shared__ float red[1024];
  const int e = blockIdx.x, t = threadIdx.x;
  const float mx = topv[e*CAPN];        // rank 0 == max
  float p0 = expf(topv[e*CAPN + t] - mx);
  float p1 = (t + 1024 < CAPN) ? expf(topv[e*CAPN + t + 1024] - mx) : 0.f;
  red[t] = p0 + p1;
  __syncthreads();
  for(int k=512;k>=1;k>>=1){ if(t<k) red[t]+=red[t+k]; __syncthreads(); }
  const float denom = red[0];
  sel_w[e*CAPN + t] = p0/denom;
  if (t + 1024 < CAPN) sel_w[e*CAPN + t + 1024] = p1/denom;
}

// ---------------- RoPE tables [CAPN][64] ----------------
__global__ __launch_bounds__(256) void rope_kernel(float* __restrict__ cosT, float* __restrict__ sinT){
  int idx = blockIdx.x*256 + threadIdx.x;
  int p = idx>>6, dm = idx&63;
  float inv = powf(10000.0f, -(float)dm/64.0f);
  float ang = (float)p*inv;
  cosT[idx]=cosf(ang);
  sinT[idx]=sinf(ang);
}

// ---------------- pre-gather + pre-rope K into swizzled tiles ----------------
__global__ __launch_bounds__(256) void prerope_k_kernel(const unsigned short* __restrict__ kb,
    const int* __restrict__ topk_idx, const float* __restrict__ cosT, const float* __restrict__ sinT,
    unsigned short* __restrict__ Kg){
  int idx = blockIdx.x*256 + threadIdx.x;   // exact 4*16*1280*16
  int ch = idx & 15;
  int rest = idx >> 4;
  int rank = rest % CAPN;
  int he = rest / CAPN;           // e*16+h
  int e = he >> 4, h = he & 15;
  int tok = topk_idx[e*CAPN + rank];
  int d0 = ch*8;
  const unsigned short* krow = kb + (size_t)tok*QKV_STRIDE + h*DH;
  unsigned short held[8], part[8];
  *(uint4*)held = *(const uint4*)(krow + d0);
  *(uint4*)part = *(const uint4*)(krow + (d0^64));
  const float* cr = cosT + rank*64;
  const float* sr = sinT + rank*64;
  float sgn = (d0<64) ? -1.f : 1.f;
  unsigned short outv[8];
  #pragma unroll
  for(int jj=0;jj<8;jj++){
    int dm = (d0+jj)&63;
    outv[jj] = f2bf(bf2f(held[jj])*cr[dm] + sgn*bf2f(part[jj])*sr[dm]);
  }
  int t = rank >> 6, row = rank & 63;
  size_t tbase = ((size_t)(he)*NTILE + t) * 8192;
  *(uint4*)(Kg + tbase + row*128 + ((ch ^ (row&7))<<3)) = *(uint4*)outv;
}

// ---------------- pre-gather + transpose V into swizzled tiles ----------------
__global__ __launch_bounds__(256) void prev_kernel(const unsigned short* __restrict__ vb,
    const int* __restrict__ topk_idx, unsigned short* __restrict__ Vg){
  __shared__ __align__(16) unsigned short T2[128][72];
  int bid = blockIdx.x;           // e*320 + h*20 + t
  int t = bid % NTILE, h = (bid/NTILE) & 15, e = bid/(NTILE*NH);
  int tid = threadIdx.x, lane = tid & 63, dchb = tid >> 6;
  int tok = topk_idx[e*CAPN + t*64 + lane];
  const unsigned short* vrow = vb + (size_t)tok*QKV_STRIDE + h*DH;
  #pragma unroll
  for(int i=0;i<4;i++){
    int d0 = (dchb + i*4)*8;
    unsigned short vv[8];
    *(uint4*)vv = *(const uint4*)(vrow + d0);
    #pragma unroll
    for(int j=0;j<8;j++) T2[d0+j][lane] = vv[j];   // lane-consecutive: conflict-free
  }
  __syncthreads();
  unsigned short* out = Vg + ((size_t)(e*NH+h)*NTILE + t)*8192;
  #pragma unroll
  for(int i=0;i<4;i++){
    int c = i*256 + tid;
    int d = c>>3, ch = c&7;
    *(uint4*)(out + d*64 + ((ch ^ (d&7))<<3)) = *(const uint4*)&T2[d][ch*8];
  }
}

// ---------------- gathered causal flash attention ----------------
__global__ __launch_bounds__(256) void attn_kernel(
    const unsigned short* __restrict__ qb,
    const unsigned short* __restrict__ Kg, const unsigned short* __restrict__ Vg,
    const int* __restrict__ topk_idx, const float* __restrict__ sel_w,
    const float* __restrict__ cosT, const float* __restrict__ sinT,
    unsigned short* __restrict__ oexp){
  __shared__ __align__(16) unsigned short KsA[2][8192];
  __shared__ __align__(16) unsigned short Vs[8192];
  __shared__ __align__(16) unsigned short Ps[4][16][72];
  const int id = blockIdx.x;
  const int xcd = id & 7, s_ = id >> 3;
  const int qt = NTILE - 1 - (s_ % NTILE);          // longest first
  const int grp = (s_ / NTILE)*8 + xcd;             // 0..63
  const int e = grp >> 4, hh = grp & 15;
  const int tid = threadIdx.x, w = tid>>6, lane = tid&63, g = lane>>4, r16 = lane&15;
  const int* idxE = topk_idx + e*CAPN;
  const unsigned short* Kgb = Kg + (size_t)(e*NH+hh)*CAPN*DH;
  const unsigned short* Vgb = Vg + (size_t)(e*NH+hh)*CAPN*DH;

  s16x8 aq[4];
  {
    int qr = qt*64 + w*16 + r16;
    int tok = idxE[qr];
    const unsigned short* qrow = qb + (size_t)tok*QKV_STRIDE + hh*DH;
    const float* cr = cosT + qr*64;
    const float* sr = sinT + qr*64;
    #pragma unroll
    for(int s=0;s<4;s++){
      int d0 = s*32 + 8*g;
      unsigned short held[8], part[8];
      *(uint4*)held = *(const uint4*)(qrow + d0);
      *(uint4*)part = *(const uint4*)(qrow + (d0^64));
      float sgn = (d0<64) ? -1.f : 1.f;
      union{ s16x8 v; unsigned short u[8]; } fr;
      #pragma unroll
      for(int jj=0;jj<8;jj++){
        int dm = (d0+jj)&63;
        float val = bf2f(held[jj])*cr[dm] + sgn*bf2f(part[jj])*sr[dm];
        fr.u[jj] = f2bf(val * (SCALE_QK*LOG2E));
      }
      aq[s] = fr.v;
    }
  }
  float m_r[4], l_r[4];
  f32x4 o[8];
  #pragma unroll
  for(int r=0;r<4;r++){ m_r[r]=-INFINITY; l_r[r]=0.f; }
  #pragma unroll
  for(int f2=0;f2<8;f2++) o[f2]=f32x4{0.f,0.f,0.f,0.f};

  // prologue: K(0), V(0); wait K(0) only (V(0) rides to the mid barrier)
  #pragma unroll
  for(int i=0;i<4;i++){ int c=i*256+tid; gl_lds16(Kgb + c*8, &KsA[0][c*8]); }
  #pragma unroll
  for(int i=0;i<4;i++){ int c=i*256+tid; gl_lds16(Vgb + c*8, &Vs[c*8]); }
  asm volatile("s_waitcnt vmcnt(4)" ::: "memory");
  __builtin_amdgcn_s_barrier();

  for(int kt=0; kt<=qt; kt++){
    const int cur = kt & 1;
    if (kt < qt){
      const unsigned short* Ksrc = Kgb + (size_t)(kt+1)*8192;
      #pragma unroll
      for(int i=0;i<4;i++){ int c=i*256+tid; gl_lds16(Ksrc + c*8, &KsA[cur^1][c*8]); }
    }
    f32x4 sfr[4];
    #pragma unroll
    for(int fc=0;fc<4;fc++){
      f32x4 a4 = f32x4{0.f,0.f,0.f,0.f};
      const int row = fc*16 + r16;
      #pragma unroll
      for(int s=0;s<4;s++){
        s16x8 bk = *(const s16x8*)&KsA[cur][row*128 + (((s*4+g) ^ (r16&7))<<3)];
        a4 = mfma_bf16(aq[s], bk, a4);
      }
      sfr[fc] = a4;
    }
    if (kt==qt){
      #pragma unroll
      for(int fc=0;fc<4;fc++)
        #pragma unroll
        for(int r=0;r<4;r++){
          int qrank  = qt*64 + w*16 + 4*g + r;
          int kvrank = kt*64 + fc*16 + r16;
          if (kvrank > qrank) sfr[fc][r] = NEG_BIG;
        }
    }
    float corr[4];
    bool need = false;
    #pragma unroll
    for(int r=0;r<4;r++){
      float mx = fmaxf(fmaxf(sfr[0][r],sfr[1][r]), fmaxf(sfr[2][r],sfr[3][r]));
      #pragma unroll
      for(int mk=1;mk<16;mk<<=1) mx = fmaxf(mx, __shfl_xor(mx,mk));
      float nm = fmaxf(m_r[r], mx);
      need = need || (nm > m_r[r]);
      corr[r] = exp2f(m_r[r]-nm);
      m_r[r] = nm;
    }
    if (__any(need)){
      #pragma unroll
      for(int f2=0;f2<8;f2++)
        #pragma unroll
        for(int r=0;r<4;r++) o[f2][r] *= corr[r];
      #pragma unroll
      for(int r=0;r<4;r++) l_r[r] *= corr[r];
    }
    float rs[4] = {0.f,0.f,0.f,0.f};
    #pragma unroll
    for(int fc=0;fc<4;fc++)
      #pragma unroll
      for(int r=0;r<4;r++){
        float p = exp2f(sfr[fc][r] - m_r[r]);
        rs[r] += p;
        Ps[w][4*g+r][fc*16+r16] = f2bf(p);
      }
    #pragma unroll
    for(int r=0;r<4;r++){
      float ts = rs[r];
      #pragma unroll
      for(int mk=1;mk<16;mk<<=1) ts += __shfl_xor(ts,mk);
      l_r[r] += ts;
    }
    // mid rendezvous: V(kt) landed (K(kt+1) may stay in flight)
    if (kt < qt) asm volatile("s_waitcnt vmcnt(4)" ::: "memory");
    else         asm volatile("s_waitcnt vmcnt(0)" ::: "memory");
    __builtin_amdgcn_s_barrier();
    #pragma unroll
    for(int ks=0;ks<2;ks++){
      s16x8 pa = *(const s16x8*)&Ps[w][r16][ks*32 + 8*g];
      #pragma unroll
      for(int fd=0;fd<8;fd++){
        const int row = fd*16 + r16;
        s16x8 vf = *(const s16x8*)&Vs[row*64 + (((ks*4+g) ^ (r16&7))<<3)];
        o[fd] = mfma_bf16(pa, vf, o[fd]);
      }
    }
    __builtin_amdgcn_s_barrier();   // PV reads done; Vs safe to overwrite
    if (kt < qt){
      const unsigned short* Vsrc = Vgb + (size_t)(kt+1)*8192;
      #pragma unroll
      for(int i=0;i<4;i++){ int c=i*256+tid; gl_lds16(Vsrc + c*8, &Vs[c*8]); }
      asm volatile("s_waitcnt vmcnt(4)" ::: "memory");
      __builtin_amdgcn_s_barrier();
    }
  }
  #pragma unroll
  for(int r=0;r<4;r++){
    int qrank = qt*64 + w*16 + 4*g + r;
    float fac = sel_w[e*CAPN + qrank] / l_r[r];
    #pragma unroll
    for(int fd=0;fd<8;fd++){
      oexp[((size_t)(e*CAPN + qrank))*E_DIM + hh*DH + fd*16 + r16] = f2bf(o[fd][r]*fac);
    }
  }
}

// ---------------- scatter-accumulate over experts ----------------
__global__ __launch_bounds__(256) void acc_kernel(const unsigned short* __restrict__ oexp,
    const int* __restrict__ rank_of, unsigned short* __restrict__ accb){
  int n = blockIdx.x, t = threadIdx.x;
  int base = t*8;
  float s[8] = {0,0,0,0,0,0,0,0};
  #pragma unroll
  for(int e=0;e<4;e++){
    int r = rank_of[e*4096+n];
    if (r>=0){
      union{uint4 q; unsigned short u[8];} ld;
      ld.q = *(const uint4*)(oexp + ((size_t)(e*CAPN+r))*E_DIM + base);
      #pragma unroll
      for(int j2=0;j2<8;j2++) s[j2] += bf2f(ld.u[j2]);
    }
  }
  union{uint4 q; unsigned short u[8];} st;
  #pragma unroll
  for(int j2=0;j2<8;j2++) st.u[j2] = f2bf(s[j2]);
  *(uint4*)(accb + (size_t)n*E_DIM + base) = st.q;
}

// ---------------- launch ----------------
extern "C" void kernel_launch(void* const* d_in, const int* in_sizes, int n_in,
                              void* d_out, int out_size, void* d_ws, size_t ws_size,
                              hipStream_t stream) {
  const float* x   = (const float*)d_in[0];
  const float* Wq  = (const float*)d_in[1];
  const float* Wk  = (const float*)d_in[2];
  const float* Wv  = (const float*)d_in[3];
  const float* Wo  = (const float*)d_in[4];
  const float* Wr1 = (const float*)d_in[5];
  const float* br1 = (const float*)d_in[6];
  const float* Wr2 = (const float*)d_in[7];
  const float* br2 = (const float*)d_in[8];

  char* ws = (char*)d_ws;
  size_t off = 0;
  auto alloc = [&](size_t bytes)->void*{
    void* p = ws + off;
    off += (bytes + 255) & ~(size_t)255;
    return p;
  };
  unsigned short* xhi   = (unsigned short*)alloc((size_t)N_TOK*E_DIM*2);
  unsigned short* xlo   = (unsigned short*)alloc((size_t)N_TOK*E_DIM*2);
  unsigned short* wr1hi = (unsigned short*)alloc((size_t)E_DIM*1024*2);   // transposed [1024][2048]
  unsigned short* wr1lo = (unsigned short*)alloc((size_t)E_DIM*1024*2);
  unsigned short* wqkvT = (unsigned short*)alloc((size_t)3*E_DIM*E_DIM*2); // [6144][2048]
  unsigned short* woT   = (unsigned short*)alloc((size_t)E_DIM*E_DIM*2);   // contiguous after wqkvT
  void* hv = alloc((size_t)KEXP*NH*CAPN*DH*2);   // max(hbuf 16.8MB, Vg 21MB)
  float* hbuf = (float*)hv;                      // dead after scores_kernel
  unsigned short* Vg = (unsigned short*)hv;      // written by prev_kernel later
  float* scores = (float*)alloc((size_t)N_TOK*4*4);
  float* tokmax = (float*)alloc((size_t)N_TOK*4);
  int*   topkI  = (int*)alloc((size_t)KEXP*CAPN*4);
  float* topv   = (float*)alloc((size_t)KEXP*CAPN*4);
  float* selw   = (float*)alloc((size_t)KEXP*CAPN*4);
  int*   rankof = (int*)alloc((size_t)KEXP*N_TOK*4);
  float* cosT   = (float*)alloc((size_t)CAPN*64*4);
  float* sinT   = (float*)alloc((size_t)CAPN*64*4);
  unsigned short* qkvbuf = (unsigned short*)alloc((size_t)N_TOK*QKV_STRIDE*2);
  unsigned short* oexp = (unsigned short*)alloc((size_t)KEXP*CAPN*E_DIM*2);
  unsigned short* accb = (unsigned short*)alloc((size_t)N_TOK*E_DIM*2);
  if (off > ws_size) return;   // fail loudly (output stays poisoned)

  // Kg (21MB, swizzled) aliases xlo+wr1hi+wr1lo (25.2MB), dead after router GEMM
  unsigned short* Kg = xlo;

  // conversions
  conv_x_kernel<<<(N_TOK*E_DIM/4+255)/256, 256, 0, stream>>>(x, xhi, xlo, N_TOK*E_DIM/4);
  tconv_kernel<<<dim3(1024/32, E_DIM/32), dim3(32,8), 0, stream>>>(Wr1, wr1hi, wr1lo, E_DIM, 1024);
  // fused transpose Wq,Wk,Wv,Wo -> wqkvT(+woT, contiguous)
  tconv4_kernel<<<dim3(E_DIM/32, E_DIM/32, 4), dim3(32,8), 0, stream>>>(Wq, Wk, Wv, Wo, wqkvT);

  // pipelined fused router: H = gelu(x@Wr1 + br1) (hi/lo split)
  gemm_router_p<<<dim3(8, 32), 512, 0, stream>>>(xhi, xlo, wr1hi, wr1lo, br1, hbuf);
  scores_kernel<<<N_TOK/4, 256, 0, stream>>>(hbuf, Wr2, br2, scores, tokmax);
  aux_kernel<<<1, 1024, 0, stream>>>(tokmax, ((float*)d_out) + (size_t)N_TOK*E_DIM);
  // exact top-k via parallel rank + per-expert softmax
  rank_kernel<<<dim3(16, KEXP), 256, 0, stream>>>(scores, topkI, topv, rankof);
  selw_kernel<<<KEXP, 1024, 0, stream>>>(topv, selw);
  rope_kernel<<<CAPN*64/256, 256, 0, stream>>>(cosT, sinT);

  // fused QKV projection: [4096][6144] via 5-slot-ring pipelined GEMM (3.0 exact rounds)
  gemm_p<1><<<dim3(QKV_STRIDE/256, N_TOK/128), 512, 0, stream>>>(xhi, wqkvT, qkvbuf, QKV_STRIDE, E_DIM);

  // pre-gather/rope/transpose K,V into dense swizzled tiles
  prerope_k_kernel<<<KEXP*NH*CAPN*16/256, 256, 0, stream>>>(qkvbuf + E_DIM, topkI, cosT, sinT, Kg);
  prev_kernel<<<KEXP*NH*NTILE, 256, 0, stream>>>(qkvbuf + 2*E_DIM, topkI, Vg);

  // gathered causal attention
  attn_kernel<<<KEXP*NH*NTILE, 256, 0, stream>>>(qkvbuf, Kg, Vg, topkI, selw, cosT, sinT, oexp);

  // scatter-accumulate experts -> token rows
  acc_kernel<<<N_TOK, 256, 0, stream>>>(oexp, rankof, accb);

  // final projection -> d_out (5-slot-ring pipelined, 256 blocks = 1.0 exact round)
  gemm_p<0><<<dim3(E_DIM/256, N_TOK/128), 512, 0, stream>>>(accb, woT, (float*)d_out, E_DIM, E_DIM);
}

// Round 10
// 439.792 us; speedup vs baseline: 1.3729x; 1.0140x over previous
//
#include <hip/hip_runtime.h>
#include <cstdint>
#include <cstddef>

// Problem constants
#define N_TOK 4096
#define E_DIM 2048
#define NH    16
#define DH    128
#define KEXP  4
#define CAPN  1280
#define NTILE 20                 // CAPN/64
#define NQB   10                 // CAPN/128 (attn q-blocks)
#define QKV_STRIDE 6144          // fused QKV output row stride
#define SCALE_QK 0.08838834764831845f
#define LOG2E    1.4426950408889634f
#define NEG_BIG -1e30f

typedef __attribute__((ext_vector_type(4))) float f32x4;
typedef __attribute__((ext_vector_type(8))) short s16x8;

__device__ __forceinline__ float bf2f(unsigned short u){
  union{unsigned int i; float fl;} c; c.i = ((unsigned int)u)<<16; return c.fl;
}
__device__ __forceinline__ unsigned short f2bf(float x){
  union{float fl; unsigned int i;} c; c.fl=x;
  return (unsigned short)((c.i + 0x7FFFu + ((c.i>>16)&1u))>>16);
}
__device__ __forceinline__ f32x4 mfma_bf16(s16x8 a, s16x8 b, f32x4 c){
  asm("v_mfma_f32_16x16x32_bf16 %0, %1, %2, %0" : "+v"(c) : "v"(a), "v"(b));
  return c;
}
// async global->LDS 16B: LDS dest must be lane-linear (base + lane*16)
__device__ __forceinline__ void gl_lds16(const unsigned short* g, unsigned short* l){
  __builtin_amdgcn_global_load_lds(
      (const __attribute__((address_space(1))) unsigned int*)g,
      (__attribute__((address_space(3))) unsigned int*)l, 16, 0, 0);
}

// ---------------- conversions ----------------
__global__ __launch_bounds__(256) void conv_x_kernel(const float* __restrict__ x,
    unsigned short* __restrict__ hi, unsigned short* __restrict__ lo, int n4){
  int idx = blockIdx.x*256 + threadIdx.x;
  if (idx >= n4) return;
  float4 v = ((const float4*)x)[idx];
  float ar[4] = {v.x, v.y, v.z, v.w};
  union{ unsigned short u[4]; uint2 q; } H, L;
  #pragma unroll
  for(int i=0;i<4;i++){
    unsigned short h = f2bf(ar[i]);
    H.u[i] = h;
    L.u[i] = f2bf(ar[i] - bf2f(h));
  }
  ((uint2*)hi)[idx] = H.q;
  ((uint2*)lo)[idx] = L.q;
}

// transpose + f32->bf16 (optionally also lo residual). W[R][C] -> T[C][R]
__global__ __launch_bounds__(256) void tconv_kernel(const float* __restrict__ W,
    unsigned short* __restrict__ Thi, unsigned short* __restrict__ Tlo, int R, int C){
  __shared__ float t[32][33];
  int tx = threadIdx.x, ty = threadIdx.y;   // (32,8)
  int c0 = blockIdx.x*32, r0 = blockIdx.y*32;
  #pragma unroll
  for(int i=0;i<4;i++){
    int r = r0 + ty + i*8;
    t[ty+i*8][tx] = W[(size_t)r*C + c0 + tx];
  }
  __syncthreads();
  #pragma unroll
  for(int i=0;i<4;i++){
    int c = c0 + ty + i*8;
    float v = t[tx][ty+i*8];
    size_t o = (size_t)c*R + r0 + tx;
    unsigned short h = f2bf(v);
    Thi[o] = h;
    if (Tlo) Tlo[o] = f2bf(v - bf2f(h));
  }
}

// fused transpose of 4 ExE weights (Wq,Wk,Wv,Wo) -> contiguous [4][E][E] bf16
__global__ __launch_bounds__(256) void tconv4_kernel(const float* __restrict__ W0,
    const float* __restrict__ W1, const float* __restrict__ W2, const float* __restrict__ W3,
    unsigned short* __restrict__ out){
  __shared__ float t[32][33];
  int z = blockIdx.z;
  const float* W = (z==0)?W0 : (z==1)?W1 : (z==2)?W2 : W3;
  unsigned short* T = out + (size_t)z*E_DIM*E_DIM;
  int tx = threadIdx.x, ty = threadIdx.y;   // (32,8)
  int c0 = blockIdx.x*32, r0 = blockIdx.y*32;
  #pragma unroll
  for(int i=0;i<4;i++){
    int r = r0 + ty + i*8;
    t[ty+i*8][tx] = W[(size_t)r*E_DIM + c0 + tx];
  }
  __syncthreads();
  #pragma unroll
  for(int i=0;i<4;i++){
    int c = c0 + ty + i*8;
    T[(size_t)c*E_DIM + r0 + tx] = f2bf(t[tx][ty+i*8]);
  }
}

// ============ 128x256 BK=32-slab 5-slot-ring pipelined GEMM (T2+T3+T4+T5) ============
template<int OUTBF>
__global__ __launch_bounds__(512, 1) void gemm_p(
    const unsigned short* __restrict__ A, const unsigned short* __restrict__ Bt,
    void* __restrict__ Cp, int N, int Kd){
  __shared__ __align__(16) unsigned short lds[5*12288];   // 120 KB
  const int tid = threadIdx.x;
  const int w = tid>>6, lane = tid&63, g = lane>>4, r16 = lane&15;
  const int wm = w>>2, wn = w&3;                   // 2M x 4N waves
  const int mb = blockIdx.y, nb = blockIdx.x;
  const unsigned short* Ab = A  + (size_t)mb*128*Kd;
  const unsigned short* Bb = Bt + (size_t)nb*256*Kd;
  const int PMAX = Kd >> 5;                        // K/32 phases

  f32x4 acc[4][4];
  #pragma unroll
  for(int i=0;i<4;i++)
    #pragma unroll
    for(int j=0;j<4;j++) acc[i][j] = f32x4{0.f,0.f,0.f,0.f};

  auto stageP = [&](int Pst, int slot){
    unsigned short* base = &lds[slot*12288];
    const int col = Pst*32;
    {
      int row = tid>>2, ch = tid&3;
      int sc = ch ^ ((row>>1)&3);
      gl_lds16(Ab + (size_t)row*Kd + col + sc*8, base + tid*8);
    }
    #pragma unroll
    for(int i=0;i<2;i++){
      int n = i*512 + tid;
      int rw = n>>2, c2 = n&3;
      int s2 = c2 ^ ((rw>>1)&3);
      gl_lds16(Bb + (size_t)rw*Kd + col + s2*8, base + 4096 + n*8);
    }
  };
  const int xoff = (g ^ ((r16>>1)&3)) << 3;

  stageP(0,0); stageP(1,1); stageP(2,2); stageP(3,3);
  asm volatile("s_waitcnt vmcnt(9)" ::: "memory");
  __builtin_amdgcn_s_barrier();

  int sR = 0, sW = 4;
  for(int P=0; P<PMAX; ++P){
    const unsigned short* base = &lds[sR*12288];
    s16x8 af[4], bfv[4];
    #pragma unroll
    for(int mf=0;mf<4;mf++)
      af[mf] = *(const s16x8*)&base[(wm*64 + mf*16 + r16)*32 + xoff];
    #pragma unroll
    for(int nf=0;nf<4;nf++)
      bfv[nf] = *(const s16x8*)&base[4096 + (wn*64 + nf*16 + r16)*32 + xoff];
    if (P+4 < PMAX) stageP(P+4, sW);
    __builtin_amdgcn_s_setprio(1);
    #pragma unroll
    for(int mf=0;mf<4;mf++)
      #pragma unroll
      for(int nf=0;nf<4;nf++)
        acc[mf][nf] = mfma_bf16(af[mf], bfv[nf], acc[mf][nf]);
    __builtin_amdgcn_s_setprio(0);
    if      (P+4 < PMAX) asm volatile("s_waitcnt vmcnt(9)" ::: "memory");
    else if (P+3 < PMAX) asm volatile("s_waitcnt vmcnt(6)" ::: "memory");
    else if (P+2 < PMAX) asm volatile("s_waitcnt vmcnt(3)" ::: "memory");
    else                 asm volatile("s_waitcnt vmcnt(0)" ::: "memory");
    __builtin_amdgcn_s_barrier();
    sR = (sR==4) ? 0 : sR+1;
    sW = (sW==4) ? 0 : sW+1;
  }

  const int rowb = mb*128 + wm*64, colb = nb*256 + wn*64;
  #pragma unroll
  for(int mf=0;mf<4;mf++)
    #pragma unroll
    for(int nf=0;nf<4;nf++)
      #pragma unroll
      for(int r=0;r<4;r++){
        int rr = rowb + mf*16 + 4*g + r;
        int cc = colb + nf*16 + r16;
        size_t o = (size_t)rr*N + cc;
        if (OUTBF) ((unsigned short*)Cp)[o] = f2bf(acc[mf][nf][r]);
        else       ((float*)Cp)[o] = acc[mf][nf][r];
      }
}

// ============ pipelined router GEMM: H = gelu(x@Wr1 + br1), hi/lo split ============
__global__ __launch_bounds__(512, 1) void gemm_router_p(
    const unsigned short* __restrict__ Ahi, const unsigned short* __restrict__ Alo,
    const unsigned short* __restrict__ Bhi, const unsigned short* __restrict__ Blo,
    const float* __restrict__ br1, float* __restrict__ H){
  __shared__ __align__(16) unsigned short lds[2][32768];
  const int tid = threadIdx.x;
  const int w = tid>>6, lane = tid&63, g = lane>>4, r16 = lane&15;
  const int wm = w>>2, wn = w&3;                   // 2M x 4N waves, tile 64x32
  const int mb = blockIdx.y, nb = blockIdx.x;
  const unsigned short* AbH = Ahi + (size_t)mb*128*E_DIM;
  const unsigned short* AbL = Alo + (size_t)mb*128*E_DIM;
  const unsigned short* BbH = Bhi + (size_t)nb*128*E_DIM;
  const unsigned short* BbL = Blo + (size_t)nb*128*E_DIM;
  const int NT = E_DIM >> 6;   // 32

  f32x4 acc[4][2];
  #pragma unroll
  for(int i=0;i<4;i++){ acc[i][0]=f32x4{0.f,0.f,0.f,0.f}; acc[i][1]=f32x4{0.f,0.f,0.f,0.f}; }

  auto stage = [&](int buf, int ks, int t){   // 4 slabs x (128x32), 1 load/thread each
    int row = tid>>2, ch = tid&3;
    int sc = ch ^ ((row>>1)&3);
    size_t go = (size_t)row*E_DIM + t*64 + ks*32 + sc*8;
    unsigned short* base = &lds[buf][ks*16384];
    gl_lds16(AbH + go, base +         tid*8);
    gl_lds16(AbL + go, base +  4096 + tid*8);
    gl_lds16(BbH + go, base +  8192 + tid*8);
    gl_lds16(BbL + go, base + 12288 + tid*8);
  };
  const int xoff = (g ^ ((r16>>1)&3)) << 3;

  stage(0,0,0); stage(0,1,0); stage(1,0,1);
  asm volatile("s_waitcnt vmcnt(8)" ::: "memory");
  __builtin_amdgcn_s_barrier();

  int cur = 0;
  for(int t=0; t<NT; ++t){
    const int nxt = cur^1;
    #pragma unroll
    for(int ph=0; ph<2; ph++){
      const unsigned short* base = &lds[cur][ph*16384];
      s16x8 ah[4], al[4], bh[2], bl[2];
      #pragma unroll
      for(int mf=0;mf<4;mf++){
        int ro = (wm*64 + mf*16 + r16)*32 + xoff;
        ah[mf] = *(const s16x8*)&base[ro];
        al[mf] = *(const s16x8*)&base[4096 + ro];
      }
      #pragma unroll
      for(int nf=0;nf<2;nf++){
        int ro = (wn*32 + nf*16 + r16)*32 + xoff;
        bh[nf] = *(const s16x8*)&base[8192 + ro];
        bl[nf] = *(const s16x8*)&base[12288 + ro];
      }
      if (ph==0){
        if (t+1 < NT){ stage(nxt,1,t+1); asm volatile("s_waitcnt vmcnt(8)" ::: "memory"); }
        else         {                   asm volatile("s_waitcnt vmcnt(0)" ::: "memory"); }
      } else {
        if (t+2 < NT){ stage(cur,0,t+2); asm volatile("s_waitcnt vmcnt(8)" ::: "memory"); }
        else if (t+1 < NT){              asm volatile("s_waitcnt vmcnt(4)" ::: "memory"); }
        else              {              asm volatile("s_waitcnt vmcnt(0)" ::: "memory"); }
      }
      __builtin_amdgcn_s_barrier();
      __builtin_amdgcn_s_setprio(1);
      #pragma unroll
      for(int mf=0;mf<4;mf++)
        #pragma unroll
        for(int nf=0;nf<2;nf++){
          acc[mf][nf] = mfma_bf16(ah[mf], bh[nf], acc[mf][nf]);
          acc[mf][nf] = mfma_bf16(ah[mf], bl[nf], acc[mf][nf]);
          acc[mf][nf] = mfma_bf16(al[mf], bh[nf], acc[mf][nf]);
        }
      __builtin_amdgcn_s_setprio(0);
      __builtin_amdgcn_s_barrier();
    }
    cur ^= 1;
  }

  const int rowb = mb*128 + wm*64, colb = nb*128 + wn*32;
  #pragma unroll
  for(int mf=0;mf<4;mf++)
    #pragma unroll
    for(int nf=0;nf<2;nf++)
      #pragma unroll
      for(int r=0;r<4;r++){
        int rr = rowb + mf*16 + 4*g + r;
        int cc = colb + nf*16 + r16;
        float v = acc[mf][nf][r] + br1[cc];
        H[(size_t)rr*1024 + cc] = 0.5f*v*(1.0f + erff(v*0.70710678118654752f));
      }
}

// ---------------- router scores ----------------
__global__ __launch_bounds__(256) void scores_kernel(const float* __restrict__ h,
    const float* __restrict__ Wr2, const float* __restrict__ br2,
    float* __restrict__ scores, float* __restrict__ tokmax){
  int tid = threadIdx.x;
  int n = blockIdx.x*4 + (tid>>6);
  int lane = tid & 63;
  const float* hr = h + (size_t)n*1024;
  float s0=0,s1=0,s2=0,s3=0;
  #pragma unroll
  for(int i=0;i<16;i++){
    int j = lane + i*64;
    float hv = hr[j];
    float4 wv = *(const float4*)(Wr2 + (size_t)j*4);
    s0 += hv*wv.x; s1 += hv*wv.y; s2 += hv*wv.z; s3 += hv*wv.w;
  }
  #pragma unroll
  for(int m=32;m>=1;m>>=1){
    s0 += __shfl_xor(s0,m); s1 += __shfl_xor(s1,m);
    s2 += __shfl_xor(s2,m); s3 += __shfl_xor(s3,m);
  }
  if (lane==0){
    s0+=br2[0]; s1+=br2[1]; s2+=br2[2]; s3+=br2[3];
    scores[n*4+0]=s0; scores[n*4+1]=s1; scores[n*4+2]=s2; scores[n*4+3]=s3;
    tokmax[n]=fmaxf(fmaxf(s0,s1),fmaxf(s2,s3));
  }
}

__global__ __launch_bounds__(1024) void aux_kernel(const float* __restrict__ tokmax, float* __restrict__ out_aux){
  __shared__ float red[1024];
  int t = threadIdx.x;
  red[t] = tokmax[t] + tokmax[t+1024] + tokmax[t+2048] + tokmax[t+3072];
  __syncthreads();
  for(int k=512;k>=1;k>>=1){ if(t<k) red[t]+=red[t+k]; __syncthreads(); }
  if (t==0) out_aux[0] = -red[0]/4096.0f;
}

// ---------------- exact top-k via parallel rank ----------------
__global__ __launch_bounds__(256) void rank_kernel(const float* __restrict__ scores,
    int* __restrict__ topk_idx, float* __restrict__ topv, int* __restrict__ rank_of){
  __shared__ unsigned long long keys[4096];   // 32KB
  const int e = blockIdx.y, blk = blockIdx.x, tid = threadIdx.x;
  for(int i=tid;i<4096;i+=256){
    unsigned u = __float_as_uint(scores[i*4+e]);
    unsigned m = (u & 0x80000000u) ? ~u : (u | 0x80000000u);
    keys[i] = (((unsigned long long)m)<<32) | (unsigned)(4095-i);
  }
  __syncthreads();
  const int i = blk*256 + tid;
  const unsigned long long mykey = keys[i];
  int cnt = 0;
  #pragma unroll 8
  for(int j=0;j<4096;j++) cnt += (keys[j] > mykey) ? 1 : 0;
  if (cnt < CAPN){
    topk_idx[e*CAPN + cnt] = i;
    topv[e*CAPN + cnt]     = scores[i*4+e];
    rank_of[e*4096 + i]    = cnt;
  } else {
    rank_of[e*4096 + i]    = -1;
  }
}

// per-expert softmax over the CAPN sorted top values -> sel_w
__global__ __launch_bounds__(1024) void selw_kernel(const float* __restrict__ topv,
    float* __restrict__ sel_w){
  __shared__ float red[1024];
  const int e = blockIdx.x, t = threadIdx.x;
  const float mx = topv[e*CAPN];        // rank 0 == max
  float p0 = expf(topv[e*CAPN + t] - mx);
  float p1 = (t + 1024 < CAPN) ? expf(topv[e*CAPN + t + 1024] - mx) : 0.f;
  red[t] = p0 + p1;
  __syncthreads();
  for(int k=512;k>=1;k>>=1){ if(t<k) red[t]+=red[t+k]; __syncthreads(); }
  const float denom = red[0];
  sel_w[e*CAPN + t] = p0/denom;
  if (t + 1024 < CAPN) sel_w[e*CAPN + t + 1024] = p1/denom;
}

// ---------------- RoPE tables [CAPN][64] ----------------
__global__ __launch_bounds__(256) void rope_kernel(float* __restrict__ cosT, float* __restrict__ sinT){
  int idx = blockIdx.x*256 + threadIdx.x;
  int p = idx>>6, dm = idx&63;
  float inv = powf(10000.0f, -(float)dm/64.0f);
  float ang = (float)p*inv;
  cosT[idx]=cosf(ang);
  sinT[idx]=sinf(ang);
}

// ---------------- pre-gather + pre-rope K into swizzled tiles ----------------
__global__ __launch_bounds__(256) void prerope_k_kernel(const unsigned short* __restrict__ kb,
    const int* __restrict__ topk_idx, const float* __restrict__ cosT, const float* __restrict__ sinT,
    unsigned short* __restrict__ Kg){
  int idx = blockIdx.x*256 + threadIdx.x;   // exact 4*16*1280*16
  int ch = idx & 15;
  int rest = idx >> 4;
  int rank = rest % CAPN;
  int he = rest / CAPN;           // e*16+h
  int e = he >> 4, h = he & 15;
  int tok = topk_idx[e*CAPN + rank];
  int d0 = ch*8;
  const unsigned short* krow = kb + (size_t)tok*QKV_STRIDE + h*DH;
  unsigned short held[8], part[8];
  *(uint4*)held = *(const uint4*)(krow + d0);
  *(uint4*)part = *(const uint4*)(krow + (d0^64));
  const float* cr = cosT + rank*64;
  const float* sr = sinT + rank*64;
  float sgn = (d0<64) ? -1.f : 1.f;
  unsigned short outv[8];
  #pragma unroll
  for(int jj=0;jj<8;jj++){
    int dm = (d0+jj)&63;
    outv[jj] = f2bf(bf2f(held[jj])*cr[dm] + sgn*bf2f(part[jj])*sr[dm]);
  }
  int t = rank >> 6, row = rank & 63;
  size_t tbase = ((size_t)(he)*NTILE + t) * 8192;
  *(uint4*)(Kg + tbase + row*128 + ((ch ^ (row&7))<<3)) = *(uint4*)outv;
}

// ---------------- pre-gather + transpose V into swizzled tiles ----------------
__global__ __launch_bounds__(256) void prev_kernel(const unsigned short* __restrict__ vb,
    const int* __restrict__ topk_idx, unsigned short* __restrict__ Vg){
  __shared__ __align__(16) unsigned short T2[128][72];
  int bid = blockIdx.x;           // e*320 + h*20 + t
  int t = bid % NTILE, h = (bid/NTILE) & 15, e = bid/(NTILE*NH);
  int tid = threadIdx.x, lane = tid & 63, dchb = tid >> 6;
  int tok = topk_idx[e*CAPN + t*64 + lane];
  const unsigned short* vrow = vb + (size_t)tok*QKV_STRIDE + h*DH;
  #pragma unroll
  for(int i=0;i<4;i++){
    int d0 = (dchb + i*4)*8;
    unsigned short vv[8];
    *(uint4*)vv = *(const uint4*)(vrow + d0);
    #pragma unroll
    for(int j=0;j<8;j++) T2[d0+j][lane] = vv[j];   // lane-consecutive: conflict-free
  }
  __syncthreads();
  unsigned short* out = Vg + ((size_t)(e*NH+h)*NTILE + t)*8192;
  #pragma unroll
  for(int i=0;i<4;i++){
    int c = i*256 + tid;
    int d = c>>3, ch = c&7;
    *(uint4*)(out + d*64 + ((ch ^ (d&7))<<3)) = *(const uint4*)&T2[d][ch*8];
  }
}

// ---------------- gathered causal flash attention (128 Q rows / block, 8 waves) ----------------
// counted-vmcnt pipeline identical to r9 but 2-load stage units: K(t+1) staged at iter
// top, V(t+1) at iter end; every rendezvous = (per-wave vmcnt(2); s_barrier).
__global__ __launch_bounds__(512) void attn_kernel(
    const unsigned short* __restrict__ qb,
    const unsigned short* __restrict__ Kg, const unsigned short* __restrict__ Vg,
    const int* __restrict__ topk_idx, const float* __restrict__ sel_w,
    const float* __restrict__ cosT, const float* __restrict__ sinT,
    unsigned short* __restrict__ oexp){
  __shared__ __align__(16) unsigned short KsA[2][8192];
  __shared__ __align__(16) unsigned short Vs[8192];
  __shared__ __align__(16) unsigned short Ps[8][16][72];
  const int id = blockIdx.x;
  const int xcd = id & 7, s_ = id >> 3;             // 80 per xcd
  const int qb2 = NQB - 1 - (s_ % NQB);             // longest first
  const int grp = (s_ / NQB)*8 + xcd;               // 0..63
  const int e = grp >> 4, hh = grp & 15;
  const int tid = threadIdx.x, w = tid>>6, lane = tid&63, g = lane>>4, r16 = lane&15;
  const int* idxE = topk_idx + e*CAPN;
  const unsigned short* Kgb = Kg + (size_t)(e*NH+hh)*CAPN*DH;
  const unsigned short* Vgb = Vg + (size_t)(e*NH+hh)*CAPN*DH;
  const int ktmax = 2*qb2 + 1;

  s16x8 aq[4];
  {
    int qr = qb2*128 + w*16 + r16;
    int tok = idxE[qr];
    const unsigned short* qrow = qb + (size_t)tok*QKV_STRIDE + hh*DH;
    const float* cr = cosT + qr*64;
    const float* sr = sinT + qr*64;
    #pragma unroll
    for(int s=0;s<4;s++){
      int d0 = s*32 + 8*g;
      unsigned short held[8], part[8];
      *(uint4*)held = *(const uint4*)(qrow + d0);
      *(uint4*)part = *(const uint4*)(qrow + (d0^64));
      float sgn = (d0<64) ? -1.f : 1.f;
      union{ s16x8 v; unsigned short u[8]; } fr;
      #pragma unroll
      for(int jj=0;jj<8;jj++){
        int dm = (d0+jj)&63;
        float val = bf2f(held[jj])*cr[dm] + sgn*bf2f(part[jj])*sr[dm];
        fr.u[jj] = f2bf(val * (SCALE_QK*LOG2E));
      }
      aq[s] = fr.v;
    }
  }
  float m_r[4], l_r[4];
  f32x4 o[8];
  #pragma unroll
  for(int r=0;r<4;r++){ m_r[r]=-INFINITY; l_r[r]=0.f; }
  #pragma unroll
  for(int f2=0;f2<8;f2++) o[f2]=f32x4{0.f,0.f,0.f,0.f};

  // prologue: K(0), V(0) — 2 loads each (1024 chunks / 512 thr); wait K(0) only
  #pragma unroll
  for(int i=0;i<2;i++){ int c=i*512+tid; gl_lds16(Kgb + c*8, &KsA[0][c*8]); }
  #pragma unroll
  for(int i=0;i<2;i++){ int c=i*512+tid; gl_lds16(Vgb + c*8, &Vs[c*8]); }
  asm volatile("s_waitcnt vmcnt(2)" ::: "memory");
  __builtin_amdgcn_s_barrier();

  for(int kt=0; kt<=ktmax; kt++){
    const int cur = kt & 1;
    if (kt < ktmax){
      const unsigned short* Ksrc = Kgb + (size_t)(kt+1)*8192;
      #pragma unroll
      for(int i=0;i<2;i++){ int c=i*512+tid; gl_lds16(Ksrc + c*8, &KsA[cur^1][c*8]); }
    }
    f32x4 sfr[4];
    #pragma unroll
    for(int fc=0;fc<4;fc++){
      f32x4 a4 = f32x4{0.f,0.f,0.f,0.f};
      const int row = fc*16 + r16;
      #pragma unroll
      for(int s=0;s<4;s++){
        s16x8 bk = *(const s16x8*)&KsA[cur][row*128 + (((s*4+g) ^ (r16&7))<<3)];
        a4 = mfma_bf16(aq[s], bk, a4);
      }
      sfr[fc] = a4;
    }
    if (kt >= 2*qb2){   // diagonal tiles only
      #pragma unroll
      for(int fc=0;fc<4;fc++)
        #pragma unroll
        for(int r=0;r<4;r++){
          int qrank  = qb2*128 + w*16 + 4*g + r;
          int kvrank = kt*64 + fc*16 + r16;
          if (kvrank > qrank) sfr[fc][r] = NEG_BIG;
        }
    }
    float corr[4];
    bool need = false;
    #pragma unroll
    for(int r=0;r<4;r++){
      float mx = fmaxf(fmaxf(sfr[0][r],sfr[1][r]), fmaxf(sfr[2][r],sfr[3][r]));
      #pragma unroll
      for(int mk=1;mk<16;mk<<=1) mx = fmaxf(mx, __shfl_xor(mx,mk));
      float nm = fmaxf(m_r[r], mx);
      need = need || (nm > m_r[r]);
      corr[r] = exp2f(m_r[r]-nm);
      m_r[r] = nm;
    }
    if (__any(need)){
      #pragma unroll
      for(int f2=0;f2<8;f2++)
        #pragma unroll
        for(int r=0;r<4;r++) o[f2][r] *= corr[r];
      #pragma unroll
      for(int r=0;r<4;r++) l_r[r] *= corr[r];
    }
    float rs[4] = {0.f,0.f,0.f,0.f};
    #pragma unroll
    for(int fc=0;fc<4;fc++)
      #pragma unroll
      for(int r=0;r<4;r++){
        float p = exp2f(sfr[fc][r] - m_r[r]);
        rs[r] += p;
        Ps[w][4*g+r][fc*16+r16] = f2bf(p);
      }
    #pragma unroll
    for(int r=0;r<4;r++){
      float ts = rs[r];
      #pragma unroll
      for(int mk=1;mk<16;mk<<=1) ts += __shfl_xor(ts,mk);
      l_r[r] += ts;
    }
    // mid rendezvous: V(kt) landed (K(kt+1) may stay in flight)
    if (kt < ktmax) asm volatile("s_waitcnt vmcnt(2)" ::: "memory");
    else            asm volatile("s_waitcnt vmcnt(0)" ::: "memory");
    __builtin_amdgcn_s_barrier();
    #pragma unroll
    for(int ks=0;ks<2;ks++){
      s16x8 pa = *(const s16x8*)&Ps[w][r16][ks*32 + 8*g];
      #pragma unroll
      for(int fd=0;fd<8;fd++){
        const int row = fd*16 + r16;
        s16x8 vf = *(const s16x8*)&Vs[row*64 + (((ks*4+g) ^ (r16&7))<<3)];
        o[fd] = mfma_bf16(pa, vf, o[fd]);
      }
    }
    __builtin_amdgcn_s_barrier();   // PV reads done; Vs safe to overwrite
    if (kt < ktmax){
      const unsigned short* Vsrc = Vgb + (size_t)(kt+1)*8192;
      #pragma unroll
      for(int i=0;i<2;i++){ int c=i*512+tid; gl_lds16(Vsrc + c*8, &Vs[c*8]); }
      asm volatile("s_waitcnt vmcnt(2)" ::: "memory");   // K(kt+1) landed
      __builtin_amdgcn_s_barrier();
    }
  }
  #pragma unroll
  for(int r=0;r<4;r++){
    int qrank = qb2*128 + w*16 + 4*g + r;
    float fac = sel_w[e*CAPN + qrank] / l_r[r];
    #pragma unroll
    for(int fd=0;fd<8;fd++){
      oexp[((size_t)(e*CAPN + qrank))*E_DIM + hh*DH + fd*16 + r16] = f2bf(o[fd][r]*fac);
    }
  }
}

// ---------------- scatter-accumulate over experts ----------------
__global__ __launch_bounds__(256) void acc_kernel(const unsigned short* __restrict__ oexp,
    const int* __restrict__ rank_of, unsigned short* __restrict__ accb){
  int n = blockIdx.x, t = threadIdx.x;
  int base = t*8;
  float s[8] = {0,0,0,0,0,0,0,0};
  #pragma unroll
  for(int e=0;e<4;e++){
    int r = rank_of[e*4096+n];
    if (r>=0){
      union{uint4 q; unsigned short u[8];} ld;
      ld.q = *(const uint4*)(oexp + ((size_t)(e*CAPN+r))*E_DIM + base);
      #pragma unroll
      for(int j2=0;j2<8;j2++) s[j2] += bf2f(ld.u[j2]);
    }
  }
  union{uint4 q; unsigned short u[8];} st;
  #pragma unroll
  for(int j2=0;j2<8;j2++) st.u[j2] = f2bf(s[j2]);
  *(uint4*)(accb + (size_t)n*E_DIM + base) = st.q;
}

// ---------------- launch ----------------
extern "C" void kernel_launch(void* const* d_in, const int* in_sizes, int n_in,
                              void* d_out, int out_size, void* d_ws, size_t ws_size,
                              hipStream_t stream) {
  const float* x   = (const float*)d_in[0];
  const float* Wq  = (const float*)d_in[1];
  const float* Wk  = (const float*)d_in[2];
  const float* Wv  = (const float*)d_in[3];
  const float* Wo  = (const float*)d_in[4];
  const float* Wr1 = (const float*)d_in[5];
  const float* br1 = (const float*)d_in[6];
  const float* Wr2 = (const float*)d_in[7];
  const float* br2 = (const float*)d_in[8];

  char* ws = (char*)d_ws;
  size_t off = 0;
  auto alloc = [&](size_t bytes)->void*{
    void* p = ws + off;
    off += (bytes + 255) & ~(size_t)255;
    return p;
  };
  unsigned short* xhi   = (unsigned short*)alloc((size_t)N_TOK*E_DIM*2);
  unsigned short* xlo   = (unsigned short*)alloc((size_t)N_TOK*E_DIM*2);
  unsigned short* wr1hi = (unsigned short*)alloc((size_t)E_DIM*1024*2);   // transposed [1024][2048]
  unsigned short* wr1lo = (unsigned short*)alloc((size_t)E_DIM*1024*2);
  unsigned short* wqkvT = (unsigned short*)alloc((size_t)3*E_DIM*E_DIM*2); // [6144][2048]
  unsigned short* woT   = (unsigned short*)alloc((size_t)E_DIM*E_DIM*2);   // contiguous after wqkvT
  void* hv = alloc((size_t)KEXP*NH*CAPN*DH*2);   // max(hbuf 16.8MB, Vg 21MB)
  float* hbuf = (float*)hv;                      // dead after scores_kernel
  unsigned short* Vg = (unsigned short*)hv;      // written by prev_kernel later
  float* scores = (float*)alloc((size_t)N_TOK*4*4);
  float* tokmax = (float*)alloc((size_t)N_TOK*4);
  int*   topkI  = (int*)alloc((size_t)KEXP*CAPN*4);
  float* topv   = (float*)alloc((size_t)KEXP*CAPN*4);
  float* selw   = (float*)alloc((size_t)KEXP*CAPN*4);
  int*   rankof = (int*)alloc((size_t)KEXP*N_TOK*4);
  float* cosT   = (float*)alloc((size_t)CAPN*64*4);
  float* sinT   = (float*)alloc((size_t)CAPN*64*4);
  unsigned short* qkvbuf = (unsigned short*)alloc((size_t)N_TOK*QKV_STRIDE*2);
  unsigned short* oexp = (unsigned short*)alloc((size_t)KEXP*CAPN*E_DIM*2);
  unsigned short* accb = (unsigned short*)alloc((size_t)N_TOK*E_DIM*2);
  if (off > ws_size) return;   // fail loudly (output stays poisoned)

  // Kg (21MB, swizzled) aliases xlo+wr1hi+wr1lo (25.2MB), dead after router GEMM
  unsigned short* Kg = xlo;

  // conversions
  conv_x_kernel<<<(N_TOK*E_DIM/4+255)/256, 256, 0, stream>>>(x, xhi, xlo, N_TOK*E_DIM/4);
  tconv_kernel<<<dim3(1024/32, E_DIM/32), dim3(32,8), 0, stream>>>(Wr1, wr1hi, wr1lo, E_DIM, 1024);
  // fused transpose Wq,Wk,Wv,Wo -> wqkvT(+woT, contiguous)
  tconv4_kernel<<<dim3(E_DIM/32, E_DIM/32, 4), dim3(32,8), 0, stream>>>(Wq, Wk, Wv, Wo, wqkvT);

  // pipelined fused router: H = gelu(x@Wr1 + br1) (hi/lo split)
  gemm_router_p<<<dim3(8, 32), 512, 0, stream>>>(xhi, xlo, wr1hi, wr1lo, br1, hbuf);
  scores_kernel<<<N_TOK/4, 256, 0, stream>>>(hbuf, Wr2, br2, scores, tokmax);
  aux_kernel<<<1, 1024, 0, stream>>>(tokmax, ((float*)d_out) + (size_t)N_TOK*E_DIM);
  // exact top-k via parallel rank + per-expert softmax
  rank_kernel<<<dim3(16, KEXP), 256, 0, stream>>>(scores, topkI, topv, rankof);
  selw_kernel<<<KEXP, 1024, 0, stream>>>(topv, selw);
  rope_kernel<<<CAPN*64/256, 256, 0, stream>>>(cosT, sinT);

  // fused QKV projection: [4096][6144] via 5-slot-ring pipelined GEMM (3.0 exact rounds)
  gemm_p<1><<<dim3(QKV_STRIDE/256, N_TOK/128), 512, 0, stream>>>(xhi, wqkvT, qkvbuf, QKV_STRIDE, E_DIM);

  // pre-gather/rope/transpose K,V into dense swizzled tiles
  prerope_k_kernel<<<KEXP*NH*CAPN*16/256, 256, 0, stream>>>(qkvbuf + E_DIM, topkI, cosT, sinT, Kg);
  prev_kernel<<<KEXP*NH*NTILE, 256, 0, stream>>>(qkvbuf + 2*E_DIM, topkI, Vg);

  // gathered causal attention: 128 Q rows / block, 8 waves, 640 blocks
  attn_kernel<<<KEXP*NH*NQB, 512, 0, stream>>>(qkvbuf, Kg, Vg, topkI, selw, cosT, sinT, oexp);

  // scatter-accumulate experts -> token rows
  acc_kernel<<<N_TOK, 256, 0, stream>>>(oexp, rankof, accb);

  // final projection -> d_out (5-slot-ring pipelined, 256 blocks = 1.0 exact round)
  gemm_p<0><<<dim3(E_DIM/256, N_TOK/128), 512, 0, stream>>>(accb, woT, (float*)d_out, E_DIM, E_DIM);
}

// Round 11
// 430.045 us; speedup vs baseline: 1.4040x; 1.0227x over previous
//
#include <hip/hip_runtime.h>
#include <cstdint>
#include <cstddef>

// Problem constants
#define N_TOK 4096
#define E_DIM 2048
#define NH    16
#define DH    128
#define KEXP  4
#define CAPN  1280
#define NTILE 20                 // CAPN/64
#define NQB   10                 // CAPN/128 (attn q-blocks)
#define QKV_STRIDE 6144          // fused QKV output row stride
#define SCALE_QK 0.08838834764831845f
#define LOG2E    1.4426950408889634f
#define NEG_BIG -1e30f

typedef __attribute__((ext_vector_type(4))) float f32x4;
typedef __attribute__((ext_vector_type(8))) short s16x8;

__device__ __forceinline__ float bf2f(unsigned short u){
  union{unsigned int i; float fl;} c; c.i = ((unsigned int)u)<<16; return c.fl;
}
__device__ __forceinline__ unsigned short f2bf(float x){
  union{float fl; unsigned int i;} c; c.fl=x;
  return (unsigned short)((c.i + 0x7FFFu + ((c.i>>16)&1u))>>16);
}
__device__ __forceinline__ f32x4 mfma_bf16(s16x8 a, s16x8 b, f32x4 c){
  asm("v_mfma_f32_16x16x32_bf16 %0, %1, %2, %0" : "+v"(c) : "v"(a), "v"(b));
  return c;
}
// async global->LDS 16B: LDS dest must be lane-linear (base + lane*16)
__device__ __forceinline__ void gl_lds16(const unsigned short* g, unsigned short* l){
  __builtin_amdgcn_global_load_lds(
      (const __attribute__((address_space(1))) unsigned int*)g,
      (__attribute__((address_space(3))) unsigned int*)l, 16, 0, 0);
}

// ---------------- conversions ----------------
__global__ __launch_bounds__(256) void conv_x_kernel(const float* __restrict__ x,
    unsigned short* __restrict__ hi, unsigned short* __restrict__ lo, int n4){
  int idx = blockIdx.x*256 + threadIdx.x;
  if (idx >= n4) return;
  float4 v = ((const float4*)x)[idx];
  float ar[4] = {v.x, v.y, v.z, v.w};
  union{ unsigned short u[4]; uint2 q; } H, L;
  #pragma unroll
  for(int i=0;i<4;i++){
    unsigned short h = f2bf(ar[i]);
    H.u[i] = h;
    L.u[i] = f2bf(ar[i] - bf2f(h));
  }
  ((uint2*)hi)[idx] = H.q;
  ((uint2*)lo)[idx] = L.q;
}

// transpose + f32->bf16 (optionally also lo residual). W[R][C] -> T[C][R]
__global__ __launch_bounds__(256) void tconv_kernel(const float* __restrict__ W,
    unsigned short* __restrict__ Thi, unsigned short* __restrict__ Tlo, int R, int C){
  __shared__ float t[32][33];
  int tx = threadIdx.x, ty = threadIdx.y;   // (32,8)
  int c0 = blockIdx.x*32, r0 = blockIdx.y*32;
  #pragma unroll
  for(int i=0;i<4;i++){
    int r = r0 + ty + i*8;
    t[ty+i*8][tx] = W[(size_t)r*C + c0 + tx];
  }
  __syncthreads();
  #pragma unroll
  for(int i=0;i<4;i++){
    int c = c0 + ty + i*8;
    float v = t[tx][ty+i*8];
    size_t o = (size_t)c*R + r0 + tx;
    unsigned short h = f2bf(v);
    Thi[o] = h;
    if (Tlo) Tlo[o] = f2bf(v - bf2f(h));
  }
}

// fused transpose of 4 ExE weights (Wq,Wk,Wv,Wo) -> contiguous [4][E][E] bf16
__global__ __launch_bounds__(256) void tconv4_kernel(const float* __restrict__ W0,
    const float* __restrict__ W1, const float* __restrict__ W2, const float* __restrict__ W3,
    unsigned short* __restrict__ out){
  __shared__ float t[32][33];
  int z = blockIdx.z;
  const float* W = (z==0)?W0 : (z==1)?W1 : (z==2)?W2 : W3;
  unsigned short* T = out + (size_t)z*E_DIM*E_DIM;
  int tx = threadIdx.x, ty = threadIdx.y;   // (32,8)
  int c0 = blockIdx.x*32, r0 = blockIdx.y*32;
  #pragma unroll
  for(int i=0;i<4;i++){
    int r = r0 + ty + i*8;
    t[ty+i*8][tx] = W[(size_t)r*E_DIM + c0 + tx];
  }
  __syncthreads();
  #pragma unroll
  for(int i=0;i<4;i++){
    int c = c0 + ty + i*8;
    T[(size_t)c*E_DIM + r0 + tx] = f2bf(t[tx][ty+i*8]);
  }
}

// ============ 128x256 BK=32-slab 3-slot-ring pipelined GEMM (T2+T3+T4+T5) ============
// C[M][N] = A[M][K] * Bt[N][K]^T. 512 thr = 8 waves 2Mx4N, wave tile 64x64.
// Phase P = K-column-slab 32*P. LDS ring of 3 slots (A 4096 + B 8192 shorts each,
// 72KB -> 2 blocks/CU: the co-resident block hides barrier/lgkmcnt stalls).
// Read slot P%3; stage phase P+2 into slot (P+2)%3 (= (P-1)%3, readers done before
// barrier(P-1)). One barrier/phase. Steady vmcnt(3): stage(P+1) (issued P-1) complete,
// stage(P+2)'s 3 loads ride. Epilogue 3->0. Queue never drains mid-loop.
// Swizzle (verified r7): LDS(row,ch)=G(row, ch^((row>>1)&3)); read chunk g^((r16>>1)&3).
template<int OUTBF>
__global__ __launch_bounds__(512, 2) void gemm_p(
    const unsigned short* __restrict__ A, const unsigned short* __restrict__ Bt,
    void* __restrict__ Cp, int N, int Kd){
  __shared__ __align__(16) unsigned short lds[3*12288];   // 72 KB
  const int tid = threadIdx.x;
  const int w = tid>>6, lane = tid&63, g = lane>>4, r16 = lane&15;
  const int wm = w>>2, wn = w&3;                   // 2M x 4N waves
  const int mb = blockIdx.y, nb = blockIdx.x;
  const unsigned short* Ab = A  + (size_t)mb*128*Kd;
  const unsigned short* Bb = Bt + (size_t)nb*256*Kd;
  const int PMAX = Kd >> 5;                        // K/32 phases

  f32x4 acc[4][4];
  #pragma unroll
  for(int i=0;i<4;i++)
    #pragma unroll
    for(int j=0;j<4;j++) acc[i][j] = f32x4{0.f,0.f,0.f,0.f};

  auto stageP = [&](int Pst, int slot){
    unsigned short* base = &lds[slot*12288];
    const int col = Pst*32;
    {
      int row = tid>>2, ch = tid&3;
      int sc = ch ^ ((row>>1)&3);
      gl_lds16(Ab + (size_t)row*Kd + col + sc*8, base + tid*8);
    }
    #pragma unroll
    for(int i=0;i<2;i++){
      int n = i*512 + tid;
      int rw = n>>2, c2 = n&3;
      int s2 = c2 ^ ((rw>>1)&3);
      gl_lds16(Bb + (size_t)rw*Kd + col + s2*8, base + 4096 + n*8);
    }
  };
  const int xoff = (g ^ ((r16>>1)&3)) << 3;

  // prologue: phases 0,1 into slots 0,1; wait phase-0's unit (leave stage(1) in flight)
  stageP(0,0); stageP(1,1);
  asm volatile("s_waitcnt vmcnt(3)" ::: "memory");
  __builtin_amdgcn_s_barrier();

  int sR = 0, sW = 2;
  for(int P=0; P<PMAX; ++P){
    const unsigned short* base = &lds[sR*12288];
    s16x8 af[4], bfv[4];
    #pragma unroll
    for(int mf=0;mf<4;mf++)
      af[mf] = *(const s16x8*)&base[(wm*64 + mf*16 + r16)*32 + xoff];
    #pragma unroll
    for(int nf=0;nf<4;nf++)
      bfv[nf] = *(const s16x8*)&base[4096 + (wn*64 + nf*16 + r16)*32 + xoff];
    if (P+2 < PMAX) stageP(P+2, sW);
    __builtin_amdgcn_s_setprio(1);
    #pragma unroll
    for(int mf=0;mf<4;mf++)
      #pragma unroll
      for(int nf=0;nf<4;nf++)
        acc[mf][nf] = mfma_bf16(af[mf], bfv[nf], acc[mf][nf]);
    __builtin_amdgcn_s_setprio(0);
    // guard next phase's slot: stage(P+1) must land; stage(P+2)'s 3 loads may ride
    if      (P+2 < PMAX) asm volatile("s_waitcnt vmcnt(3)" ::: "memory");
    else                 asm volatile("s_waitcnt vmcnt(0)" ::: "memory");
    __builtin_amdgcn_s_barrier();
    sR = (sR==2) ? 0 : sR+1;
    sW = (sW==2) ? 0 : sW+1;
  }

  const int rowb = mb*128 + wm*64, colb = nb*256 + wn*64;
  #pragma unroll
  for(int mf=0;mf<4;mf++)
    #pragma unroll
    for(int nf=0;nf<4;nf++)
      #pragma unroll
      for(int r=0;r<4;r++){
        int rr = rowb + mf*16 + 4*g + r;
        int cc = colb + nf*16 + r16;
        size_t o = (size_t)rr*N + cc;
        if (OUTBF) ((unsigned short*)Cp)[o] = f2bf(acc[mf][nf][r]);
        else       ((float*)Cp)[o] = acc[mf][nf][r];
      }
}

// ============ pipelined router GEMM: H = gelu(x@Wr1 + br1), hi/lo split ============
__global__ __launch_bounds__(512, 1) void gemm_router_p(
    const unsigned short* __restrict__ Ahi, const unsigned short* __restrict__ Alo,
    const unsigned short* __restrict__ Bhi, const unsigned short* __restrict__ Blo,
    const float* __restrict__ br1, float* __restrict__ H){
  __shared__ __align__(16) unsigned short lds[2][32768];
  const int tid = threadIdx.x;
  const int w = tid>>6, lane = tid&63, g = lane>>4, r16 = lane&15;
  const int wm = w>>2, wn = w&3;                   // 2M x 4N waves, tile 64x32
  const int mb = blockIdx.y, nb = blockIdx.x;
  const unsigned short* AbH = Ahi + (size_t)mb*128*E_DIM;
  const unsigned short* AbL = Alo + (size_t)mb*128*E_DIM;
  const unsigned short* BbH = Bhi + (size_t)nb*128*E_DIM;
  const unsigned short* BbL = Blo + (size_t)nb*128*E_DIM;
  const int NT = E_DIM >> 6;   // 32

  f32x4 acc[4][2];
  #pragma unroll
  for(int i=0;i<4;i++){ acc[i][0]=f32x4{0.f,0.f,0.f,0.f}; acc[i][1]=f32x4{0.f,0.f,0.f,0.f}; }

  auto stage = [&](int buf, int ks, int t){   // 4 slabs x (128x32), 1 load/thread each
    int row = tid>>2, ch = tid&3;
    int sc = ch ^ ((row>>1)&3);
    size_t go = (size_t)row*E_DIM + t*64 + ks*32 + sc*8;
    unsigned short* base = &lds[buf][ks*16384];
    gl_lds16(AbH + go, base +         tid*8);
    gl_lds16(AbL + go, base +  4096 + tid*8);
    gl_lds16(BbH + go, base +  8192 + tid*8);
    gl_lds16(BbL + go, base + 12288 + tid*8);
  };
  const int xoff = (g ^ ((r16>>1)&3)) << 3;

  stage(0,0,0); stage(0,1,0); stage(1,0,1);
  asm volatile("s_waitcnt vmcnt(8)" ::: "memory");
  __builtin_amdgcn_s_barrier();

  int cur = 0;
  for(int t=0; t<NT; ++t){
    const int nxt = cur^1;
    #pragma unroll
    for(int ph=0; ph<2; ph++){
      const unsigned short* base = &lds[cur][ph*16384];
      s16x8 ah[4], al[4], bh[2], bl[2];
      #pragma unroll
      for(int mf=0;mf<4;mf++){
        int ro = (wm*64 + mf*16 + r16)*32 + xoff;
        ah[mf] = *(const s16x8*)&base[ro];
        al[mf] = *(const s16x8*)&base[4096 + ro];
      }
      #pragma unroll
      for(int nf=0;nf<2;nf++){
        int ro = (wn*32 + nf*16 + r16)*32 + xoff;
        bh[nf] = *(const s16x8*)&base[8192 + ro];
        bl[nf] = *(const s16x8*)&base[12288 + ro];
      }
      if (ph==0){
        if (t+1 < NT){ stage(nxt,1,t+1); asm volatile("s_waitcnt vmcnt(8)" ::: "memory"); }
        else         {                   asm volatile("s_waitcnt vmcnt(0)" ::: "memory"); }
      } else {
        if (t+2 < NT){ stage(cur,0,t+2); asm volatile("s_waitcnt vmcnt(8)" ::: "memory"); }
        else if (t+1 < NT){              asm volatile("s_waitcnt vmcnt(4)" ::: "memory"); }
        else              {              asm volatile("s_waitcnt vmcnt(0)" ::: "memory"); }
      }
      __builtin_amdgcn_s_barrier();
      __builtin_amdgcn_s_setprio(1);
      #pragma unroll
      for(int mf=0;mf<4;mf++)
        #pragma unroll
        for(int nf=0;nf<2;nf++){
          acc[mf][nf] = mfma_bf16(ah[mf], bh[nf], acc[mf][nf]);
          acc[mf][nf] = mfma_bf16(ah[mf], bl[nf], acc[mf][nf]);
          acc[mf][nf] = mfma_bf16(al[mf], bh[nf], acc[mf][nf]);
        }
      __builtin_amdgcn_s_setprio(0);
      __builtin_amdgcn_s_barrier();
    }
    cur ^= 1;
  }

  const int rowb = mb*128 + wm*64, colb = nb*128 + wn*32;
  #pragma unroll
  for(int mf=0;mf<4;mf++)
    #pragma unroll
    for(int nf=0;nf<2;nf++)
      #pragma unroll
      for(int r=0;r<4;r++){
        int rr = rowb + mf*16 + 4*g + r;
        int cc = colb + nf*16 + r16;
        float v = acc[mf][nf][r] + br1[cc];
        H[(size_t)rr*1024 + cc] = 0.5f*v*(1.0f + erff(v*0.70710678118654752f));
      }
}

// ---------------- router scores ----------------
__global__ __launch_bounds__(256) void scores_kernel(const float* __restrict__ h,
    const float* __restrict__ Wr2, const float* __restrict__ br2,
    float* __restrict__ scores, float* __restrict__ tokmax){
  int tid = threadIdx.x;
  int n = blockIdx.x*4 + (tid>>6);
  int lane = tid & 63;
  const float* hr = h + (size_t)n*1024;
  float s0=0,s1=0,s2=0,s3=0;
  #pragma unroll
  for(int i=0;i<16;i++){
    int j = lane + i*64;
    float hv = hr[j];
    float4 wv = *(const float4*)(Wr2 + (size_t)j*4);
    s0 += hv*wv.x; s1 += hv*wv.y; s2 += hv*wv.z; s3 += hv*wv.w;
  }
  #pragma unroll
  for(int m=32;m>=1;m>>=1){
    s0 += __shfl_xor(s0,m); s1 += __shfl_xor(s1,m);
    s2 += __shfl_xor(s2,m); s3 += __shfl_xor(s3,m);
  }
  if (lane==0){
    s0+=br2[0]; s1+=br2[1]; s2+=br2[2]; s3+=br2[3];
    scores[n*4+0]=s0; scores[n*4+1]=s1; scores[n*4+2]=s2; scores[n*4+3]=s3;
    tokmax[n]=fmaxf(fmaxf(s0,s1),fmaxf(s2,s3));
  }
}

__global__ __launch_bounds__(1024) void aux_kernel(const float* __restrict__ tokmax, float* __restrict__ out_aux){
  __shared__ float red[1024];
  int t = threadIdx.x;
  red[t] = tokmax[t] + tokmax[t+1024] + tokmax[t+2048] + tokmax[t+3072];
  __syncthreads();
  for(int k=512;k>=1;k>>=1){ if(t<k) red[t]+=red[t+k]; __syncthreads(); }
  if (t==0) out_aux[0] = -red[0]/4096.0f;
}

// ---------------- exact top-k via parallel rank ----------------
__global__ __launch_bounds__(256) void rank_kernel(const float* __restrict__ scores,
    int* __restrict__ topk_idx, float* __restrict__ topv, int* __restrict__ rank_of){
  __shared__ unsigned long long keys[4096];   // 32KB
  const int e = blockIdx.y, blk = blockIdx.x, tid = threadIdx.x;
  for(int i=tid;i<4096;i+=256){
    unsigned u = __float_as_uint(scores[i*4+e]);
    unsigned m = (u & 0x80000000u) ? ~u : (u | 0x80000000u);
    keys[i] = (((unsigned long long)m)<<32) | (unsigned)(4095-i);
  }
  __syncthreads();
  const int i = blk*256 + tid;
  const unsigned long long mykey = keys[i];
  int cnt = 0;
  #pragma unroll 8
  for(int j=0;j<4096;j++) cnt += (keys[j] > mykey) ? 1 : 0;
  if (cnt < CAPN){
    topk_idx[e*CAPN + cnt] = i;
    topv[e*CAPN + cnt]     = scores[i*4+e];
    rank_of[e*4096 + i]    = cnt;
  } else {
    rank_of[e*4096 + i]    = -1;
  }
}

// per-expert softmax over the CAPN sorted top values -> sel_w
__global__ __launch_bounds__(1024) void selw_kernel(const float* __restrict__ topv,
    float* __restrict__ sel_w){
  __shared__ float red[1024];
  const int e = blockIdx.x, t = threadIdx.x;
  const float mx = topv[e*CAPN];        // rank 0 == max
  float p0 = expf(topv[e*CAPN + t] - mx);
  float p1 = (t + 1024 < CAPN) ? expf(topv[e*CAPN + t + 1024] - mx) : 0.f;
  red[t] = p0 + p1;
  __syncthreads();
  for(int k=512;k>=1;k>>=1){ if(t<k) red[t]+=red[t+k]; __syncthreads(); }
  const float denom = red[0];
  sel_w[e*CAPN + t] = p0/denom;
  if (t + 1024 < CAPN) sel_w[e*CAPN + t + 1024] = p1/denom;
}

// ---------------- RoPE tables [CAPN][64] ----------------
__global__ __launch_bounds__(256) void rope_kernel(float* __restrict__ cosT, float* __restrict__ sinT){
  int idx = blockIdx.x*256 + threadIdx.x;
  int p = idx>>6, dm = idx&63;
  float inv = powf(10000.0f, -(float)dm/64.0f);
  float ang = (float)p*inv;
  cosT[idx]=cosf(ang);
  sinT[idx]=sinf(ang);
}

// ---------------- pre-gather + pre-rope K into swizzled tiles ----------------
__global__ __launch_bounds__(256) void prerope_k_kernel(const unsigned short* __restrict__ kb,
    const int* __restrict__ topk_idx, const float* __restrict__ cosT, const float* __restrict__ sinT,
    unsigned short* __restrict__ Kg){
  int idx = blockIdx.x*256 + threadIdx.x;   // exact 4*16*1280*16
  int ch = idx & 15;
  int rest = idx >> 4;
  int rank = rest % CAPN;
  int he = rest / CAPN;           // e*16+h
  int e = he >> 4, h = he & 15;
  int tok = topk_idx[e*CAPN + rank];
  int d0 = ch*8;
  const unsigned short* krow = kb + (size_t)tok*QKV_STRIDE + h*DH;
  unsigned short held[8], part[8];
  *(uint4*)held = *(const uint4*)(krow + d0);
  *(uint4*)part = *(const uint4*)(krow + (d0^64));
  const float* cr = cosT + rank*64;
  const float* sr = sinT + rank*64;
  float sgn = (d0<64) ? -1.f : 1.f;
  unsigned short outv[8];
  #pragma unroll
  for(int jj=0;jj<8;jj++){
    int dm = (d0+jj)&63;
    outv[jj] = f2bf(bf2f(held[jj])*cr[dm] + sgn*bf2f(part[jj])*sr[dm]);
  }
  int t = rank >> 6, row = rank & 63;
  size_t tbase = ((size_t)(he)*NTILE + t) * 8192;
  *(uint4*)(Kg + tbase + row*128 + ((ch ^ (row&7))<<3)) = *(uint4*)outv;
}

// ---------------- pre-gather + transpose V into swizzled tiles ----------------
__global__ __launch_bounds__(256) void prev_kernel(const unsigned short* __restrict__ vb,
    const int* __restrict__ topk_idx, unsigned short* __restrict__ Vg){
  __shared__ __align__(16) unsigned short T2[128][72];
  int bid = blockIdx.x;           // e*320 + h*20 + t
  int t = bid % NTILE, h = (bid/NTILE) & 15, e = bid/(NTILE*NH);
  int tid = threadIdx.x, lane = tid & 63, dchb = tid >> 6;
  int tok = topk_idx[e*CAPN + t*64 + lane];
  const unsigned short* vrow = vb + (size_t)tok*QKV_STRIDE + h*DH;
  #pragma unroll
  for(int i=0;i<4;i++){
    int d0 = (dchb + i*4)*8;
    unsigned short vv[8];
    *(uint4*)vv = *(const uint4*)(vrow + d0);
    #pragma unroll
    for(int j=0;j<8;j++) T2[d0+j][lane] = vv[j];   // lane-consecutive: conflict-free
  }
  __syncthreads();
  unsigned short* out = Vg + ((size_t)(e*NH+h)*NTILE + t)*8192;
  #pragma unroll
  for(int i=0;i<4;i++){
    int c = i*256 + tid;
    int d = c>>3, ch = c&7;
    *(uint4*)(out + d*64 + ((ch ^ (d&7))<<3)) = *(const uint4*)&T2[d][ch*8];
  }
}

// ---------------- gathered causal flash attention (128 Q rows / block, 8 waves) ----------------
__global__ __launch_bounds__(512) void attn_kernel(
    const unsigned short* __restrict__ qb,
    const unsigned short* __restrict__ Kg, const unsigned short* __restrict__ Vg,
    const int* __restrict__ topk_idx, const float* __restrict__ sel_w,
    const float* __restrict__ cosT, const float* __restrict__ sinT,
    unsigned short* __restrict__ oexp){
  __shared__ __align__(16) unsigned short KsA[2][8192];
  __shared__ __align__(16) unsigned short Vs[8192];
  __shared__ __align__(16) unsigned short Ps[8][16][72];
  const int id = blockIdx.x;
  const int xcd = id & 7, s_ = id >> 3;             // 80 per xcd
  const int qb2 = NQB - 1 - (s_ % NQB);             // longest first
  const int grp = (s_ / NQB)*8 + xcd;               // 0..63
  const int e = grp >> 4, hh = grp & 15;
  const int tid = threadIdx.x, w = tid>>6, lane = tid&63, g = lane>>4, r16 = lane&15;
  const int* idxE = topk_idx + e*CAPN;
  const unsigned short* Kgb = Kg + (size_t)(e*NH+hh)*CAPN*DH;
  const unsigned short* Vgb = Vg + (size_t)(e*NH+hh)*CAPN*DH;
  const int ktmax = 2*qb2 + 1;

  s16x8 aq[4];
  {
    int qr = qb2*128 + w*16 + r16;
    int tok = idxE[qr];
    const unsigned short* qrow = qb + (size_t)tok*QKV_STRIDE + hh*DH;
    const float* cr = cosT + qr*64;
    const float* sr = sinT + qr*64;
    #pragma unroll
    for(int s=0;s<4;s++){
      int d0 = s*32 + 8*g;
      unsigned short held[8], part[8];
      *(uint4*)held = *(const uint4*)(qrow + d0);
      *(uint4*)part = *(const uint4*)(qrow + (d0^64));
      float sgn = (d0<64) ? -1.f : 1.f;
      union{ s16x8 v; unsigned short u[8]; } fr;
      #pragma unroll
      for(int jj=0;jj<8;jj++){
        int dm = (d0+jj)&63;
        float val = bf2f(held[jj])*cr[dm] + sgn*bf2f(part[jj])*sr[dm];
        fr.u[jj] = f2bf(val * (SCALE_QK*LOG2E));
      }
      aq[s] = fr.v;
    }
  }
  float m_r[4], l_r[4];
  f32x4 o[8];
  #pragma unroll
  for(int r=0;r<4;r++){ m_r[r]=-INFINITY; l_r[r]=0.f; }
  #pragma unroll
  for(int f2=0;f2<8;f2++) o[f2]=f32x4{0.f,0.f,0.f,0.f};

  // prologue: K(0), V(0) — 2 loads each; wait K(0) only
  #pragma unroll
  for(int i=0;i<2;i++){ int c=i*512+tid; gl_lds16(Kgb + c*8, &KsA[0][c*8]); }
  #pragma unroll
  for(int i=0;i<2;i++){ int c=i*512+tid; gl_lds16(Vgb + c*8, &Vs[c*8]); }
  asm volatile("s_waitcnt vmcnt(2)" ::: "memory");
  __builtin_amdgcn_s_barrier();

  for(int kt=0; kt<=ktmax; kt++){
    const int cur = kt & 1;
    if (kt < ktmax){
      const unsigned short* Ksrc = Kgb + (size_t)(kt+1)*8192;
      #pragma unroll
      for(int i=0;i<2;i++){ int c=i*512+tid; gl_lds16(Ksrc + c*8, &KsA[cur^1][c*8]); }
    }
    f32x4 sfr[4];
    #pragma unroll
    for(int fc=0;fc<4;fc++){
      f32x4 a4 = f32x4{0.f,0.f,0.f,0.f};
      const int row = fc*16 + r16;
      #pragma unroll
      for(int s=0;s<4;s++){
        s16x8 bk = *(const s16x8*)&KsA[cur][row*128 + (((s*4+g) ^ (r16&7))<<3)];
        a4 = mfma_bf16(aq[s], bk, a4);
      }
      sfr[fc] = a4;
    }
    if (kt >= 2*qb2){   // diagonal tiles only
      #pragma unroll
      for(int fc=0;fc<4;fc++)
        #pragma unroll
        for(int r=0;r<4;r++){
          int qrank  = qb2*128 + w*16 + 4*g + r;
          int kvrank = kt*64 + fc*16 + r16;
          if (kvrank > qrank) sfr[fc][r] = NEG_BIG;
        }
    }
    float corr[4];
    bool need = false;
    #pragma unroll
    for(int r=0;r<4;r++){
      float mx = fmaxf(fmaxf(sfr[0][r],sfr[1][r]), fmaxf(sfr[2][r],sfr[3][r]));
      #pragma unroll
      for(int mk=1;mk<16;mk<<=1) mx = fmaxf(mx, __shfl_xor(mx,mk));
      float nm = fmaxf(m_r[r], mx);
      need = need || (nm > m_r[r]);
      corr[r] = exp2f(m_r[r]-nm);
      m_r[r] = nm;
    }
    if (__any(need)){
      #pragma unroll
      for(int f2=0;f2<8;f2++)
        #pragma unroll
        for(int r=0;r<4;r++) o[f2][r] *= corr[r];
      #pragma unroll
      for(int r=0;r<4;r++) l_r[r] *= corr[r];
    }
    float rs[4] = {0.f,0.f,0.f,0.f};
    #pragma unroll
    for(int fc=0;fc<4;fc++)
      #pragma unroll
      for(int r=0;r<4;r++){
        float p = exp2f(sfr[fc][r] - m_r[r]);
        rs[r] += p;
        Ps[w][4*g+r][fc*16+r16] = f2bf(p);
      }
    #pragma unroll
    for(int r=0;r<4;r++){
      float ts = rs[r];
      #pragma unroll
      for(int mk=1;mk<16;mk<<=1) ts += __shfl_xor(ts,mk);
      l_r[r] += ts;
    }
    // mid rendezvous: V(kt) landed (K(kt+1) may stay in flight)
    if (kt < ktmax) asm volatile("s_waitcnt vmcnt(2)" ::: "memory");
    else            asm volatile("s_waitcnt vmcnt(0)" ::: "memory");
    __builtin_amdgcn_s_barrier();
    #pragma unroll
    for(int ks=0;ks<2;ks++){
      s16x8 pa = *(const s16x8*)&Ps[w][r16][ks*32 + 8*g];
      #pragma unroll
      for(int fd=0;fd<8;fd++){
        const int row = fd*16 + r16;
        s16x8 vf = *(const s16x8*)&Vs[row*64 + (((ks*4+g) ^ (r16&7))<<3)];
        o[fd] = mfma_bf16(pa, vf, o[fd]);
      }
    }
    __builtin_amdgcn_s_barrier();   // PV reads done; Vs safe to overwrite
    if (kt < ktmax){
      const unsigned short* Vsrc = Vgb + (size_t)(kt+1)*8192;
      #pragma unroll
      for(int i=0;i<2;i++){ int c=i*512+tid; gl_lds16(Vsrc + c*8, &Vs[c*8]); }
      asm volatile("s_waitcnt vmcnt(2)" ::: "memory");   // K(kt+1) landed
      __builtin_amdgcn_s_barrier();
    }
  }
  #pragma unroll
  for(int r=0;r<4;r++){
    int qrank = qb2*128 + w*16 + 4*g + r;
    float fac = sel_w[e*CAPN + qrank] / l_r[r];
    #pragma unroll
    for(int fd=0;fd<8;fd++){
      oexp[((size_t)(e*CAPN + qrank))*E_DIM + hh*DH + fd*16 + r16] = f2bf(o[fd][r]*fac);
    }
  }
}

// ---------------- scatter-accumulate over experts ----------------
__global__ __launch_bounds__(256) void acc_kernel(const unsigned short* __restrict__ oexp,
    const int* __restrict__ rank_of, unsigned short* __restrict__ accb){
  int n = blockIdx.x, t = threadIdx.x;
  int base = t*8;
  float s[8] = {0,0,0,0,0,0,0,0};
  #pragma unroll
  for(int e=0;e<4;e++){
    int r = rank_of[e*4096+n];
    if (r>=0){
      union{uint4 q; unsigned short u[8];} ld;
      ld.q = *(const uint4*)(oexp + ((size_t)(e*CAPN+r))*E_DIM + base);
      #pragma unroll
      for(int j2=0;j2<8;j2++) s[j2] += bf2f(ld.u[j2]);
    }
  }
  union{uint4 q; unsigned short u[8];} st;
  #pragma unroll
  for(int j2=0;j2<8;j2++) st.u[j2] = f2bf(s[j2]);
  *(uint4*)(accb + (size_t)n*E_DIM + base) = st.q;
}

// ---------------- launch ----------------
extern "C" void kernel_launch(void* const* d_in, const int* in_sizes, int n_in,
                              void* d_out, int out_size, void* d_ws, size_t ws_size,
                              hipStream_t stream) {
  const float* x   = (const float*)d_in[0];
  const float* Wq  = (const float*)d_in[1];
  const float* Wk  = (const float*)d_in[2];
  const float* Wv  = (const float*)d_in[3];
  const float* Wo  = (const float*)d_in[4];
  const float* Wr1 = (const float*)d_in[5];
  const float* br1 = (const float*)d_in[6];
  const float* Wr2 = (const float*)d_in[7];
  const float* br2 = (const float*)d_in[8];

  char* ws = (char*)d_ws;
  size_t off = 0;
  auto alloc = [&](size_t bytes)->void*{
    void* p = ws + off;
    off += (bytes + 255) & ~(size_t)255;
    return p;
  };
  unsigned short* xhi   = (unsigned short*)alloc((size_t)N_TOK*E_DIM*2);
  unsigned short* xlo   = (unsigned short*)alloc((size_t)N_TOK*E_DIM*2);
  unsigned short* wr1hi = (unsigned short*)alloc((size_t)E_DIM*1024*2);   // transposed [1024][2048]
  unsigned short* wr1lo = (unsigned short*)alloc((size_t)E_DIM*1024*2);
  unsigned short* wqkvT = (unsigned short*)alloc((size_t)3*E_DIM*E_DIM*2); // [6144][2048]
  unsigned short* woT   = (unsigned short*)alloc((size_t)E_DIM*E_DIM*2);   // contiguous after wqkvT
  void* hv = alloc((size_t)KEXP*NH*CAPN*DH*2);   // max(hbuf 16.8MB, Vg 21MB)
  float* hbuf = (float*)hv;                      // dead after scores_kernel
  unsigned short* Vg = (unsigned short*)hv;      // written by prev_kernel later
  float* scores = (float*)alloc((size_t)N_TOK*4*4);
  float* tokmax = (float*)alloc((size_t)N_TOK*4);
  int*   topkI  = (int*)alloc((size_t)KEXP*CAPN*4);
  float* topv   = (float*)alloc((size_t)KEXP*CAPN*4);
  float* selw   = (float*)alloc((size_t)KEXP*CAPN*4);
  int*   rankof = (int*)alloc((size_t)KEXP*N_TOK*4);
  float* cosT   = (float*)alloc((size_t)CAPN*64*4);
  float* sinT   = (float*)alloc((size_t)CAPN*64*4);
  unsigned short* qkvbuf = (unsigned short*)alloc((size_t)N_TOK*QKV_STRIDE*2);
  unsigned short* oexp = (unsigned short*)alloc((size_t)KEXP*CAPN*E_DIM*2);
  unsigned short* accb = (unsigned short*)alloc((size_t)N_TOK*E_DIM*2);
  if (off > ws_size) return;   // fail loudly (output stays poisoned)

  // Kg (21MB, swizzled) aliases xlo+wr1hi+wr1lo (25.2MB), dead after router GEMM
  unsigned short* Kg = xlo;

  // conversions
  conv_x_kernel<<<(N_TOK*E_DIM/4+255)/256, 256, 0, stream>>>(x, xhi, xlo, N_TOK*E_DIM/4);
  tconv_kernel<<<dim3(1024/32, E_DIM/32), dim3(32,8), 0, stream>>>(Wr1, wr1hi, wr1lo, E_DIM, 1024);
  // fused transpose Wq,Wk,Wv,Wo -> wqkvT(+woT, contiguous)
  tconv4_kernel<<<dim3(E_DIM/32, E_DIM/32, 4), dim3(32,8), 0, stream>>>(Wq, Wk, Wv, Wo, wqkvT);

  // pipelined fused router: H = gelu(x@Wr1 + br1) (hi/lo split)
  gemm_router_p<<<dim3(8, 32), 512, 0, stream>>>(xhi, xlo, wr1hi, wr1lo, br1, hbuf);
  scores_kernel<<<N_TOK/4, 256, 0, stream>>>(hbuf, Wr2, br2, scores, tokmax);
  aux_kernel<<<1, 1024, 0, stream>>>(tokmax, ((float*)d_out) + (size_t)N_TOK*E_DIM);
  // exact top-k via parallel rank + per-expert softmax
  rank_kernel<<<dim3(16, KEXP), 256, 0, stream>>>(scores, topkI, topv, rankof);
  selw_kernel<<<KEXP, 1024, 0, stream>>>(topv, selw);
  rope_kernel<<<CAPN*64/256, 256, 0, stream>>>(cosT, sinT);

  // fused QKV projection: [4096][6144] via 3-slot-ring pipelined GEMM (2 blocks/CU)
  gemm_p<1><<<dim3(QKV_STRIDE/256, N_TOK/128), 512, 0, stream>>>(xhi, wqkvT, qkvbuf, QKV_STRIDE, E_DIM);

  // pre-gather/rope/transpose K,V into dense swizzled tiles
  prerope_k_kernel<<<KEXP*NH*CAPN*16/256, 256, 0, stream>>>(qkvbuf + E_DIM, topkI, cosT, sinT, Kg);
  prev_kernel<<<KEXP*NH*NTILE, 256, 0, stream>>>(qkvbuf + 2*E_DIM, topkI, Vg);

  // gathered causal attention: 128 Q rows / block, 8 waves, 640 blocks
  attn_kernel<<<KEXP*NH*NQB, 512, 0, stream>>>(qkvbuf, Kg, Vg, topkI, selw, cosT, sinT, oexp);

  // scatter-accumulate experts -> token rows
  acc_kernel<<<N_TOK, 256, 0, stream>>>(oexp, rankof, accb);

  // final projection -> d_out (3-slot-ring pipelined, 2 blocks/CU)
  gemm_p<0><<<dim3(E_DIM/256, N_TOK/128), 512, 0, stream>>>(accb, woT, (float*)d_out, E_DIM, E_DIM);
}